// Round 1
// baseline (11090.770 us; speedup 1.0000x reference)
//
#include <hip/hip_runtime.h>

#define T_SEQ   1024
#define E_DIM   1024
#define H_HEADS 16
#define D_HEAD  64
#define L_LAYERS 6
#define B_BATCH 2
#define F_DIM   4096
#define V_VOCAB 32000

typedef float f32x4 __attribute__((ext_vector_type(4)));
typedef short short8 __attribute__((ext_vector_type(8)));

__device__ __forceinline__ unsigned short f2bf(float f) {
  union { float f; unsigned int u; } v; v.f = f;
  unsigned int r = v.u + 0x7fffu + ((v.u >> 16) & 1u);  // RNE
  return (unsigned short)(r >> 16);
}

// ---------------- embedding: x = tok_w[idx] + pos_w ----------------
__global__ void embed_kernel(const int* __restrict__ idx, const float* __restrict__ tok,
                             const float* __restrict__ pos, float* __restrict__ x) {
  int i = blockIdx.x * 256 + threadIdx.x;   // over B*T*(E/4)
  int bt = i >> 8;                          // E/4 = 256 chunks per row
  int e4 = i & 255;
  int t  = bt & (T_SEQ - 1);
  int tokid = idx[bt];
  f32x4 a = *(const f32x4*)(tok + (size_t)tokid * E_DIM + e4 * 4);
  f32x4 p = *(const f32x4*)(pos + (size_t)t * E_DIM + e4 * 4);
  *(f32x4*)(x + (size_t)bt * E_DIM + e4 * 4) = a + p;
}

// ---------------- layernorm (f32 in, bf16 out) ----------------
__global__ void ln_kernel(const float* __restrict__ x, const float* __restrict__ g,
                          const float* __restrict__ b, unsigned short* __restrict__ out) {
  int row = blockIdx.x;
  int tid = threadIdx.x;             // 256 threads, 4 elems each
  const float* xr = x + (size_t)row * E_DIM;
  f32x4 v = *(const f32x4*)(xr + tid * 4);
  float s  = v[0] + v[1] + v[2] + v[3];
  float s2 = v[0]*v[0] + v[1]*v[1] + v[2]*v[2] + v[3]*v[3];
  #pragma unroll
  for (int off = 32; off > 0; off >>= 1) {
    s  += __shfl_xor(s,  off);
    s2 += __shfl_xor(s2, off);
  }
  __shared__ float red[2][4];
  int wave = tid >> 6;
  if ((tid & 63) == 0) { red[0][wave] = s; red[1][wave] = s2; }
  __syncthreads();
  s  = red[0][0] + red[0][1] + red[0][2] + red[0][3];
  s2 = red[1][0] + red[1][1] + red[1][2] + red[1][3];
  float mean = s * (1.0f / E_DIM);
  float var  = s2 * (1.0f / E_DIM) - mean * mean;
  float rstd = rsqrtf(var + 1e-5f);
  f32x4 gv = *(const f32x4*)(g + tid * 4);
  f32x4 bv = *(const f32x4*)(b + tid * 4);
  ushort4 o;
  o.x = f2bf((v[0] - mean) * rstd * gv[0] + bv[0]);
  o.y = f2bf((v[1] - mean) * rstd * gv[1] + bv[1]);
  o.z = f2bf((v[2] - mean) * rstd * gv[2] + bv[2]);
  o.w = f2bf((v[3] - mean) * rstd * gv[3] + bv[3]);
  *(ushort4*)(out + (size_t)row * E_DIM + tid * 4) = o;
}

// ---------------- attention: one wave per (b,h,t), lane = head dim ----------------
__global__ __launch_bounds__(256) void attn_kernel(const float* __restrict__ q,
    const float* __restrict__ k, const float* __restrict__ v,
    unsigned short* __restrict__ y) {
  const int lane = threadIdx.x & 63;
  const int gid  = blockIdx.x * 4 + (threadIdx.x >> 6);
  const int t  = gid & (T_SEQ - 1);
  const int bh = gid >> 10;
  const int h  = bh & (H_HEADS - 1);
  const int b  = bh >> 4;
  const size_t base = (size_t)b * T_SEQ * E_DIM + (size_t)h * D_HEAD;
  const float qd = q[base + (size_t)t * E_DIM + lane] * 0.125f;  // 1/sqrt(64)
  float m = -1e30f, l = 0.0f, acc = 0.0f;
  const float* kp = k + base + lane;
  const float* vp = v + base + lane;
  for (int j = 0; j <= t; ++j) {
    float s = qd * kp[(size_t)j * E_DIM];
    #pragma unroll
    for (int off = 32; off > 0; off >>= 1) s += __shfl_xor(s, off);
    float mn = fmaxf(m, s);
    float c = __expf(m - mn);
    float p = __expf(s - mn);
    l = l * c + p;
    acc = acc * c + p * vp[(size_t)j * E_DIM];
    m = mn;
  }
  y[base + (size_t)t * E_DIM + lane] = f2bf(acc / l);
}

// ---------------- bf16 MFMA GEMM: C = act(A@W + bias) [+res], A bf16 [M,K], W f32 [K,N] ----------------
template<bool HAS_BIAS, bool GELU_ACT, bool HAS_RES, bool OUT_BF16>
__global__ __launch_bounds__(256) void gemm_kernel(
    const unsigned short* __restrict__ A, const float* __restrict__ W,
    const float* __restrict__ bias, const float* __restrict__ res,
    void* __restrict__ out, int M, int N, int K) {
  __shared__ __align__(16) unsigned short As[64][32];   // [row][k]
  __shared__ __align__(16) unsigned short Bs[64][32];   // [col][k]  (W transposed)
  const int tid  = threadIdx.x;
  const int lane = tid & 63;
  const int wave = tid >> 6;
  const int wr = wave >> 1, wc = wave & 1;
  const int m0 = blockIdx.y * 64, n0 = blockIdx.x * 64;
  const int arow = tid >> 2, ak = (tid & 3) * 8;   // A stage: 8 bf16 per thread
  const int bk   = tid >> 3, bn = (tid & 7) * 8;   // W stage: 8 f32 per thread
  const int fr = lane & 15, kb = (lane >> 4) * 8;

  f32x4 acc[2][2];
  #pragma unroll
  for (int i = 0; i < 2; ++i)
    #pragma unroll
    for (int j = 0; j < 2; ++j) acc[i][j] = (f32x4){0.f, 0.f, 0.f, 0.f};

  const unsigned short* aptr = A + (size_t)(m0 + arow) * K + ak;
  const float* wptr = W + (size_t)bk * N + n0 + bn;

  for (int k0 = 0; k0 < K; k0 += 32) {
    uint4 av = *(const uint4*)aptr;  aptr += 32;
    f32x4 w0 = *(const f32x4*)wptr;
    f32x4 w1 = *(const f32x4*)(wptr + 4);
    wptr += (size_t)32 * N;
    *(uint4*)&As[arow][ak] = av;
    #pragma unroll
    for (int i = 0; i < 4; ++i) Bs[bn + i][bk]     = f2bf(w0[i]);
    #pragma unroll
    for (int i = 0; i < 4; ++i) Bs[bn + 4 + i][bk] = f2bf(w1[i]);
    __syncthreads();
    short8 af0 = *(const short8*)&As[32 * wr + fr][kb];
    short8 af1 = *(const short8*)&As[32 * wr + 16 + fr][kb];
    short8 bf0 = *(const short8*)&Bs[32 * wc + fr][kb];
    short8 bf1 = *(const short8*)&Bs[32 * wc + 16 + fr][kb];
    acc[0][0] = __builtin_amdgcn_mfma_f32_16x16x32_bf16(af0, bf0, acc[0][0], 0, 0, 0);
    acc[0][1] = __builtin_amdgcn_mfma_f32_16x16x32_bf16(af0, bf1, acc[0][1], 0, 0, 0);
    acc[1][0] = __builtin_amdgcn_mfma_f32_16x16x32_bf16(af1, bf0, acc[1][0], 0, 0, 0);
    acc[1][1] = __builtin_amdgcn_mfma_f32_16x16x32_bf16(af1, bf1, acc[1][1], 0, 0, 0);
    __syncthreads();
  }

  const int orow = (lane >> 4) * 4, ocol = lane & 15;
  #pragma unroll
  for (int mi = 0; mi < 2; ++mi) {
    #pragma unroll
    for (int ni = 0; ni < 2; ++ni) {
      int col = n0 + 32 * wc + 16 * ni + ocol;
      float bv = HAS_BIAS ? bias[col] : 0.0f;
      #pragma unroll
      for (int r = 0; r < 4; ++r) {
        int row = m0 + 32 * wr + 16 * mi + orow + r;
        float val = acc[mi][ni][r] + bv;
        if (GELU_ACT) val = 0.5f * val * (1.0f + erff(val * 0.70710678118f));
        if (HAS_RES)  val += res[(size_t)row * N + col];
        if (OUT_BF16) ((unsigned short*)out)[(size_t)row * N + col] = f2bf(val);
        else          ((float*)out)[(size_t)row * N + col] = val;
      }
    }
  }
}

extern "C" void kernel_launch(void* const* d_in, const int* in_sizes, int n_in,
                              void* d_out, int out_size, void* d_ws, size_t ws_size,
                              hipStream_t stream) {
  const int*   idx   = (const int*)  d_in[0];
  const float* tok_w = (const float*)d_in[1];
  const float* pos_w = (const float*)d_in[2];
  const float* ln1_g = (const float*)d_in[3];
  const float* ln1_b = (const float*)d_in[4];
  const float* wq    = (const float*)d_in[5];
  const float* wk    = (const float*)d_in[6];
  const float* wv    = (const float*)d_in[7];
  const float* wp    = (const float*)d_in[8];
  const float* bp    = (const float*)d_in[9];
  const float* ln2_g = (const float*)d_in[10];
  const float* ln2_b = (const float*)d_in[11];
  const float* w1    = (const float*)d_in[12];
  const float* b1    = (const float*)d_in[13];
  const float* w2    = (const float*)d_in[14];
  const float* b2    = (const float*)d_in[15];
  const float* lnf_g = (const float*)d_in[16];
  const float* lnf_b = (const float*)d_in[17];
  const float* wlm   = (const float*)d_in[18];
  const float* blm   = (const float*)d_in[19];

  const int M = B_BATCH * T_SEQ;  // 2048
  char* w = (char*)d_ws;
  float* x  = (float*)w;                   w += (size_t)M * E_DIM * 4;
  float* qb = (float*)w;                   w += (size_t)M * E_DIM * 4;
  float* kb = (float*)w;                   w += (size_t)M * E_DIM * 4;
  float* vb = (float*)w;                   w += (size_t)M * E_DIM * 4;
  unsigned short* hb = (unsigned short*)w; w += (size_t)M * E_DIM * 2;
  unsigned short* yb = (unsigned short*)w; w += (size_t)M * E_DIM * 2;
  unsigned short* tb = (unsigned short*)w; w += (size_t)M * F_DIM * 2;

  embed_kernel<<<M * E_DIM / 4 / 256, 256, 0, stream>>>(idx, tok_w, pos_w, x);

  dim3 g_e(E_DIM / 64, M / 64);
  dim3 g_f(F_DIM / 64, M / 64);
  for (int l = 0; l < L_LAYERS; ++l) {
    ln_kernel<<<M, 256, 0, stream>>>(x, ln1_g + (size_t)l * E_DIM, ln1_b + (size_t)l * E_DIM, hb);
    gemm_kernel<false,false,false,false><<<g_e, 256, 0, stream>>>(
        hb, wq + (size_t)l * E_DIM * E_DIM, nullptr, nullptr, qb, M, E_DIM, E_DIM);
    gemm_kernel<false,false,false,false><<<g_e, 256, 0, stream>>>(
        hb, wk + (size_t)l * E_DIM * E_DIM, nullptr, nullptr, kb, M, E_DIM, E_DIM);
    gemm_kernel<false,false,false,false><<<g_e, 256, 0, stream>>>(
        hb, wv + (size_t)l * E_DIM * E_DIM, nullptr, nullptr, vb, M, E_DIM, E_DIM);
    attn_kernel<<<B_BATCH * H_HEADS * T_SEQ / 4, 256, 0, stream>>>(qb, kb, vb, yb);
    gemm_kernel<true,false,true,false><<<g_e, 256, 0, stream>>>(
        yb, wp + (size_t)l * E_DIM * E_DIM, bp + (size_t)l * E_DIM, x, x, M, E_DIM, E_DIM);
    ln_kernel<<<M, 256, 0, stream>>>(x, ln2_g + (size_t)l * E_DIM, ln2_b + (size_t)l * E_DIM, hb);
    gemm_kernel<true,true,false,true><<<g_f, 256, 0, stream>>>(
        hb, w1 + (size_t)l * E_DIM * F_DIM, b1 + (size_t)l * F_DIM, nullptr, tb, M, F_DIM, E_DIM);
    gemm_kernel<true,false,true,false><<<g_e, 256, 0, stream>>>(
        tb, w2 + (size_t)l * F_DIM * E_DIM, b2 + (size_t)l * E_DIM, x, x, M, E_DIM, F_DIM);
  }
  ln_kernel<<<M, 256, 0, stream>>>(x, lnf_g, lnf_b, hb);
  dim3 g_v(V_VOCAB / 64, M / 64);
  gemm_kernel<true,false,false,false><<<g_v, 256, 0, stream>>>(
      hb, wlm, blm, nullptr, (float*)d_out, M, V_VOCAB, E_DIM);
}

// Round 2
// 3123.267 us; speedup vs baseline: 3.5510x; 3.5510x over previous
//
#include <hip/hip_runtime.h>

#define T_SEQ   1024
#define E_DIM   1024
#define H_HEADS 16
#define D_HEAD  64
#define L_LAYERS 6
#define B_BATCH 2
#define F_DIM   4096
#define V_VOCAB 32000

typedef float f32x4 __attribute__((ext_vector_type(4)));
typedef short short8 __attribute__((ext_vector_type(8)));

__device__ __forceinline__ unsigned short f2bf(float f) {
  union { float f; unsigned int u; } v; v.f = f;
  unsigned int r = v.u + 0x7fffu + ((v.u >> 16) & 1u);  // RNE
  return (unsigned short)(r >> 16);
}

// ---------------- embedding: x = tok_w[idx] + pos_w ----------------
__global__ void embed_kernel(const int* __restrict__ idx, const float* __restrict__ tok,
                             const float* __restrict__ pos, float* __restrict__ x) {
  int i = blockIdx.x * 256 + threadIdx.x;   // over B*T*(E/4)
  int bt = i >> 8;                          // E/4 = 256 chunks per row
  int e4 = i & 255;
  int t  = bt & (T_SEQ - 1);
  int tokid = idx[bt];
  f32x4 a = *(const f32x4*)(tok + (size_t)tokid * E_DIM + e4 * 4);
  f32x4 p = *(const f32x4*)(pos + (size_t)t * E_DIM + e4 * 4);
  *(f32x4*)(x + (size_t)bt * E_DIM + e4 * 4) = a + p;
}

// ---------------- layernorm (f32 in, bf16 out) ----------------
__global__ void ln_kernel(const float* __restrict__ x, const float* __restrict__ g,
                          const float* __restrict__ b, unsigned short* __restrict__ out) {
  int row = blockIdx.x;
  int tid = threadIdx.x;             // 256 threads, 4 elems each
  const float* xr = x + (size_t)row * E_DIM;
  f32x4 v = *(const f32x4*)(xr + tid * 4);
  float s  = v[0] + v[1] + v[2] + v[3];
  float s2 = v[0]*v[0] + v[1]*v[1] + v[2]*v[2] + v[3]*v[3];
  #pragma unroll
  for (int off = 32; off > 0; off >>= 1) {
    s  += __shfl_xor(s,  off);
    s2 += __shfl_xor(s2, off);
  }
  __shared__ float red[2][4];
  int wave = tid >> 6;
  if ((tid & 63) == 0) { red[0][wave] = s; red[1][wave] = s2; }
  __syncthreads();
  s  = red[0][0] + red[0][1] + red[0][2] + red[0][3];
  s2 = red[1][0] + red[1][1] + red[1][2] + red[1][3];
  float mean = s * (1.0f / E_DIM);
  float var  = s2 * (1.0f / E_DIM) - mean * mean;
  float rstd = rsqrtf(var + 1e-5f);
  f32x4 gv = *(const f32x4*)(g + tid * 4);
  f32x4 bv = *(const f32x4*)(b + tid * 4);
  ushort4 o;
  o.x = f2bf((v[0] - mean) * rstd * gv[0] + bv[0]);
  o.y = f2bf((v[1] - mean) * rstd * gv[1] + bv[1]);
  o.z = f2bf((v[2] - mean) * rstd * gv[2] + bv[2]);
  o.w = f2bf((v[3] - mean) * rstd * gv[3] + bv[3]);
  *(ushort4*)(out + (size_t)row * E_DIM + tid * 4) = o;
}

// ---------------- MFMA flash attention ----------------
// Block = 4 waves; wave owns 16 q-rows of one (b,h). Key tiles of 32.
// Layouts (16x16x32 bf16 MFMA): A-frag row=lane&15, k=(lane>>4)*8+i.
//                               B-frag col=lane&15, k=(lane>>4)*8+i.
//                               C/D  col=lane&15, row=(lane>>4)*4+r.
__global__ __launch_bounds__(256) void attn_mfma_kernel(
    const unsigned short* __restrict__ q, const unsigned short* __restrict__ k,
    const unsigned short* __restrict__ v, unsigned short* __restrict__ y) {
  __shared__ unsigned short pbuf[4][16][32];   // per-wave P tile (rows x keys)
  const int lane = threadIdx.x & 63;
  const int wave = threadIdx.x >> 6;
  const int h  = blockIdx.y & (H_HEADS - 1);
  const int b  = blockIdx.y >> 4;
  const int r0 = blockIdx.x * 64 + wave * 16;
  const size_t base = (size_t)b * T_SEQ * E_DIM + (size_t)h * D_HEAD;
  const int fr = lane & 15, fg = lane >> 4;

  // Q fragment: rows r0+fr, d = c*32 + fg*8 .. +7
  short8 aq[2];
  #pragma unroll
  for (int c = 0; c < 2; ++c)
    aq[c] = *(const short8*)(q + base + (size_t)(r0 + fr) * E_DIM + c * 32 + fg * 8);

  f32x4 oacc[4];
  #pragma unroll
  for (int cg = 0; cg < 4; ++cg) oacc[cg] = (f32x4){0.f, 0.f, 0.f, 0.f};
  float m_[4], l_[4];
  #pragma unroll
  for (int r = 0; r < 4; ++r) { m_[r] = -1e30f; l_[r] = 0.0f; }

  const int ntiles = (r0 + 47) / 32;
  for (int t = 0; t < ntiles; ++t) {
    const int j0 = t * 32;
    // ---- S = Q @ K^T (2 col-groups of 16 keys) ----
    f32x4 s[2];
    #pragma unroll
    for (int c = 0; c < 2; ++c) {
      const unsigned short* kr = k + base + (size_t)(j0 + c * 16 + fr) * E_DIM + fg * 8;
      short8 bk0 = *(const short8*)kr;
      short8 bk1 = *(const short8*)(kr + 32);
      f32x4 z = (f32x4){0.f, 0.f, 0.f, 0.f};
      z = __builtin_amdgcn_mfma_f32_16x16x32_bf16(aq[0], bk0, z, 0, 0, 0);
      z = __builtin_amdgcn_mfma_f32_16x16x32_bf16(aq[1], bk1, z, 0, 0, 0);
      s[c] = z;
    }
    // ---- mask + online softmax (reduce across the 16-lane col groups) ----
    float cf[4];
    #pragma unroll
    for (int r = 0; r < 4; ++r) {
      const int row = r0 + fg * 4 + r;
      float s0 = (j0 + fr      <= row) ? s[0][r] * 0.125f : -1e30f;
      float s1 = (j0 + 16 + fr <= row) ? s[1][r] * 0.125f : -1e30f;
      float mx = fmaxf(s0, s1);
      mx = fmaxf(mx, __shfl_xor(mx, 1));
      mx = fmaxf(mx, __shfl_xor(mx, 2));
      mx = fmaxf(mx, __shfl_xor(mx, 4));
      mx = fmaxf(mx, __shfl_xor(mx, 8));
      float mn = fmaxf(m_[r], mx);
      cf[r] = __expf(m_[r] - mn);
      float p0 = __expf(s0 - mn), p1 = __expf(s1 - mn);
      float ls = p0 + p1;
      ls += __shfl_xor(ls, 1); ls += __shfl_xor(ls, 2);
      ls += __shfl_xor(ls, 4); ls += __shfl_xor(ls, 8);
      l_[r] = l_[r] * cf[r] + ls;
      m_[r] = mn;
      pbuf[wave][fg * 4 + r][fr]      = f2bf(p0);
      pbuf[wave][fg * 4 + r][16 + fr] = f2bf(p1);
    }
    // drain LDS writes before cross-lane read (intra-wave, no barrier needed)
    asm volatile("s_waitcnt lgkmcnt(0)" ::: "memory");
    __builtin_amdgcn_sched_barrier(0);
    short8 pa = *(const short8*)&pbuf[wave][fr][fg * 8];
    // ---- O = O*cf + P @ V ----
    #pragma unroll
    for (int cg = 0; cg < 4; ++cg) {
      short8 bv;
      #pragma unroll
      for (int i = 0; i < 8; ++i)
        bv[i] = (short)v[base + (size_t)(j0 + fg * 8 + i) * E_DIM + cg * 16 + fr];
      #pragma unroll
      for (int r = 0; r < 4; ++r) oacc[cg][r] *= cf[r];
      oacc[cg] = __builtin_amdgcn_mfma_f32_16x16x32_bf16(pa, bv, oacc[cg], 0, 0, 0);
    }
  }
  #pragma unroll
  for (int cg = 0; cg < 4; ++cg)
    #pragma unroll
    for (int r = 0; r < 4; ++r)
      y[base + (size_t)(r0 + fg * 4 + r) * E_DIM + cg * 16 + fr] = f2bf(oacc[cg][r] / l_[r]);
}

// ---------------- bf16 MFMA GEMM: C = act(A@W + bias) [+res], A bf16 [M,K], W f32 [K,N] ----------------
template<bool HAS_BIAS, bool GELU_ACT, bool HAS_RES, bool OUT_BF16>
__global__ __launch_bounds__(256) void gemm_kernel(
    const unsigned short* __restrict__ A, const float* __restrict__ W,
    const float* __restrict__ bias, const float* __restrict__ res,
    void* __restrict__ out, int M, int N, int K) {
  __shared__ __align__(16) unsigned short As[64][32];   // [row][k]
  __shared__ __align__(16) unsigned short Bs[64][32];   // [col][k]  (W transposed)
  const int tid  = threadIdx.x;
  const int lane = tid & 63;
  const int wave = tid >> 6;
  const int wr = wave >> 1, wc = wave & 1;
  const int m0 = blockIdx.y * 64, n0 = blockIdx.x * 64;
  const int arow = tid >> 2, ak = (tid & 3) * 8;   // A stage: 8 bf16 per thread
  const int bk   = tid >> 3, bn = (tid & 7) * 8;   // W stage: 8 f32 per thread
  const int fr = lane & 15, kb = (lane >> 4) * 8;

  f32x4 acc[2][2];
  #pragma unroll
  for (int i = 0; i < 2; ++i)
    #pragma unroll
    for (int j = 0; j < 2; ++j) acc[i][j] = (f32x4){0.f, 0.f, 0.f, 0.f};

  const unsigned short* aptr = A + (size_t)(m0 + arow) * K + ak;
  const float* wptr = W + (size_t)bk * N + n0 + bn;

  for (int k0 = 0; k0 < K; k0 += 32) {
    uint4 av = *(const uint4*)aptr;  aptr += 32;
    f32x4 w0 = *(const f32x4*)wptr;
    f32x4 w1 = *(const f32x4*)(wptr + 4);
    wptr += (size_t)32 * N;
    *(uint4*)&As[arow][ak] = av;
    #pragma unroll
    for (int i = 0; i < 4; ++i) Bs[bn + i][bk]     = f2bf(w0[i]);
    #pragma unroll
    for (int i = 0; i < 4; ++i) Bs[bn + 4 + i][bk] = f2bf(w1[i]);
    __syncthreads();
    short8 af0 = *(const short8*)&As[32 * wr + fr][kb];
    short8 af1 = *(const short8*)&As[32 * wr + 16 + fr][kb];
    short8 bf0 = *(const short8*)&Bs[32 * wc + fr][kb];
    short8 bf1 = *(const short8*)&Bs[32 * wc + 16 + fr][kb];
    acc[0][0] = __builtin_amdgcn_mfma_f32_16x16x32_bf16(af0, bf0, acc[0][0], 0, 0, 0);
    acc[0][1] = __builtin_amdgcn_mfma_f32_16x16x32_bf16(af0, bf1, acc[0][1], 0, 0, 0);
    acc[1][0] = __builtin_amdgcn_mfma_f32_16x16x32_bf16(af1, bf0, acc[1][0], 0, 0, 0);
    acc[1][1] = __builtin_amdgcn_mfma_f32_16x16x32_bf16(af1, bf1, acc[1][1], 0, 0, 0);
    __syncthreads();
  }

  const int orow = (lane >> 4) * 4, ocol = lane & 15;
  #pragma unroll
  for (int mi = 0; mi < 2; ++mi) {
    #pragma unroll
    for (int ni = 0; ni < 2; ++ni) {
      int col = n0 + 32 * wc + 16 * ni + ocol;
      float bv = HAS_BIAS ? bias[col] : 0.0f;
      #pragma unroll
      for (int r = 0; r < 4; ++r) {
        int row = m0 + 32 * wr + 16 * mi + orow + r;
        float val = acc[mi][ni][r] + bv;
        if (GELU_ACT) val = 0.5f * val * (1.0f + erff(val * 0.70710678118f));
        if (HAS_RES)  val += res[(size_t)row * N + col];
        if (OUT_BF16) ((unsigned short*)out)[(size_t)row * N + col] = f2bf(val);
        else          ((float*)out)[(size_t)row * N + col] = val;
      }
    }
  }
}

extern "C" void kernel_launch(void* const* d_in, const int* in_sizes, int n_in,
                              void* d_out, int out_size, void* d_ws, size_t ws_size,
                              hipStream_t stream) {
  const int*   idx   = (const int*)  d_in[0];
  const float* tok_w = (const float*)d_in[1];
  const float* pos_w = (const float*)d_in[2];
  const float* ln1_g = (const float*)d_in[3];
  const float* ln1_b = (const float*)d_in[4];
  const float* wq    = (const float*)d_in[5];
  const float* wk    = (const float*)d_in[6];
  const float* wv    = (const float*)d_in[7];
  const float* wp    = (const float*)d_in[8];
  const float* bp    = (const float*)d_in[9];
  const float* ln2_g = (const float*)d_in[10];
  const float* ln2_b = (const float*)d_in[11];
  const float* w1    = (const float*)d_in[12];
  const float* b1    = (const float*)d_in[13];
  const float* w2    = (const float*)d_in[14];
  const float* b2    = (const float*)d_in[15];
  const float* lnf_g = (const float*)d_in[16];
  const float* lnf_b = (const float*)d_in[17];
  const float* wlm   = (const float*)d_in[18];
  const float* blm   = (const float*)d_in[19];

  const int M = B_BATCH * T_SEQ;  // 2048
  char* w = (char*)d_ws;
  float* x  = (float*)w;                    w += (size_t)M * E_DIM * 4;
  unsigned short* qb = (unsigned short*)w;  w += (size_t)M * E_DIM * 2;
  unsigned short* kb = (unsigned short*)w;  w += (size_t)M * E_DIM * 2;
  unsigned short* vb = (unsigned short*)w;  w += (size_t)M * E_DIM * 2;
  unsigned short* hb = (unsigned short*)w;  w += (size_t)M * E_DIM * 2;
  unsigned short* yb = (unsigned short*)w;  w += (size_t)M * E_DIM * 2;
  unsigned short* tb = (unsigned short*)w;  w += (size_t)M * F_DIM * 2;

  embed_kernel<<<M * E_DIM / 4 / 256, 256, 0, stream>>>(idx, tok_w, pos_w, x);

  dim3 g_e(E_DIM / 64, M / 64);
  dim3 g_f(F_DIM / 64, M / 64);
  dim3 g_a(T_SEQ / 64, B_BATCH * H_HEADS);
  for (int l = 0; l < L_LAYERS; ++l) {
    ln_kernel<<<M, 256, 0, stream>>>(x, ln1_g + (size_t)l * E_DIM, ln1_b + (size_t)l * E_DIM, hb);
    gemm_kernel<false,false,false,true><<<g_e, 256, 0, stream>>>(
        hb, wq + (size_t)l * E_DIM * E_DIM, nullptr, nullptr, qb, M, E_DIM, E_DIM);
    gemm_kernel<false,false,false,true><<<g_e, 256, 0, stream>>>(
        hb, wk + (size_t)l * E_DIM * E_DIM, nullptr, nullptr, kb, M, E_DIM, E_DIM);
    gemm_kernel<false,false,false,true><<<g_e, 256, 0, stream>>>(
        hb, wv + (size_t)l * E_DIM * E_DIM, nullptr, nullptr, vb, M, E_DIM, E_DIM);
    attn_mfma_kernel<<<g_a, 256, 0, stream>>>(qb, kb, vb, yb);
    gemm_kernel<true,false,true,false><<<g_e, 256, 0, stream>>>(
        yb, wp + (size_t)l * E_DIM * E_DIM, bp + (size_t)l * E_DIM, x, x, M, E_DIM, E_DIM);
    ln_kernel<<<M, 256, 0, stream>>>(x, ln2_g + (size_t)l * E_DIM, ln2_b + (size_t)l * E_DIM, hb);
    gemm_kernel<true,true,false,true><<<g_f, 256, 0, stream>>>(
        hb, w1 + (size_t)l * E_DIM * F_DIM, b1 + (size_t)l * F_DIM, nullptr, tb, M, F_DIM, E_DIM);
    gemm_kernel<true,false,true,false><<<g_e, 256, 0, stream>>>(
        tb, w2 + (size_t)l * F_DIM * E_DIM, b2 + (size_t)l * E_DIM, x, x, M, E_DIM, F_DIM);
  }
  ln_kernel<<<M, 256, 0, stream>>>(x, lnf_g, lnf_b, hb);
  dim3 g_v(V_VOCAB / 64, M / 64);
  gemm_kernel<true,false,false,false><<<g_v, 256, 0, stream>>>(
      hb, wlm, blm, nullptr, (float*)d_out, M, V_VOCAB, E_DIM);
}

// Round 3
// 1725.297 us; speedup vs baseline: 6.4283x; 1.8103x over previous
//
#include <hip/hip_runtime.h>

#define T_SEQ   1024
#define E_DIM   1024
#define H_HEADS 16
#define D_HEAD  64
#define L_LAYERS 6
#define B_BATCH 2
#define F_DIM   4096
#define V_VOCAB 32000

typedef float f32x4 __attribute__((ext_vector_type(4)));
typedef short short8 __attribute__((ext_vector_type(8)));

__device__ __forceinline__ unsigned short f2bf(float f) {
  union { float f; unsigned int u; } v; v.f = f;
  unsigned int r = v.u + 0x7fffu + ((v.u >> 16) & 1u);  // RNE
  return (unsigned short)(r >> 16);
}

// async global->LDS, 16B per lane; lds dest = wave-uniform base + lane*16
#define GLDS16(gp, lp) __builtin_amdgcn_global_load_lds( \
    (const __attribute__((address_space(1))) void*)(gp), \
    (__attribute__((address_space(3))) void*)(lp), 16, 0, 0)

// ---------------- embedding: x = tok_w[idx] + pos_w ----------------
__global__ void embed_kernel(const int* __restrict__ idx, const float* __restrict__ tok,
                             const float* __restrict__ pos, float* __restrict__ x) {
  int i = blockIdx.x * 256 + threadIdx.x;
  int bt = i >> 8;
  int e4 = i & 255;
  int t  = bt & (T_SEQ - 1);
  int tokid = idx[bt];
  f32x4 a = *(const f32x4*)(tok + (size_t)tokid * E_DIM + e4 * 4);
  f32x4 p = *(const f32x4*)(pos + (size_t)t * E_DIM + e4 * 4);
  *(f32x4*)(x + (size_t)bt * E_DIM + e4 * 4) = a + p;
}

// ---------------- layernorm (f32 in, bf16 out) ----------------
__global__ void ln_kernel(const float* __restrict__ x, const float* __restrict__ g,
                          const float* __restrict__ b, unsigned short* __restrict__ out) {
  int row = blockIdx.x;
  int tid = threadIdx.x;
  const float* xr = x + (size_t)row * E_DIM;
  f32x4 v = *(const f32x4*)(xr + tid * 4);
  float s  = v[0] + v[1] + v[2] + v[3];
  float s2 = v[0]*v[0] + v[1]*v[1] + v[2]*v[2] + v[3]*v[3];
  #pragma unroll
  for (int off = 32; off > 0; off >>= 1) {
    s  += __shfl_xor(s,  off);
    s2 += __shfl_xor(s2, off);
  }
  __shared__ float red[2][4];
  int wave = tid >> 6;
  if ((tid & 63) == 0) { red[0][wave] = s; red[1][wave] = s2; }
  __syncthreads();
  s  = red[0][0] + red[0][1] + red[0][2] + red[0][3];
  s2 = red[1][0] + red[1][1] + red[1][2] + red[1][3];
  float mean = s * (1.0f / E_DIM);
  float var  = s2 * (1.0f / E_DIM) - mean * mean;
  float rstd = rsqrtf(var + 1e-5f);
  f32x4 gv = *(const f32x4*)(g + tid * 4);
  f32x4 bv = *(const f32x4*)(b + tid * 4);
  ushort4 o;
  o.x = f2bf((v[0] - mean) * rstd * gv[0] + bv[0]);
  o.y = f2bf((v[1] - mean) * rstd * gv[1] + bv[1]);
  o.z = f2bf((v[2] - mean) * rstd * gv[2] + bv[2]);
  o.w = f2bf((v[3] - mean) * rstd * gv[3] + bv[3]);
  *(ushort4*)(out + (size_t)row * E_DIM + tid * 4) = o;
}

// ---------------- weight transpose+convert: W f32 [K][N] -> Wt bf16 [N][K] ----------------
__global__ __launch_bounds__(256) void wtrans_kernel(const float* __restrict__ W,
    unsigned short* __restrict__ Wt, int K, int N) {
  __shared__ float tile[64][65];
  const int n0 = blockIdx.x * 64, k0 = blockIdx.y * 64;
  const int tr  = threadIdx.x >> 4;         // 0..15
  const int tc4 = (threadIdx.x & 15) * 4;   // 0..60
  #pragma unroll
  for (int p = 0; p < 4; ++p) {
    f32x4 v = *(const f32x4*)(W + (size_t)(k0 + p * 16 + tr) * N + n0 + tc4);
    tile[p * 16 + tr][tc4 + 0] = v[0];
    tile[p * 16 + tr][tc4 + 1] = v[1];
    tile[p * 16 + tr][tc4 + 2] = v[2];
    tile[p * 16 + tr][tc4 + 3] = v[3];
  }
  __syncthreads();
  #pragma unroll
  for (int p = 0; p < 4; ++p) {
    int n = p * 16 + tr;
    ushort4 o;
    o.x = f2bf(tile[tc4 + 0][n]);
    o.y = f2bf(tile[tc4 + 1][n]);
    o.z = f2bf(tile[tc4 + 2][n]);
    o.w = f2bf(tile[tc4 + 3][n]);
    *(ushort4*)(Wt + (size_t)(n0 + n) * K + k0 + tc4) = o;
  }
}

// ---------------- MFMA flash attention (fused qkv input, row stride 3E) ----------------
__global__ __launch_bounds__(256) void attn_mfma_kernel(
    const unsigned short* __restrict__ qkv, unsigned short* __restrict__ y) {
  __shared__ unsigned short pbuf[4][16][32];
  const int lane = threadIdx.x & 63;
  const int wave = threadIdx.x >> 6;
  const int h  = blockIdx.y & (H_HEADS - 1);
  const int b  = blockIdx.y >> 4;
  const int r0 = blockIdx.x * 64 + wave * 16;
  const size_t RS = 3 * E_DIM;
  const unsigned short* q = qkv + (size_t)b * T_SEQ * RS + (size_t)h * D_HEAD;
  const unsigned short* k = q + E_DIM;
  const unsigned short* v = q + 2 * E_DIM;
  const size_t ybase = (size_t)b * T_SEQ * E_DIM + (size_t)h * D_HEAD;
  const int fr = lane & 15, fg = lane >> 4;

  short8 aq[2];
  #pragma unroll
  for (int c = 0; c < 2; ++c)
    aq[c] = *(const short8*)(q + (size_t)(r0 + fr) * RS + c * 32 + fg * 8);

  f32x4 oacc[4];
  #pragma unroll
  for (int cg = 0; cg < 4; ++cg) oacc[cg] = (f32x4){0.f, 0.f, 0.f, 0.f};
  float m_[4], l_[4];
  #pragma unroll
  for (int r = 0; r < 4; ++r) { m_[r] = -1e30f; l_[r] = 0.0f; }

  const int ntiles = (r0 + 47) / 32;
  for (int t = 0; t < ntiles; ++t) {
    const int j0 = t * 32;
    f32x4 s[2];
    #pragma unroll
    for (int c = 0; c < 2; ++c) {
      const unsigned short* kr = k + (size_t)(j0 + c * 16 + fr) * RS + fg * 8;
      short8 bk0 = *(const short8*)kr;
      short8 bk1 = *(const short8*)(kr + 32);
      f32x4 z = (f32x4){0.f, 0.f, 0.f, 0.f};
      z = __builtin_amdgcn_mfma_f32_16x16x32_bf16(aq[0], bk0, z, 0, 0, 0);
      z = __builtin_amdgcn_mfma_f32_16x16x32_bf16(aq[1], bk1, z, 0, 0, 0);
      s[c] = z;
    }
    float cf[4];
    #pragma unroll
    for (int r = 0; r < 4; ++r) {
      const int row = r0 + fg * 4 + r;
      float s0 = (j0 + fr      <= row) ? s[0][r] * 0.125f : -1e30f;
      float s1 = (j0 + 16 + fr <= row) ? s[1][r] * 0.125f : -1e30f;
      float mx = fmaxf(s0, s1);
      mx = fmaxf(mx, __shfl_xor(mx, 1));
      mx = fmaxf(mx, __shfl_xor(mx, 2));
      mx = fmaxf(mx, __shfl_xor(mx, 4));
      mx = fmaxf(mx, __shfl_xor(mx, 8));
      float mn = fmaxf(m_[r], mx);
      cf[r] = __expf(m_[r] - mn);
      float p0 = __expf(s0 - mn), p1 = __expf(s1 - mn);
      float ls = p0 + p1;
      ls += __shfl_xor(ls, 1); ls += __shfl_xor(ls, 2);
      ls += __shfl_xor(ls, 4); ls += __shfl_xor(ls, 8);
      l_[r] = l_[r] * cf[r] + ls;
      m_[r] = mn;
      pbuf[wave][fg * 4 + r][fr]      = f2bf(p0);
      pbuf[wave][fg * 4 + r][16 + fr] = f2bf(p1);
    }
    asm volatile("s_waitcnt lgkmcnt(0)" ::: "memory");
    __builtin_amdgcn_sched_barrier(0);
    short8 pa = *(const short8*)&pbuf[wave][fr][fg * 8];
    #pragma unroll
    for (int cg = 0; cg < 4; ++cg) {
      short8 bv;
      #pragma unroll
      for (int i = 0; i < 8; ++i)
        bv[i] = (short)v[(size_t)(j0 + fg * 8 + i) * RS + cg * 16 + fr];
      #pragma unroll
      for (int r = 0; r < 4; ++r) oacc[cg][r] *= cf[r];
      oacc[cg] = __builtin_amdgcn_mfma_f32_16x16x32_bf16(pa, bv, oacc[cg], 0, 0, 0);
    }
  }
  #pragma unroll
  for (int cg = 0; cg < 4; ++cg)
    #pragma unroll
    for (int r = 0; r < 4; ++r)
      y[ybase + (size_t)(r0 + fg * 4 + r) * E_DIM + cg * 16 + fr] = f2bf(oacc[cg][r] / l_[r]);
}

// ---------------- m97-style bf16 GEMM: C = act(A@Bt^T + bias) [+res] ----------------
// A bf16 [M][K], Bt bf16 [N][K]. BM x BN tile, BK=32, 4 waves (2x2),
// global_load_lds width-16 staging, ds_read_b128 fragments.
template<int BM, int BN, bool HAS_BIAS, bool GELU_ACT, bool HAS_RES, bool OUT_BF16>
__global__ __launch_bounds__(256) void gemm_bt_kernel(
    const unsigned short* __restrict__ A, const unsigned short* __restrict__ Bt,
    const float* __restrict__ bias, const float* __restrict__ res,
    void* __restrict__ out, int M, int N, int K) {
  constexpr int BK = 32;
  constexpr int MR = BM / 32;   // A frags per wave
  constexpr int NR = BN / 32;   // B frags per wave
  constexpr int ACH = BM / 64;  // 4KB staging chunks for A
  constexpr int BCH = BN / 64;
  __shared__ __align__(16) unsigned short As[BM * BK];
  __shared__ __align__(16) unsigned short Bs[BN * BK];
  const int tid  = threadIdx.x;
  const int lane = tid & 63;
  const int wave = tid >> 6;
  const int wr = wave >> 1, wc = wave & 1;
  const int m0 = blockIdx.y * BM, n0 = blockIdx.x * BN;
  const int fr = lane & 15, fg = lane >> 4;

  // staging: chunk i covers rows i*64..i*64+63; wave handles 16 rows, lane/4 within
  const int srow  = wave * 16 + (lane >> 2);
  const int skoff = (lane & 3) * 8;
  const unsigned short* aG = A  + (size_t)(m0 + srow) * K + skoff;
  const unsigned short* bG = Bt + (size_t)(n0 + srow) * K + skoff;
  const int ldsoff = wave * 1024;  // bytes within a 4KB chunk

  f32x4 acc[MR][NR];
  #pragma unroll
  for (int mi = 0; mi < MR; ++mi)
    #pragma unroll
    for (int ni = 0; ni < NR; ++ni) acc[mi][ni] = (f32x4){0.f, 0.f, 0.f, 0.f};

  for (int k0 = 0; k0 < K; k0 += BK) {
    __syncthreads();   // prior tile's reads complete before overwrite
    #pragma unroll
    for (int i = 0; i < ACH; ++i)
      GLDS16(aG + (size_t)i * 64 * K + k0, (char*)As + i * 4096 + ldsoff);
    #pragma unroll
    for (int i = 0; i < BCH; ++i)
      GLDS16(bG + (size_t)i * 64 * K + k0, (char*)Bs + i * 4096 + ldsoff);
    __syncthreads();   // staged data visible (vmcnt(0) drained by barrier)

    short8 af[MR], bf[NR];
    #pragma unroll
    for (int mi = 0; mi < MR; ++mi)
      af[mi] = *(const short8*)&As[(wr * (BM / 2) + mi * 16 + fr) * BK + fg * 8];
    #pragma unroll
    for (int ni = 0; ni < NR; ++ni)
      bf[ni] = *(const short8*)&Bs[(wc * (BN / 2) + ni * 16 + fr) * BK + fg * 8];
    #pragma unroll
    for (int mi = 0; mi < MR; ++mi)
      #pragma unroll
      for (int ni = 0; ni < NR; ++ni)
        acc[mi][ni] = __builtin_amdgcn_mfma_f32_16x16x32_bf16(af[mi], bf[ni], acc[mi][ni], 0, 0, 0);
  }

  #pragma unroll
  for (int mi = 0; mi < MR; ++mi) {
    #pragma unroll
    for (int ni = 0; ni < NR; ++ni) {
      const int col = n0 + wc * (BN / 2) + ni * 16 + fr;
      float bv = HAS_BIAS ? bias[col] : 0.0f;
      #pragma unroll
      for (int r = 0; r < 4; ++r) {
        const int row = m0 + wr * (BM / 2) + mi * 16 + fg * 4 + r;
        float val = acc[mi][ni][r] + bv;
        if (GELU_ACT) val = 0.5f * val * (1.0f + erff(val * 0.70710678118f));
        if (HAS_RES)  val += res[(size_t)row * N + col];
        if (OUT_BF16) ((unsigned short*)out)[(size_t)row * N + col] = f2bf(val);
        else          ((float*)out)[(size_t)row * N + col] = val;
      }
    }
  }
}

extern "C" void kernel_launch(void* const* d_in, const int* in_sizes, int n_in,
                              void* d_out, int out_size, void* d_ws, size_t ws_size,
                              hipStream_t stream) {
  const int*   idx   = (const int*)  d_in[0];
  const float* tok_w = (const float*)d_in[1];
  const float* pos_w = (const float*)d_in[2];
  const float* ln1_g = (const float*)d_in[3];
  const float* ln1_b = (const float*)d_in[4];
  const float* wq    = (const float*)d_in[5];
  const float* wk    = (const float*)d_in[6];
  const float* wv    = (const float*)d_in[7];
  const float* wp    = (const float*)d_in[8];
  const float* bp    = (const float*)d_in[9];
  const float* ln2_g = (const float*)d_in[10];
  const float* ln2_b = (const float*)d_in[11];
  const float* w1    = (const float*)d_in[12];
  const float* b1    = (const float*)d_in[13];
  const float* w2    = (const float*)d_in[14];
  const float* b2    = (const float*)d_in[15];
  const float* lnf_g = (const float*)d_in[16];
  const float* lnf_b = (const float*)d_in[17];
  const float* wlm   = (const float*)d_in[18];
  const float* blm   = (const float*)d_in[19];

  const int M = B_BATCH * T_SEQ;  // 2048
  const size_t EE = (size_t)E_DIM * E_DIM;
  char* p = (char*)d_ws;
  float* x            = (float*)p;          p += (size_t)M * E_DIM * 4;       // 8 MB
  unsigned short* hb  = (unsigned short*)p; p += (size_t)M * E_DIM * 2;       // 4 MB
  unsigned short* qkv = (unsigned short*)p; p += (size_t)M * 3 * E_DIM * 2;   // 12 MB
  unsigned short* yb  = (unsigned short*)p; p += (size_t)M * E_DIM * 2;       // 4 MB
  unsigned short* tb  = (unsigned short*)p; p += (size_t)M * F_DIM * 2;       // 16 MB
  unsigned short* wtb = (unsigned short*)p; p += (size_t)V_VOCAB * E_DIM * 2; // 65.5 MB

  auto wtrans = [&](const float* W, unsigned short* Wt, int K, int N) {
    wtrans_kernel<<<dim3(N / 64, K / 64), 256, 0, stream>>>(W, Wt, K, N);
  };

  embed_kernel<<<M * E_DIM / 4 / 256, 256, 0, stream>>>(idx, tok_w, pos_w, x);

  dim3 g_a(T_SEQ / 64, B_BATCH * H_HEADS);
  for (int l = 0; l < L_LAYERS; ++l) {
    ln_kernel<<<M, 256, 0, stream>>>(x, ln1_g + (size_t)l * E_DIM, ln1_b + (size_t)l * E_DIM, hb);
    // fused QKV: Wt rows [0,E)=q, [E,2E)=k, [2E,3E)=v
    wtrans(wq + l * EE, wtb,          E_DIM, E_DIM);
    wtrans(wk + l * EE, wtb + EE,     E_DIM, E_DIM);
    wtrans(wv + l * EE, wtb + 2 * EE, E_DIM, E_DIM);
    gemm_bt_kernel<128, 128, false, false, false, true>
        <<<dim3(3 * E_DIM / 128, M / 128), 256, 0, stream>>>(
        hb, wtb, nullptr, nullptr, qkv, M, 3 * E_DIM, E_DIM);
    attn_mfma_kernel<<<g_a, 256, 0, stream>>>(qkv, yb);
    wtrans(wp + l * EE, wtb, E_DIM, E_DIM);
    gemm_bt_kernel<64, 128, true, false, true, false>
        <<<dim3(E_DIM / 128, M / 64), 256, 0, stream>>>(
        yb, wtb, bp + (size_t)l * E_DIM, x, x, M, E_DIM, E_DIM);
    ln_kernel<<<M, 256, 0, stream>>>(x, ln2_g + (size_t)l * E_DIM, ln2_b + (size_t)l * E_DIM, hb);
    wtrans(w1 + (size_t)l * E_DIM * F_DIM, wtb, E_DIM, F_DIM);
    gemm_bt_kernel<128, 128, true, true, false, true>
        <<<dim3(F_DIM / 128, M / 128), 256, 0, stream>>>(
        hb, wtb, b1 + (size_t)l * F_DIM, nullptr, tb, M, F_DIM, E_DIM);
    wtrans(w2 + (size_t)l * F_DIM * E_DIM, wtb, F_DIM, E_DIM);
    gemm_bt_kernel<64, 128, true, false, true, false>
        <<<dim3(E_DIM / 128, M / 64), 256, 0, stream>>>(
        tb, wtb, b2 + (size_t)l * E_DIM, x, x, M, E_DIM, F_DIM);
  }
  ln_kernel<<<M, 256, 0, stream>>>(x, lnf_g, lnf_b, hb);
  wtrans(wlm, wtb, E_DIM, V_VOCAB);
  gemm_bt_kernel<128, 128, true, false, false, false>
      <<<dim3(V_VOCAB / 128, M / 128), 256, 0, stream>>>(
      hb, wtb, blm, nullptr, (float*)d_out, M, V_VOCAB, E_DIM);
}

// Round 4
// 1718.173 us; speedup vs baseline: 6.4550x; 1.0041x over previous
//
#include <hip/hip_runtime.h>

#define T_SEQ   1024
#define E_DIM   1024
#define H_HEADS 16
#define D_HEAD  64
#define L_LAYERS 6
#define B_BATCH 2
#define F_DIM   4096
#define V_VOCAB 32000

typedef float f32x4 __attribute__((ext_vector_type(4)));
typedef short short8 __attribute__((ext_vector_type(8)));

__device__ __forceinline__ unsigned short f2bf(float f) {
  union { float f; unsigned int u; } v; v.f = f;
  unsigned int r = v.u + 0x7fffu + ((v.u >> 16) & 1u);  // RNE
  return (unsigned short)(r >> 16);
}

// async global->LDS, 16B per lane; lds dest = wave-uniform base + lane*16
#define GLDS16(gp, lp) __builtin_amdgcn_global_load_lds( \
    (const __attribute__((address_space(1))) void*)(gp), \
    (__attribute__((address_space(3))) void*)(lp), 16, 0, 0)

// ---------------- embedding: x = tok_w[idx] + pos_w ----------------
__global__ void embed_kernel(const int* __restrict__ idx, const float* __restrict__ tok,
                             const float* __restrict__ pos, float* __restrict__ x) {
  int i = blockIdx.x * 256 + threadIdx.x;
  int bt = i >> 8;
  int e4 = i & 255;
  int t  = bt & (T_SEQ - 1);
  int tokid = idx[bt];
  f32x4 a = *(const f32x4*)(tok + (size_t)tokid * E_DIM + e4 * 4);
  f32x4 p = *(const f32x4*)(pos + (size_t)t * E_DIM + e4 * 4);
  *(f32x4*)(x + (size_t)bt * E_DIM + e4 * 4) = a + p;
}

// ---------------- layernorm (f32 in, bf16 out) ----------------
__global__ void ln_kernel(const float* __restrict__ x, const float* __restrict__ g,
                          const float* __restrict__ b, unsigned short* __restrict__ out) {
  int row = blockIdx.x;
  int tid = threadIdx.x;
  const float* xr = x + (size_t)row * E_DIM;
  f32x4 v = *(const f32x4*)(xr + tid * 4);
  float s  = v[0] + v[1] + v[2] + v[3];
  float s2 = v[0]*v[0] + v[1]*v[1] + v[2]*v[2] + v[3]*v[3];
  #pragma unroll
  for (int off = 32; off > 0; off >>= 1) {
    s  += __shfl_xor(s,  off);
    s2 += __shfl_xor(s2, off);
  }
  __shared__ float red[2][4];
  int wave = tid >> 6;
  if ((tid & 63) == 0) { red[0][wave] = s; red[1][wave] = s2; }
  __syncthreads();
  s  = red[0][0] + red[0][1] + red[0][2] + red[0][3];
  s2 = red[1][0] + red[1][1] + red[1][2] + red[1][3];
  float mean = s * (1.0f / E_DIM);
  float var  = s2 * (1.0f / E_DIM) - mean * mean;
  float rstd = rsqrtf(var + 1e-5f);
  f32x4 gv = *(const f32x4*)(g + tid * 4);
  f32x4 bv = *(const f32x4*)(b + tid * 4);
  ushort4 o;
  o.x = f2bf((v[0] - mean) * rstd * gv[0] + bv[0]);
  o.y = f2bf((v[1] - mean) * rstd * gv[1] + bv[1]);
  o.z = f2bf((v[2] - mean) * rstd * gv[2] + bv[2]);
  o.w = f2bf((v[3] - mean) * rstd * gv[3] + bv[3]);
  *(ushort4*)(out + (size_t)row * E_DIM + tid * 4) = o;
}

// ---------------- weight transpose+convert: W f32 [K][N] -> Wt bf16 [N][K] ----------------
__global__ __launch_bounds__(256) void wtrans_kernel(const float* __restrict__ W,
    unsigned short* __restrict__ Wt, int K, int N) {
  __shared__ float tile[64][65];
  const int n0 = blockIdx.x * 64, k0 = blockIdx.y * 64;
  const int tr  = threadIdx.x >> 4;
  const int tc4 = (threadIdx.x & 15) * 4;
  #pragma unroll
  for (int p = 0; p < 4; ++p) {
    f32x4 v = *(const f32x4*)(W + (size_t)(k0 + p * 16 + tr) * N + n0 + tc4);
    tile[p * 16 + tr][tc4 + 0] = v[0];
    tile[p * 16 + tr][tc4 + 1] = v[1];
    tile[p * 16 + tr][tc4 + 2] = v[2];
    tile[p * 16 + tr][tc4 + 3] = v[3];
  }
  __syncthreads();
  #pragma unroll
  for (int p = 0; p < 4; ++p) {
    int n = p * 16 + tr;
    ushort4 o;
    o.x = f2bf(tile[tc4 + 0][n]);
    o.y = f2bf(tile[tc4 + 1][n]);
    o.z = f2bf(tile[tc4 + 2][n]);
    o.w = f2bf(tile[tc4 + 3][n]);
    *(ushort4*)(Wt + (size_t)(n0 + n) * K + k0 + tc4) = o;
  }
}

// ---------------- MFMA flash attention, block-shared K/V LDS staging ----------------
// Block = 4 waves, 64 q-rows, one (b,h). K tile [32][64] XOR-swizzled; V tile
// transposed to [64][32] XOR-swizzled so PV B-frag is one ds_read_b128.
__global__ __launch_bounds__(256) void attn_mfma_kernel(
    const unsigned short* __restrict__ qkv, unsigned short* __restrict__ y) {
  __shared__ __align__(16) unsigned short Kl[32 * 64];
  __shared__ __align__(16) unsigned short Vt[64 * 32];
  __shared__ unsigned short pbuf[4][16][32];
  const int tid  = threadIdx.x;
  const int lane = tid & 63;
  const int wave = tid >> 6;
  const int h  = blockIdx.y & (H_HEADS - 1);
  const int b  = blockIdx.y >> 4;
  const int r0 = blockIdx.x * 64 + wave * 16;
  const size_t RS = 3 * E_DIM;
  const unsigned short* q = qkv + (size_t)b * T_SEQ * RS + (size_t)h * D_HEAD;
  const unsigned short* k = q + E_DIM;
  const unsigned short* v = q + 2 * E_DIM;
  const size_t ybase = (size_t)b * T_SEQ * E_DIM + (size_t)h * D_HEAD;
  const int fr = lane & 15, fg = lane >> 4;
  const int skey = tid >> 3;        // 0..31
  const int schk = tid & 7;         // 0..7

  short8 aq[2];
  #pragma unroll
  for (int c = 0; c < 2; ++c)
    aq[c] = *(const short8*)(q + (size_t)(r0 + fr) * RS + c * 32 + fg * 8);

  f32x4 oacc[4];
  #pragma unroll
  for (int cg = 0; cg < 4; ++cg) oacc[cg] = (f32x4){0.f, 0.f, 0.f, 0.f};
  float m_[4], l_[4];
  #pragma unroll
  for (int r = 0; r < 4; ++r) { m_[r] = -1e30f; l_[r] = 0.0f; }

  const int ntiles = blockIdx.x * 2 + 2;   // block-uniform (covers rows r0..r0+63)
  for (int t = 0; t < ntiles; ++t) {
    const int j0 = t * 32;
    __syncthreads();
    // ---- stage K [32][64] swizzled: byte ^= (row&7)<<4 ----
    short8 kv8 = *(const short8*)(k + (size_t)(j0 + skey) * RS + schk * 8);
    *(short8*)((char*)Kl + ((skey * 128 + schk * 16) ^ ((skey & 7) << 4)));
    *(short8*)((char*)Kl + ((skey * 128 + schk * 16) ^ ((skey & 7) << 4))) = kv8;
    // ---- stage V transposed [64][32] swizzled: byte ^= ((d>>3)&3)<<4 ----
    short8 vv8 = *(const short8*)(v + (size_t)(j0 + skey) * RS + schk * 8);
    #pragma unroll
    for (int i = 0; i < 8; ++i) {
      int d = schk * 8 + i;
      *(unsigned short*)((char*)Vt + ((d * 64 + skey * 2) ^ (((d >> 3) & 3) << 4))) =
          (unsigned short)vv8[i];
    }
    __syncthreads();
    if (j0 <= r0 + 15) {   // wave-uniform guard; barriers stay block-uniform
      // ---- S = Q @ K^T ----
      f32x4 s[2];
      #pragma unroll
      for (int c = 0; c < 2; ++c) {
        const int row = c * 16 + fr;
        short8 bk0 = *(const short8*)((char*)Kl + ((row * 128 + fg * 16)      ^ ((row & 7) << 4)));
        short8 bk1 = *(const short8*)((char*)Kl + ((row * 128 + 64 + fg * 16) ^ ((row & 7) << 4)));
        f32x4 z = (f32x4){0.f, 0.f, 0.f, 0.f};
        z = __builtin_amdgcn_mfma_f32_16x16x32_bf16(aq[0], bk0, z, 0, 0, 0);
        z = __builtin_amdgcn_mfma_f32_16x16x32_bf16(aq[1], bk1, z, 0, 0, 0);
        s[c] = z;
      }
      // ---- mask + online softmax ----
      float cf[4];
      #pragma unroll
      for (int r = 0; r < 4; ++r) {
        const int row = r0 + fg * 4 + r;
        float s0 = (j0 + fr      <= row) ? s[0][r] * 0.125f : -1e30f;
        float s1 = (j0 + 16 + fr <= row) ? s[1][r] * 0.125f : -1e30f;
        float mx = fmaxf(s0, s1);
        mx = fmaxf(mx, __shfl_xor(mx, 1));
        mx = fmaxf(mx, __shfl_xor(mx, 2));
        mx = fmaxf(mx, __shfl_xor(mx, 4));
        mx = fmaxf(mx, __shfl_xor(mx, 8));
        float mn = fmaxf(m_[r], mx);
        cf[r] = __expf(m_[r] - mn);
        float p0 = __expf(s0 - mn), p1 = __expf(s1 - mn);
        float ls = p0 + p1;
        ls += __shfl_xor(ls, 1); ls += __shfl_xor(ls, 2);
        ls += __shfl_xor(ls, 4); ls += __shfl_xor(ls, 8);
        l_[r] = l_[r] * cf[r] + ls;
        m_[r] = mn;
        pbuf[wave][fg * 4 + r][fr]      = f2bf(p0);
        pbuf[wave][fg * 4 + r][16 + fr] = f2bf(p1);
      }
      asm volatile("s_waitcnt lgkmcnt(0)" ::: "memory");
      __builtin_amdgcn_sched_barrier(0);
      short8 pa = *(const short8*)&pbuf[wave][fr][fg * 8];
      // ---- O = O*cf + P @ V ----
      #pragma unroll
      for (int cg = 0; cg < 4; ++cg) {
        const int d = cg * 16 + fr;
        short8 bv = *(const short8*)((char*)Vt + ((d * 64 + fg * 16) ^ (((d >> 3) & 3) << 4)));
        #pragma unroll
        for (int r = 0; r < 4; ++r) oacc[cg][r] *= cf[r];
        oacc[cg] = __builtin_amdgcn_mfma_f32_16x16x32_bf16(pa, bv, oacc[cg], 0, 0, 0);
      }
    }
  }
  #pragma unroll
  for (int cg = 0; cg < 4; ++cg)
    #pragma unroll
    for (int r = 0; r < 4; ++r)
      y[ybase + (size_t)(r0 + fg * 4 + r) * E_DIM + cg * 16 + fr] = f2bf(oacc[cg][r] / l_[r]);
}

// ---------------- m97-style bf16 GEMM: C = act(A@Bt^T + bias) [+res] ----------------
// Grid: x = M-tiles (consecutive blocks share the weight tile -> L2/L3 reuse).
template<int BM, int BN, bool HAS_BIAS, bool GELU_ACT, bool HAS_RES, bool OUT_BF16>
__global__ __launch_bounds__(256) void gemm_bt_kernel(
    const unsigned short* __restrict__ A, const unsigned short* __restrict__ Bt,
    const float* __restrict__ bias, const float* __restrict__ res,
    void* __restrict__ out, int M, int N, int K) {
  constexpr int BK = 32;
  constexpr int MR = BM / 32;
  constexpr int NR = BN / 32;
  constexpr int ACH = BM / 64;
  constexpr int BCH = BN / 64;
  __shared__ __align__(16) unsigned short As[BM * BK];
  __shared__ __align__(16) unsigned short Bs[BN * BK];
  const int tid  = threadIdx.x;
  const int lane = tid & 63;
  const int wave = tid >> 6;
  const int wr = wave >> 1, wc = wave & 1;
  const int m0 = blockIdx.x * BM, n0 = blockIdx.y * BN;
  const int fr = lane & 15, fg = lane >> 4;

  const int srow  = wave * 16 + (lane >> 2);
  const int skoff = (lane & 3) * 8;
  const unsigned short* aG = A  + (size_t)(m0 + srow) * K + skoff;
  const unsigned short* bG = Bt + (size_t)(n0 + srow) * K + skoff;
  const int ldsoff = wave * 1024;

  f32x4 acc[MR][NR];
  #pragma unroll
  for (int mi = 0; mi < MR; ++mi)
    #pragma unroll
    for (int ni = 0; ni < NR; ++ni) acc[mi][ni] = (f32x4){0.f, 0.f, 0.f, 0.f};

  for (int k0 = 0; k0 < K; k0 += BK) {
    __syncthreads();
    #pragma unroll
    for (int i = 0; i < ACH; ++i)
      GLDS16(aG + (size_t)i * 64 * K + k0, (char*)As + i * 4096 + ldsoff);
    #pragma unroll
    for (int i = 0; i < BCH; ++i)
      GLDS16(bG + (size_t)i * 64 * K + k0, (char*)Bs + i * 4096 + ldsoff);
    __syncthreads();

    short8 af[MR], bf[NR];
    #pragma unroll
    for (int mi = 0; mi < MR; ++mi)
      af[mi] = *(const short8*)&As[(wr * (BM / 2) + mi * 16 + fr) * BK + fg * 8];
    #pragma unroll
    for (int ni = 0; ni < NR; ++ni)
      bf[ni] = *(const short8*)&Bs[(wc * (BN / 2) + ni * 16 + fr) * BK + fg * 8];
    #pragma unroll
    for (int mi = 0; mi < MR; ++mi)
      #pragma unroll
      for (int ni = 0; ni < NR; ++ni)
        acc[mi][ni] = __builtin_amdgcn_mfma_f32_16x16x32_bf16(af[mi], bf[ni], acc[mi][ni], 0, 0, 0);
  }

  #pragma unroll
  for (int mi = 0; mi < MR; ++mi) {
    #pragma unroll
    for (int ni = 0; ni < NR; ++ni) {
      const int col = n0 + wc * (BN / 2) + ni * 16 + fr;
      float bv = HAS_BIAS ? bias[col] : 0.0f;
      #pragma unroll
      for (int r = 0; r < 4; ++r) {
        const int row = m0 + wr * (BM / 2) + mi * 16 + fg * 4 + r;
        float val = acc[mi][ni][r] + bv;
        if (GELU_ACT) val = 0.5f * val * (1.0f + erff(val * 0.70710678118f));
        if (HAS_RES)  val += res[(size_t)row * N + col];
        if (OUT_BF16) ((unsigned short*)out)[(size_t)row * N + col] = f2bf(val);
        else          ((float*)out)[(size_t)row * N + col] = val;
      }
    }
  }
}

extern "C" void kernel_launch(void* const* d_in, const int* in_sizes, int n_in,
                              void* d_out, int out_size, void* d_ws, size_t ws_size,
                              hipStream_t stream) {
  const int*   idx   = (const int*)  d_in[0];
  const float* tok_w = (const float*)d_in[1];
  const float* pos_w = (const float*)d_in[2];
  const float* ln1_g = (const float*)d_in[3];
  const float* ln1_b = (const float*)d_in[4];
  const float* wq    = (const float*)d_in[5];
  const float* wk    = (const float*)d_in[6];
  const float* wv    = (const float*)d_in[7];
  const float* wp    = (const float*)d_in[8];
  const float* bp    = (const float*)d_in[9];
  const float* ln2_g = (const float*)d_in[10];
  const float* ln2_b = (const float*)d_in[11];
  const float* w1    = (const float*)d_in[12];
  const float* b1    = (const float*)d_in[13];
  const float* w2    = (const float*)d_in[14];
  const float* b2    = (const float*)d_in[15];
  const float* lnf_g = (const float*)d_in[16];
  const float* lnf_b = (const float*)d_in[17];
  const float* wlm   = (const float*)d_in[18];
  const float* blm   = (const float*)d_in[19];

  const int M = B_BATCH * T_SEQ;  // 2048
  const size_t EE = (size_t)E_DIM * E_DIM;
  char* p = (char*)d_ws;
  float* x            = (float*)p;          p += (size_t)M * E_DIM * 4;
  unsigned short* hb  = (unsigned short*)p; p += (size_t)M * E_DIM * 2;
  unsigned short* qkv = (unsigned short*)p; p += (size_t)M * 3 * E_DIM * 2;
  unsigned short* yb  = (unsigned short*)p; p += (size_t)M * E_DIM * 2;
  unsigned short* tb  = (unsigned short*)p; p += (size_t)M * F_DIM * 2;
  unsigned short* wtb = (unsigned short*)p; p += (size_t)V_VOCAB * E_DIM * 2;

  auto wtrans = [&](const float* W, unsigned short* Wt, int K, int N) {
    wtrans_kernel<<<dim3(N / 64, K / 64), 256, 0, stream>>>(W, Wt, K, N);
  };

  embed_kernel<<<M * E_DIM / 4 / 256, 256, 0, stream>>>(idx, tok_w, pos_w, x);

  dim3 g_a(T_SEQ / 64, B_BATCH * H_HEADS);
  for (int l = 0; l < L_LAYERS; ++l) {
    ln_kernel<<<M, 256, 0, stream>>>(x, ln1_g + (size_t)l * E_DIM, ln1_b + (size_t)l * E_DIM, hb);
    wtrans(wq + l * EE, wtb,          E_DIM, E_DIM);
    wtrans(wk + l * EE, wtb + EE,     E_DIM, E_DIM);
    wtrans(wv + l * EE, wtb + 2 * EE, E_DIM, E_DIM);
    gemm_bt_kernel<128, 128, false, false, false, true>
        <<<dim3(M / 128, 3 * E_DIM / 128), 256, 0, stream>>>(
        hb, wtb, nullptr, nullptr, qkv, M, 3 * E_DIM, E_DIM);
    attn_mfma_kernel<<<g_a, 256, 0, stream>>>(qkv, yb);
    wtrans(wp + l * EE, wtb, E_DIM, E_DIM);
    gemm_bt_kernel<64, 128, true, false, true, false>
        <<<dim3(M / 64, E_DIM / 128), 256, 0, stream>>>(
        yb, wtb, bp + (size_t)l * E_DIM, x, x, M, E_DIM, E_DIM);
    ln_kernel<<<M, 256, 0, stream>>>(x, ln2_g + (size_t)l * E_DIM, ln2_b + (size_t)l * E_DIM, hb);
    wtrans(w1 + (size_t)l * E_DIM * F_DIM, wtb, E_DIM, F_DIM);
    gemm_bt_kernel<128, 128, true, true, false, true>
        <<<dim3(M / 128, F_DIM / 128), 256, 0, stream>>>(
        hb, wtb, b1 + (size_t)l * F_DIM, nullptr, tb, M, F_DIM, E_DIM);
    wtrans(w2 + (size_t)l * F_DIM * E_DIM, wtb, F_DIM, E_DIM);
    gemm_bt_kernel<64, 128, true, false, true, false>
        <<<dim3(M / 64, E_DIM / 128), 256, 0, stream>>>(
        tb, wtb, b2 + (size_t)l * E_DIM, x, x, M, E_DIM, F_DIM);
  }
  ln_kernel<<<M, 256, 0, stream>>>(x, lnf_g, lnf_b, hb);
  wtrans(wlm, wtb, E_DIM, V_VOCAB);
  gemm_bt_kernel<128, 128, true, false, false, false>
      <<<dim3(M / 128, V_VOCAB / 128), 256, 0, stream>>>(
      hb, wtb, blm, nullptr, (float*)d_out, M, V_VOCAB, E_DIM);
}

// Round 5
// 1694.519 us; speedup vs baseline: 6.5451x; 1.0140x over previous
//
#include <hip/hip_runtime.h>

#define T_SEQ   1024
#define E_DIM   1024
#define H_HEADS 16
#define D_HEAD  64
#define L_LAYERS 6
#define B_BATCH 2
#define F_DIM   4096
#define V_VOCAB 32000

typedef float f32x4 __attribute__((ext_vector_type(4)));
typedef short short8 __attribute__((ext_vector_type(8)));

__device__ __forceinline__ unsigned short f2bf(float f) {
  union { float f; unsigned int u; } v; v.f = f;
  unsigned int r = v.u + 0x7fffu + ((v.u >> 16) & 1u);  // RNE
  return (unsigned short)(r >> 16);
}

// async global->LDS, 16B per lane; lds dest = wave-uniform base + lane*16
#define GLDS16(gp, lp) __builtin_amdgcn_global_load_lds( \
    (const __attribute__((address_space(1))) void*)(gp), \
    (__attribute__((address_space(3))) void*)(lp), 16, 0, 0)

// ---------------- embedding: x = tok_w[idx] + pos_w ----------------
__global__ void embed_kernel(const int* __restrict__ idx, const float* __restrict__ tok,
                             const float* __restrict__ pos, float* __restrict__ x) {
  int i = blockIdx.x * 256 + threadIdx.x;
  int bt = i >> 8;
  int e4 = i & 255;
  int t  = bt & (T_SEQ - 1);
  int tokid = idx[bt];
  f32x4 a = *(const f32x4*)(tok + (size_t)tokid * E_DIM + e4 * 4);
  f32x4 p = *(const f32x4*)(pos + (size_t)t * E_DIM + e4 * 4);
  *(f32x4*)(x + (size_t)bt * E_DIM + e4 * 4) = a + p;
}

// ---------------- layernorm (f32 in, bf16 out) ----------------
__global__ void ln_kernel(const float* __restrict__ x, const float* __restrict__ g,
                          const float* __restrict__ b, unsigned short* __restrict__ out) {
  int row = blockIdx.x;
  int tid = threadIdx.x;
  const float* xr = x + (size_t)row * E_DIM;
  f32x4 v = *(const f32x4*)(xr + tid * 4);
  float s  = v[0] + v[1] + v[2] + v[3];
  float s2 = v[0]*v[0] + v[1]*v[1] + v[2]*v[2] + v[3]*v[3];
  #pragma unroll
  for (int off = 32; off > 0; off >>= 1) {
    s  += __shfl_xor(s,  off);
    s2 += __shfl_xor(s2, off);
  }
  __shared__ float red[2][4];
  int wave = tid >> 6;
  if ((tid & 63) == 0) { red[0][wave] = s; red[1][wave] = s2; }
  __syncthreads();
  s  = red[0][0] + red[0][1] + red[0][2] + red[0][3];
  s2 = red[1][0] + red[1][1] + red[1][2] + red[1][3];
  float mean = s * (1.0f / E_DIM);
  float var  = s2 * (1.0f / E_DIM) - mean * mean;
  float rstd = rsqrtf(var + 1e-5f);
  f32x4 gv = *(const f32x4*)(g + tid * 4);
  f32x4 bv = *(const f32x4*)(b + tid * 4);
  ushort4 o;
  o.x = f2bf((v[0] - mean) * rstd * gv[0] + bv[0]);
  o.y = f2bf((v[1] - mean) * rstd * gv[1] + bv[1]);
  o.z = f2bf((v[2] - mean) * rstd * gv[2] + bv[2]);
  o.w = f2bf((v[3] - mean) * rstd * gv[3] + bv[3]);
  *(ushort4*)(out + (size_t)row * E_DIM + tid * 4) = o;
}

// ---------------- weight transpose+convert: W f32 [K][N] -> Wt bf16 [N][K] ----------------
__device__ __forceinline__ void wtrans_body(const float* __restrict__ W,
    unsigned short* __restrict__ Wt, int K, int N, int bx, int by) {
  __shared__ float tile[64][65];
  const int n0 = bx * 64, k0 = by * 64;
  const int tr  = threadIdx.x >> 4;
  const int tc4 = (threadIdx.x & 15) * 4;
  #pragma unroll
  for (int p = 0; p < 4; ++p) {
    f32x4 v = *(const f32x4*)(W + (size_t)(k0 + p * 16 + tr) * N + n0 + tc4);
    tile[p * 16 + tr][tc4 + 0] = v[0];
    tile[p * 16 + tr][tc4 + 1] = v[1];
    tile[p * 16 + tr][tc4 + 2] = v[2];
    tile[p * 16 + tr][tc4 + 3] = v[3];
  }
  __syncthreads();
  #pragma unroll
  for (int p = 0; p < 4; ++p) {
    int n = p * 16 + tr;
    ushort4 o;
    o.x = f2bf(tile[tc4 + 0][n]);
    o.y = f2bf(tile[tc4 + 1][n]);
    o.z = f2bf(tile[tc4 + 2][n]);
    o.w = f2bf(tile[tc4 + 3][n]);
    *(ushort4*)(Wt + (size_t)(n0 + n) * K + k0 + tc4) = o;
  }
}

__global__ __launch_bounds__(256) void wtrans_kernel(const float* __restrict__ W,
    unsigned short* __restrict__ Wt, int K, int N) {
  wtrans_body(W, Wt, K, N, blockIdx.x, blockIdx.y);
}

__global__ __launch_bounds__(256) void wtrans3_kernel(const float* __restrict__ W0,
    const float* __restrict__ W1, const float* __restrict__ W2,
    unsigned short* __restrict__ Wt, int K, int N) {
  const float* W = blockIdx.z == 0 ? W0 : (blockIdx.z == 1 ? W1 : W2);
  wtrans_body(W, Wt + (size_t)blockIdx.z * K * N, K, N, blockIdx.x, blockIdx.y);
}

// ---------------- MFMA flash attention, block-shared K/V LDS staging ----------------
__global__ __launch_bounds__(256) void attn_mfma_kernel(
    const unsigned short* __restrict__ qkv, unsigned short* __restrict__ y) {
  __shared__ __align__(16) unsigned short Kl[32 * 64];
  __shared__ __align__(16) unsigned short Vt[64 * 32];
  __shared__ unsigned short pbuf[4][16][32];
  const int tid  = threadIdx.x;
  const int lane = tid & 63;
  const int wave = tid >> 6;
  const int h  = blockIdx.y & (H_HEADS - 1);
  const int b  = blockIdx.y >> 4;
  const int r0 = blockIdx.x * 64 + wave * 16;
  const size_t RS = 3 * E_DIM;
  const unsigned short* q = qkv + (size_t)b * T_SEQ * RS + (size_t)h * D_HEAD;
  const unsigned short* k = q + E_DIM;
  const unsigned short* v = q + 2 * E_DIM;
  const size_t ybase = (size_t)b * T_SEQ * E_DIM + (size_t)h * D_HEAD;
  const int fr = lane & 15, fg = lane >> 4;
  const int skey = tid >> 3;
  const int schk = tid & 7;

  short8 aq[2];
  #pragma unroll
  for (int c = 0; c < 2; ++c)
    aq[c] = *(const short8*)(q + (size_t)(r0 + fr) * RS + c * 32 + fg * 8);

  f32x4 oacc[4];
  #pragma unroll
  for (int cg = 0; cg < 4; ++cg) oacc[cg] = (f32x4){0.f, 0.f, 0.f, 0.f};
  float m_[4], l_[4];
  #pragma unroll
  for (int r = 0; r < 4; ++r) { m_[r] = -1e30f; l_[r] = 0.0f; }

  const int ntiles = blockIdx.x * 2 + 2;
  for (int t = 0; t < ntiles; ++t) {
    const int j0 = t * 32;
    __syncthreads();
    short8 kv8 = *(const short8*)(k + (size_t)(j0 + skey) * RS + schk * 8);
    *(short8*)((char*)Kl + ((skey * 128 + schk * 16) ^ ((skey & 7) << 4))) = kv8;
    short8 vv8 = *(const short8*)(v + (size_t)(j0 + skey) * RS + schk * 8);
    #pragma unroll
    for (int i = 0; i < 8; ++i) {
      int d = schk * 8 + i;
      *(unsigned short*)((char*)Vt + ((d * 64 + skey * 2) ^ (((d >> 3) & 3) << 4))) =
          (unsigned short)vv8[i];
    }
    __syncthreads();
    if (j0 <= r0 + 15) {
      f32x4 s[2];
      #pragma unroll
      for (int c = 0; c < 2; ++c) {
        const int row = c * 16 + fr;
        short8 bk0 = *(const short8*)((char*)Kl + ((row * 128 + fg * 16)      ^ ((row & 7) << 4)));
        short8 bk1 = *(const short8*)((char*)Kl + ((row * 128 + 64 + fg * 16) ^ ((row & 7) << 4)));
        f32x4 z = (f32x4){0.f, 0.f, 0.f, 0.f};
        z = __builtin_amdgcn_mfma_f32_16x16x32_bf16(aq[0], bk0, z, 0, 0, 0);
        z = __builtin_amdgcn_mfma_f32_16x16x32_bf16(aq[1], bk1, z, 0, 0, 0);
        s[c] = z;
      }
      float cf[4];
      #pragma unroll
      for (int r = 0; r < 4; ++r) {
        const int row = r0 + fg * 4 + r;
        float s0 = (j0 + fr      <= row) ? s[0][r] * 0.125f : -1e30f;
        float s1 = (j0 + 16 + fr <= row) ? s[1][r] * 0.125f : -1e30f;
        float mx = fmaxf(s0, s1);
        mx = fmaxf(mx, __shfl_xor(mx, 1));
        mx = fmaxf(mx, __shfl_xor(mx, 2));
        mx = fmaxf(mx, __shfl_xor(mx, 4));
        mx = fmaxf(mx, __shfl_xor(mx, 8));
        float mn = fmaxf(m_[r], mx);
        cf[r] = __expf(m_[r] - mn);
        float p0 = __expf(s0 - mn), p1 = __expf(s1 - mn);
        float ls = p0 + p1;
        ls += __shfl_xor(ls, 1); ls += __shfl_xor(ls, 2);
        ls += __shfl_xor(ls, 4); ls += __shfl_xor(ls, 8);
        l_[r] = l_[r] * cf[r] + ls;
        m_[r] = mn;
        pbuf[wave][fg * 4 + r][fr]      = f2bf(p0);
        pbuf[wave][fg * 4 + r][16 + fr] = f2bf(p1);
      }
      asm volatile("s_waitcnt lgkmcnt(0)" ::: "memory");
      __builtin_amdgcn_sched_barrier(0);
      short8 pa = *(const short8*)&pbuf[wave][fr][fg * 8];
      #pragma unroll
      for (int cg = 0; cg < 4; ++cg) {
        const int d = cg * 16 + fr;
        short8 bv = *(const short8*)((char*)Vt + ((d * 64 + fg * 16) ^ (((d >> 3) & 3) << 4)));
        #pragma unroll
        for (int r = 0; r < 4; ++r) oacc[cg][r] *= cf[r];
        oacc[cg] = __builtin_amdgcn_mfma_f32_16x16x32_bf16(pa, bv, oacc[cg], 0, 0, 0);
      }
    }
  }
  #pragma unroll
  for (int cg = 0; cg < 4; ++cg)
    #pragma unroll
    for (int r = 0; r < 4; ++r)
      y[ybase + (size_t)(r0 + fg * 4 + r) * E_DIM + cg * 16 + fr] = f2bf(oacc[cg][r] / l_[r]);
}

// ---------------- 128-tile bf16 GEMM (2-barrier m97 structure) ----------------
template<int BM, int BN, bool HAS_BIAS, bool GELU_ACT, bool HAS_RES, bool OUT_BF16>
__global__ __launch_bounds__(256) void gemm_bt_kernel(
    const unsigned short* __restrict__ A, const unsigned short* __restrict__ Bt,
    const float* __restrict__ bias, const float* __restrict__ res,
    void* __restrict__ out, int M, int N, int K) {
  constexpr int BK = 32;
  constexpr int MR = BM / 32;
  constexpr int NR = BN / 32;
  constexpr int ACH = BM / 64;
  constexpr int BCH = BN / 64;
  __shared__ __align__(16) unsigned short As[BM * BK];
  __shared__ __align__(16) unsigned short Bs[BN * BK];
  const int tid  = threadIdx.x;
  const int lane = tid & 63;
  const int wave = tid >> 6;
  const int wr = wave >> 1, wc = wave & 1;
  const int m0 = blockIdx.x * BM, n0 = blockIdx.y * BN;
  const int fr = lane & 15, fg = lane >> 4;

  const int srow  = wave * 16 + (lane >> 2);
  const int skoff = (lane & 3) * 8;
  const unsigned short* aG = A  + (size_t)(m0 + srow) * K + skoff;
  const unsigned short* bG = Bt + (size_t)(n0 + srow) * K + skoff;
  const int ldsoff = wave * 1024;

  f32x4 acc[MR][NR];
  #pragma unroll
  for (int mi = 0; mi < MR; ++mi)
    #pragma unroll
    for (int ni = 0; ni < NR; ++ni) acc[mi][ni] = (f32x4){0.f, 0.f, 0.f, 0.f};

  for (int k0 = 0; k0 < K; k0 += BK) {
    __syncthreads();
    #pragma unroll
    for (int i = 0; i < ACH; ++i)
      GLDS16(aG + (size_t)i * 64 * K + k0, (char*)As + i * 4096 + ldsoff);
    #pragma unroll
    for (int i = 0; i < BCH; ++i)
      GLDS16(bG + (size_t)i * 64 * K + k0, (char*)Bs + i * 4096 + ldsoff);
    __syncthreads();

    short8 af[MR], bf[NR];
    #pragma unroll
    for (int mi = 0; mi < MR; ++mi)
      af[mi] = *(const short8*)&As[(wr * (BM / 2) + mi * 16 + fr) * BK + fg * 8];
    #pragma unroll
    for (int ni = 0; ni < NR; ++ni)
      bf[ni] = *(const short8*)&Bs[(wc * (BN / 2) + ni * 16 + fr) * BK + fg * 8];
    #pragma unroll
    for (int mi = 0; mi < MR; ++mi)
      #pragma unroll
      for (int ni = 0; ni < NR; ++ni)
        acc[mi][ni] = __builtin_amdgcn_mfma_f32_16x16x32_bf16(af[mi], bf[ni], acc[mi][ni], 0, 0, 0);
  }

  #pragma unroll
  for (int mi = 0; mi < MR; ++mi) {
    #pragma unroll
    for (int ni = 0; ni < NR; ++ni) {
      const int col = n0 + wc * (BN / 2) + ni * 16 + fr;
      float bv = HAS_BIAS ? bias[col] : 0.0f;
      #pragma unroll
      for (int r = 0; r < 4; ++r) {
        const int row = m0 + wr * (BM / 2) + mi * 16 + fg * 4 + r;
        float val = acc[mi][ni][r] + bv;
        if (GELU_ACT) val = 0.5f * val * (1.0f + erff(val * 0.70710678118f));
        if (HAS_RES)  val += res[(size_t)row * N + col];
        if (OUT_BF16) ((unsigned short*)out)[(size_t)row * N + col] = f2bf(val);
        else          ((float*)out)[(size_t)row * N + col] = val;
      }
    }
  }
}

// ---------------- 256x256 8-phase bf16 GEMM (T2+T3+T4+T5), C = A@Bt^T + bias ----------------
// 512 thr = 8 waves (2M x 4N), BK=64, 2-tile LDS double buffer (128 KiB),
// row-XOR swizzle col^((row&7)<<4) via pre-swizzled gload_lds source + swizzled ds_read,
// region-granular staging, counted vmcnt(4) gates at phases 3/7.
__global__ __launch_bounds__(512, 1) void gemm8p_kernel(
    const unsigned short* __restrict__ A, const unsigned short* __restrict__ Bt,
    const float* __restrict__ bias, float* __restrict__ out, int M, int N, int K) {
  __shared__ __align__(16) char lds[131072];
  const int tid  = threadIdx.x;
  const int lane = tid & 63;
  const int wv   = tid >> 6;
  const int wm = wv >> 2, wn = wv & 3;
  const int m0 = blockIdx.x * 256, n0 = blockIdx.y * 256;
  const int fr = lane & 15, fg = lane >> 4;
  const size_t K2 = (size_t)K * 2;
  const int nIter = K >> 7;   // 2 K-tiles (BK=64) per iteration

  // swizzled col-parts for fragment reads (k-half 0/1)
  const int csw0 = (fg * 16) ^ ((fr & 7) << 4);
  const int csw1 = (64 + fg * 16) ^ ((fr & 7) << 4);

  // staging lane constants: lane covers LDS row (+lane/8), col byte (lane*16)&127;
  // source col pre-swizzled with ((lane/8)<<4) since dest_row&7 == lane/8.
  const int sc = (lane * 16) & 127;
  const size_t laneoff = (size_t)(lane >> 3) * K2 + (size_t)(sc ^ ((lane >> 3) << 4));
  const char* Asrc = (const char*)(A + (size_t)m0 * K) + (size_t)(wv * 8) * K2 + laneoff;
  const char* Bsrc = (const char*)(Bt + (size_t)n0 * K) + laneoff;

  f32x4 acc[8][4];
  #pragma unroll
  for (int i = 0; i < 8; ++i)
    #pragma unroll
    for (int j = 0; j < 4; ++j) acc[i][j] = (f32x4){0.f, 0.f, 0.f, 0.f};

  // stage one 8KB A-quarter q (rows q*64..+63) of buffer b from K-tile kt
  auto stageA = [&](int b, int q, int kt) {
    GLDS16(Asrc + (size_t)(q * 64) * K2 + (size_t)kt * 128,
           lds + b * 65536 + q * 8192 + wv * 1024);
  };
  // stage half (j=0,1) of the 16KB B eighth-group of parity o
  auto stageB = [&](int b, int j, int o, int kt) {
    const int gw = j * 64 + wv * 8;
    const int rw = ((gw >> 5) << 6) + (gw & 31) + o * 32;
    GLDS16(Bsrc + (size_t)rw * K2 + (size_t)kt * 128,
           lds + b * 65536 + 32768 + rw * 128);
  };

  // prologue: buf0 <- tile0 (Ae,Be,Ao,Bo), buf1 <- tile1 (Ae,Be)
  stageA(0, 0, 0); stageA(0, 2, 0);
  stageB(0, 0, 0, 0); stageB(0, 1, 0, 0);
  stageA(0, 1, 0); stageA(0, 3, 0);
  stageB(0, 0, 1, 0); stageB(0, 1, 1, 0);
  stageA(1, 0, 1); stageA(1, 2, 1);
  stageB(1, 0, 0, 1); stageB(1, 1, 0, 1);
  __builtin_amdgcn_sched_barrier(0);
  asm volatile("s_waitcnt vmcnt(4)" ::: "memory");  // buf0's 8 loads landed
  __builtin_amdgcn_s_barrier();

  for (int i = 0; i < nIter; ++i) {
    const bool last = (i == nIter - 1);
    #pragma unroll
    for (int p = 0; p < 8; ++p) {
      const int b  = p >> 2;
      const int mh = (p & 3) >> 1;
      const int nh = p & 1;
      const char* Ab = lds + b * 65536;
      const char* Bb = Ab + 32768;
      __builtin_amdgcn_sched_barrier(0);
      short8 fa[4][2], fb[2][2];
      #pragma unroll
      for (int j = 0; j < 4; ++j) {
        const int row = wm * 128 + mh * 64 + j * 16 + fr;
        fa[j][0] = *(const short8*)(Ab + row * 128 + csw0);
        fa[j][1] = *(const short8*)(Ab + row * 128 + csw1);
      }
      #pragma unroll
      for (int n = 0; n < 2; ++n) {
        const int row = wn * 64 + nh * 32 + n * 16 + fr;
        fb[n][0] = *(const short8*)(Bb + row * 128 + csw0);
        fb[n][1] = *(const short8*)(Bb + row * 128 + csw1);
      }
      // staging (each region issues exactly one barrier after its last reader)
      if (p == 0) { stageA(1, 1, 2 * i + 1); stageA(1, 3, 2 * i + 1); }
      if (p == 1) { stageB(1, 0, 1, 2 * i + 1); stageB(1, 1, 1, 2 * i + 1); }
      if (!last) {
        if (p == 2) { stageA(0, 0, 2 * i + 2); stageA(0, 2, 2 * i + 2); }
        if (p == 3) { stageB(0, 0, 0, 2 * i + 2); stageB(0, 1, 0, 2 * i + 2); }
        if (p == 4) { stageA(0, 1, 2 * i + 2); stageA(0, 3, 2 * i + 2); }
        if (p == 5) { stageB(0, 0, 1, 2 * i + 2); stageB(0, 1, 1, 2 * i + 2); }
        if (p == 6) { stageA(1, 0, 2 * i + 3); stageA(1, 2, 2 * i + 3); }
        if (p == 7) { stageB(1, 0, 0, 2 * i + 3); stageB(1, 1, 0, 2 * i + 3); }
      }
      __builtin_amdgcn_sched_barrier(0);
      __builtin_amdgcn_s_barrier();
      __builtin_amdgcn_sched_barrier(0);
      __builtin_amdgcn_s_setprio(1);
      #pragma unroll
      for (int j = 0; j < 4; ++j)
        #pragma unroll
        for (int n = 0; n < 2; ++n) {
          acc[mh * 4 + j][nh * 2 + n] = __builtin_amdgcn_mfma_f32_16x16x32_bf16(
              fa[j][0], fb[n][0], acc[mh * 4 + j][nh * 2 + n], 0, 0, 0);
          acc[mh * 4 + j][nh * 2 + n] = __builtin_amdgcn_mfma_f32_16x16x32_bf16(
              fa[j][1], fb[n][1], acc[mh * 4 + j][nh * 2 + n], 0, 0, 0);
        }
      __builtin_amdgcn_s_setprio(0);
      __builtin_amdgcn_sched_barrier(0);
      if (p == 3) {  // gate buf1 (tile 2i+1) before phases 4-7 read it
        if (!last) asm volatile("s_waitcnt vmcnt(4)" ::: "memory");
        else       asm volatile("s_waitcnt vmcnt(0)" ::: "memory");
      }
      if (p == 7 && !last)  // gate buf0 (tile 2i+2) before next iter reads it
        asm volatile("s_waitcnt vmcnt(4)" ::: "memory");
      __builtin_amdgcn_s_barrier();
    }
  }

  #pragma unroll
  for (int mi = 0; mi < 8; ++mi) {
    #pragma unroll
    for (int ni = 0; ni < 4; ++ni) {
      const int col = n0 + wn * 64 + ni * 16 + fr;
      const float bv = bias[col];
      #pragma unroll
      for (int r = 0; r < 4; ++r) {
        const int row = m0 + wm * 128 + mi * 16 + fg * 4 + r;
        out[(size_t)row * N + col] = acc[mi][ni][r] + bv;
      }
    }
  }
}

extern "C" void kernel_launch(void* const* d_in, const int* in_sizes, int n_in,
                              void* d_out, int out_size, void* d_ws, size_t ws_size,
                              hipStream_t stream) {
  const int*   idx   = (const int*)  d_in[0];
  const float* tok_w = (const float*)d_in[1];
  const float* pos_w = (const float*)d_in[2];
  const float* ln1_g = (const float*)d_in[3];
  const float* ln1_b = (const float*)d_in[4];
  const float* wq    = (const float*)d_in[5];
  const float* wk    = (const float*)d_in[6];
  const float* wv    = (const float*)d_in[7];
  const float* wp    = (const float*)d_in[8];
  const float* bp    = (const float*)d_in[9];
  const float* ln2_g = (const float*)d_in[10];
  const float* ln2_b = (const float*)d_in[11];
  const float* w1    = (const float*)d_in[12];
  const float* b1    = (const float*)d_in[13];
  const float* w2    = (const float*)d_in[14];
  const float* b2    = (const float*)d_in[15];
  const float* lnf_g = (const float*)d_in[16];
  const float* lnf_b = (const float*)d_in[17];
  const float* wlm   = (const float*)d_in[18];
  const float* blm   = (const float*)d_in[19];

  const int M = B_BATCH * T_SEQ;  // 2048
  const size_t EE = (size_t)E_DIM * E_DIM;
  char* p = (char*)d_ws;
  float* x            = (float*)p;          p += (size_t)M * E_DIM * 4;
  unsigned short* hb  = (unsigned short*)p; p += (size_t)M * E_DIM * 2;
  unsigned short* qkv = (unsigned short*)p; p += (size_t)M * 3 * E_DIM * 2;
  unsigned short* yb  = (unsigned short*)p; p += (size_t)M * E_DIM * 2;
  unsigned short* tb  = (unsigned short*)p; p += (size_t)M * F_DIM * 2;
  unsigned short* wtb = (unsigned short*)p; p += (size_t)V_VOCAB * E_DIM * 2;

  auto wtrans = [&](const float* W, unsigned short* Wt, int K, int N) {
    wtrans_kernel<<<dim3(N / 64, K / 64), 256, 0, stream>>>(W, Wt, K, N);
  };

  embed_kernel<<<M * E_DIM / 4 / 256, 256, 0, stream>>>(idx, tok_w, pos_w, x);

  dim3 g_a(T_SEQ / 64, B_BATCH * H_HEADS);
  for (int l = 0; l < L_LAYERS; ++l) {
    ln_kernel<<<M, 256, 0, stream>>>(x, ln1_g + (size_t)l * E_DIM, ln1_b + (size_t)l * E_DIM, hb);
    wtrans3_kernel<<<dim3(E_DIM / 64, E_DIM / 64, 3), 256, 0, stream>>>(
        wq + l * EE, wk + l * EE, wv + l * EE, wtb, E_DIM, E_DIM);
    gemm_bt_kernel<128, 128, false, false, false, true>
        <<<dim3(M / 128, 3 * E_DIM / 128), 256, 0, stream>>>(
        hb, wtb, nullptr, nullptr, qkv, M, 3 * E_DIM, E_DIM);
    attn_mfma_kernel<<<g_a, 256, 0, stream>>>(qkv, yb);
    wtrans(wp + l * EE, wtb, E_DIM, E_DIM);
    gemm_bt_kernel<64, 128, true, false, true, false>
        <<<dim3(M / 64, E_DIM / 128), 256, 0, stream>>>(
        yb, wtb, bp + (size_t)l * E_DIM, x, x, M, E_DIM, E_DIM);
    ln_kernel<<<M, 256, 0, stream>>>(x, ln2_g + (size_t)l * E_DIM, ln2_b + (size_t)l * E_DIM, hb);
    wtrans(w1 + (size_t)l * E_DIM * F_DIM, wtb, E_DIM, F_DIM);
    gemm_bt_kernel<128, 128, true, true, false, true>
        <<<dim3(M / 128, F_DIM / 128), 256, 0, stream>>>(
        hb, wtb, b1 + (size_t)l * F_DIM, nullptr, tb, M, F_DIM, E_DIM);
    wtrans(w2 + (size_t)l * F_DIM * E_DIM, wtb, F_DIM, E_DIM);
    gemm_bt_kernel<64, 128, true, false, true, false>
        <<<dim3(M / 64, E_DIM / 128), 256, 0, stream>>>(
        tb, wtb, b2 + (size_t)l * E_DIM, x, x, M, E_DIM, F_DIM);
  }
  ln_kernel<<<M, 256, 0, stream>>>(x, lnf_g, lnf_b, hb);
  wtrans(wlm, wtb, E_DIM, V_VOCAB);
  gemm8p_kernel<<<dim3(M / 256, V_VOCAB / 256), 512, 0, stream>>>(
      hb, wtb, blm, (float*)d_out, M, V_VOCAB, E_DIM);
}

// Round 6
// 1536.511 us; speedup vs baseline: 7.2182x; 1.1028x over previous
//
#include <hip/hip_runtime.h>

#define T_SEQ   1024
#define E_DIM   1024
#define H_HEADS 16
#define D_HEAD  64
#define L_LAYERS 6
#define B_BATCH 2
#define F_DIM   4096
#define V_VOCAB 32000

typedef float f32x4 __attribute__((ext_vector_type(4)));
typedef short short8 __attribute__((ext_vector_type(8)));

__device__ __forceinline__ unsigned short f2bf(float f) {
  union { float f; unsigned int u; } v; v.f = f;
  unsigned int r = v.u + 0x7fffu + ((v.u >> 16) & 1u);  // RNE
  return (unsigned short)(r >> 16);
}

// async global->LDS, 16B per lane; lds dest = wave-uniform base + lane*16
#define GLDS16(gp, lp) __builtin_amdgcn_global_load_lds( \
    (const __attribute__((address_space(1))) void*)(gp), \
    (__attribute__((address_space(3))) void*)(lp), 16, 0, 0)

// ---------------- embedding: x = tok_w[idx] + pos_w ----------------
__global__ void embed_kernel(const int* __restrict__ idx, const float* __restrict__ tok,
                             const float* __restrict__ pos, float* __restrict__ x) {
  int i = blockIdx.x * 256 + threadIdx.x;
  int bt = i >> 8;
  int e4 = i & 255;
  int t  = bt & (T_SEQ - 1);
  int tokid = idx[bt];
  f32x4 a = *(const f32x4*)(tok + (size_t)tokid * E_DIM + e4 * 4);
  f32x4 p = *(const f32x4*)(pos + (size_t)t * E_DIM + e4 * 4);
  *(f32x4*)(x + (size_t)bt * E_DIM + e4 * 4) = a + p;
}

// ---------------- layernorm (f32 in, bf16 out) ----------------
__global__ void ln_kernel(const float* __restrict__ x, const float* __restrict__ g,
                          const float* __restrict__ b, unsigned short* __restrict__ out) {
  int row = blockIdx.x;
  int tid = threadIdx.x;
  const float* xr = x + (size_t)row * E_DIM;
  f32x4 v = *(const f32x4*)(xr + tid * 4);
  float s  = v[0] + v[1] + v[2] + v[3];
  float s2 = v[0]*v[0] + v[1]*v[1] + v[2]*v[2] + v[3]*v[3];
  #pragma unroll
  for (int off = 32; off > 0; off >>= 1) {
    s  += __shfl_xor(s,  off);
    s2 += __shfl_xor(s2, off);
  }
  __shared__ float red[2][4];
  int wave = tid >> 6;
  if ((tid & 63) == 0) { red[0][wave] = s; red[1][wave] = s2; }
  __syncthreads();
  s  = red[0][0] + red[0][1] + red[0][2] + red[0][3];
  s2 = red[1][0] + red[1][1] + red[1][2] + red[1][3];
  float mean = s * (1.0f / E_DIM);
  float var  = s2 * (1.0f / E_DIM) - mean * mean;
  float rstd = rsqrtf(var + 1e-5f);
  f32x4 gv = *(const f32x4*)(g + tid * 4);
  f32x4 bv = *(const f32x4*)(b + tid * 4);
  ushort4 o;
  o.x = f2bf((v[0] - mean) * rstd * gv[0] + bv[0]);
  o.y = f2bf((v[1] - mean) * rstd * gv[1] + bv[1]);
  o.z = f2bf((v[2] - mean) * rstd * gv[2] + bv[2]);
  o.w = f2bf((v[3] - mean) * rstd * gv[3] + bv[3]);
  *(ushort4*)(out + (size_t)row * E_DIM + tid * 4) = o;
}

// ---------------- weight transpose+convert: W f32 [K][N] -> Wt bf16 [N][K] ----------------
__device__ __forceinline__ void wtrans_body(const float* __restrict__ W,
    unsigned short* __restrict__ Wt, int K, int N, int bx, int by) {
  __shared__ float tile[64][65];
  const int n0 = bx * 64, k0 = by * 64;
  const int tr  = threadIdx.x >> 4;
  const int tc4 = (threadIdx.x & 15) * 4;
  #pragma unroll
  for (int p = 0; p < 4; ++p) {
    f32x4 v = *(const f32x4*)(W + (size_t)(k0 + p * 16 + tr) * N + n0 + tc4);
    tile[p * 16 + tr][tc4 + 0] = v[0];
    tile[p * 16 + tr][tc4 + 1] = v[1];
    tile[p * 16 + tr][tc4 + 2] = v[2];
    tile[p * 16 + tr][tc4 + 3] = v[3];
  }
  __syncthreads();
  #pragma unroll
  for (int p = 0; p < 4; ++p) {
    int n = p * 16 + tr;
    ushort4 o;
    o.x = f2bf(tile[tc4 + 0][n]);
    o.y = f2bf(tile[tc4 + 1][n]);
    o.z = f2bf(tile[tc4 + 2][n]);
    o.w = f2bf(tile[tc4 + 3][n]);
    *(ushort4*)(Wt + (size_t)(n0 + n) * K + k0 + tc4) = o;
  }
}

__global__ __launch_bounds__(256) void wtrans_kernel(const float* __restrict__ W,
    unsigned short* __restrict__ Wt, int K, int N) {
  wtrans_body(W, Wt, K, N, blockIdx.x, blockIdx.y);
}

// q,k,v,p all [E][E] -> wtb[z*E*E]
__global__ __launch_bounds__(256) void wtrans4_kernel(const float* __restrict__ W0,
    const float* __restrict__ W1, const float* __restrict__ W2, const float* __restrict__ W3,
    unsigned short* __restrict__ Wt) {
  const float* W = blockIdx.z == 0 ? W0 : (blockIdx.z == 1 ? W1 : (blockIdx.z == 2 ? W2 : W3));
  wtrans_body(W, Wt + (size_t)blockIdx.z * E_DIM * E_DIM, E_DIM, E_DIM,
              blockIdx.x, blockIdx.y);
}

// w1 [E][F] -> Wt1 [F][E]; w2 [F][E] -> Wt2 [E][F]
__global__ __launch_bounds__(256) void wtrans2_kernel(const float* __restrict__ W1,
    const float* __restrict__ W2, unsigned short* __restrict__ Wt1,
    unsigned short* __restrict__ Wt2) {
  const int id = blockIdx.x;
  if (blockIdx.y == 0) wtrans_body(W1, Wt1, E_DIM, F_DIM, id % (F_DIM / 64), id / (F_DIM / 64));
  else                 wtrans_body(W2, Wt2, F_DIM, E_DIM, id % (E_DIM / 64), id / (E_DIM / 64));
}

// ---------------- MFMA flash attention, block-shared K/V LDS staging ----------------
__global__ __launch_bounds__(256) void attn_mfma_kernel(
    const unsigned short* __restrict__ qkv, unsigned short* __restrict__ y) {
  __shared__ __align__(16) unsigned short Kl[32 * 64];
  __shared__ __align__(16) unsigned short Vt[64 * 32];
  __shared__ unsigned short pbuf[4][16][32];
  const int tid  = threadIdx.x;
  const int lane = tid & 63;
  const int wave = tid >> 6;
  const int h  = blockIdx.y & (H_HEADS - 1);
  const int b  = blockIdx.y >> 4;
  const int r0 = blockIdx.x * 64 + wave * 16;
  const size_t RS = 3 * E_DIM;
  const unsigned short* q = qkv + (size_t)b * T_SEQ * RS + (size_t)h * D_HEAD;
  const unsigned short* k = q + E_DIM;
  const unsigned short* v = q + 2 * E_DIM;
  const size_t ybase = (size_t)b * T_SEQ * E_DIM + (size_t)h * D_HEAD;
  const int fr = lane & 15, fg = lane >> 4;
  const int skey = tid >> 3;
  const int schk = tid & 7;

  short8 aq[2];
  #pragma unroll
  for (int c = 0; c < 2; ++c)
    aq[c] = *(const short8*)(q + (size_t)(r0 + fr) * RS + c * 32 + fg * 8);

  f32x4 oacc[4];
  #pragma unroll
  for (int cg = 0; cg < 4; ++cg) oacc[cg] = (f32x4){0.f, 0.f, 0.f, 0.f};
  float m_[4], l_[4];
  #pragma unroll
  for (int r = 0; r < 4; ++r) { m_[r] = -1e30f; l_[r] = 0.0f; }

  const int ntiles = blockIdx.x * 2 + 2;
  for (int t = 0; t < ntiles; ++t) {
    const int j0 = t * 32;
    __syncthreads();
    short8 kv8 = *(const short8*)(k + (size_t)(j0 + skey) * RS + schk * 8);
    *(short8*)((char*)Kl + ((skey * 128 + schk * 16) ^ ((skey & 7) << 4))) = kv8;
    short8 vv8 = *(const short8*)(v + (size_t)(j0 + skey) * RS + schk * 8);
    #pragma unroll
    for (int i = 0; i < 8; ++i) {
      int d = schk * 8 + i;
      *(unsigned short*)((char*)Vt + ((d * 64 + skey * 2) ^ (((d >> 3) & 3) << 4))) =
          (unsigned short)vv8[i];
    }
    __syncthreads();
    if (j0 <= r0 + 15) {
      f32x4 s[2];
      #pragma unroll
      for (int c = 0; c < 2; ++c) {
        const int row = c * 16 + fr;
        short8 bk0 = *(const short8*)((char*)Kl + ((row * 128 + fg * 16)      ^ ((row & 7) << 4)));
        short8 bk1 = *(const short8*)((char*)Kl + ((row * 128 + 64 + fg * 16) ^ ((row & 7) << 4)));
        f32x4 z = (f32x4){0.f, 0.f, 0.f, 0.f};
        z = __builtin_amdgcn_mfma_f32_16x16x32_bf16(aq[0], bk0, z, 0, 0, 0);
        z = __builtin_amdgcn_mfma_f32_16x16x32_bf16(aq[1], bk1, z, 0, 0, 0);
        s[c] = z;
      }
      float cf[4];
      #pragma unroll
      for (int r = 0; r < 4; ++r) {
        const int row = r0 + fg * 4 + r;
        float s0 = (j0 + fr      <= row) ? s[0][r] * 0.125f : -1e30f;
        float s1 = (j0 + 16 + fr <= row) ? s[1][r] * 0.125f : -1e30f;
        float mx = fmaxf(s0, s1);
        mx = fmaxf(mx, __shfl_xor(mx, 1));
        mx = fmaxf(mx, __shfl_xor(mx, 2));
        mx = fmaxf(mx, __shfl_xor(mx, 4));
        mx = fmaxf(mx, __shfl_xor(mx, 8));
        float mn = fmaxf(m_[r], mx);
        cf[r] = __expf(m_[r] - mn);
        float p0 = __expf(s0 - mn), p1 = __expf(s1 - mn);
        float ls = p0 + p1;
        ls += __shfl_xor(ls, 1); ls += __shfl_xor(ls, 2);
        ls += __shfl_xor(ls, 4); ls += __shfl_xor(ls, 8);
        l_[r] = l_[r] * cf[r] + ls;
        m_[r] = mn;
        pbuf[wave][fg * 4 + r][fr]      = f2bf(p0);
        pbuf[wave][fg * 4 + r][16 + fr] = f2bf(p1);
      }
      asm volatile("s_waitcnt lgkmcnt(0)" ::: "memory");
      __builtin_amdgcn_sched_barrier(0);
      short8 pa = *(const short8*)&pbuf[wave][fr][fg * 8];
      #pragma unroll
      for (int cg = 0; cg < 4; ++cg) {
        const int d = cg * 16 + fr;
        short8 bv = *(const short8*)((char*)Vt + ((d * 64 + fg * 16) ^ (((d >> 3) & 3) << 4)));
        #pragma unroll
        for (int r = 0; r < 4; ++r) oacc[cg][r] *= cf[r];
        oacc[cg] = __builtin_amdgcn_mfma_f32_16x16x32_bf16(pa, bv, oacc[cg], 0, 0, 0);
      }
    }
  }
  #pragma unroll
  for (int cg = 0; cg < 4; ++cg)
    #pragma unroll
    for (int r = 0; r < 4; ++r)
      y[ybase + (size_t)(r0 + fg * 4 + r) * E_DIM + cg * 16 + fr] = f2bf(oacc[cg][r] / l_[r]);
}

// ---------------- 128-tile bf16 GEMM, BK=64, source-swizzled LDS, XCD-grouped grid ----------------
// A bf16 [M][K], Bt bf16 [N][K]. 1-D grid (nwg % 8 == 0), m-tile fast within an
// XCD's contiguous range so consecutive blocks on one XCD share the weight tile.
template<int BM, int BN, bool HAS_BIAS, bool GELU_ACT, bool HAS_RES, bool OUT_BF16>
__global__ __launch_bounds__(256) void gemm_bt_kernel(
    const unsigned short* __restrict__ A, const unsigned short* __restrict__ Bt,
    const float* __restrict__ bias, const float* __restrict__ res,
    void* __restrict__ out, int M, int N, int K) {
  constexpr int BK = 64;
  constexpr int MR = BM / 32;
  constexpr int NR = BN / 32;
  constexpr int AI = BM / 32;   // gload issues per wave for A (8 rows each)
  constexpr int BI = BN / 32;
  __shared__ __align__(16) unsigned short As[BM * BK];
  __shared__ __align__(16) unsigned short Bs[BN * BK];
  const int tid  = threadIdx.x;
  const int lane = tid & 63;
  const int wave = tid >> 6;
  const int wr = wave >> 1, wc = wave & 1;

  const int mt = M / BM;
  const int q8 = gridDim.x >> 3;
  const int g  = (blockIdx.x & 7) * q8 + (blockIdx.x >> 3);
  const int m0 = (g % mt) * BM, n0 = (g / mt) * BN;

  const int fr = lane & 15, fg = lane >> 4;
  const int lrow = lane >> 3;                       // 0..7
  const int scol = ((lane & 7) * 16) ^ (lrow << 4); // inverse-swizzled source col
  const size_t K2 = (size_t)K * 2;
  const char* aG = (const char*)A  + (size_t)(m0 + wave * 8 + lrow) * K2 + scol;
  const char* bG = (const char*)Bt + (size_t)(n0 + wave * 8 + lrow) * K2 + scol;

  f32x4 acc[MR][NR];
  #pragma unroll
  for (int mi = 0; mi < MR; ++mi)
    #pragma unroll
    for (int ni = 0; ni < NR; ++ni) acc[mi][ni] = (f32x4){0.f, 0.f, 0.f, 0.f};

  for (int k0 = 0; k0 < K; k0 += BK) {
    __syncthreads();
    #pragma unroll
    for (int i = 0; i < AI; ++i)
      GLDS16(aG + (size_t)i * 32 * K2 + (size_t)k0 * 2, (char*)As + wave * 1024 + i * 4096);
    #pragma unroll
    for (int i = 0; i < BI; ++i)
      GLDS16(bG + (size_t)i * 32 * K2 + (size_t)k0 * 2, (char*)Bs + wave * 1024 + i * 4096);
    __syncthreads();

    short8 af[MR][2], bf[NR][2];
    #pragma unroll
    for (int mi = 0; mi < MR; ++mi) {
      const int row = wr * (BM / 2) + mi * 16 + fr;
      #pragma unroll
      for (int kh = 0; kh < 2; ++kh)
        af[mi][kh] = *(const short8*)((const char*)As + row * 128 +
                       ((kh * 64 + fg * 16) ^ ((row & 7) << 4)));
    }
    #pragma unroll
    for (int ni = 0; ni < NR; ++ni) {
      const int row = wc * (BN / 2) + ni * 16 + fr;
      #pragma unroll
      for (int kh = 0; kh < 2; ++kh)
        bf[ni][kh] = *(const short8*)((const char*)Bs + row * 128 +
                       ((kh * 64 + fg * 16) ^ ((row & 7) << 4)));
    }
    #pragma unroll
    for (int mi = 0; mi < MR; ++mi)
      #pragma unroll
      for (int ni = 0; ni < NR; ++ni) {
        acc[mi][ni] = __builtin_amdgcn_mfma_f32_16x16x32_bf16(af[mi][0], bf[ni][0], acc[mi][ni], 0, 0, 0);
        acc[mi][ni] = __builtin_amdgcn_mfma_f32_16x16x32_bf16(af[mi][1], bf[ni][1], acc[mi][ni], 0, 0, 0);
      }
  }

  #pragma unroll
  for (int mi = 0; mi < MR; ++mi) {
    #pragma unroll
    for (int ni = 0; ni < NR; ++ni) {
      const int col = n0 + wc * (BN / 2) + ni * 16 + fr;
      float bv = HAS_BIAS ? bias[col] : 0.0f;
      #pragma unroll
      for (int r = 0; r < 4; ++r) {
        const int row = m0 + wr * (BM / 2) + mi * 16 + fg * 4 + r;
        float val = acc[mi][ni][r] + bv;
        if (GELU_ACT) val = 0.5f * val * (1.0f + erff(val * 0.70710678118f));
        if (HAS_RES)  val += res[(size_t)row * N + col];
        if (OUT_BF16) ((unsigned short*)out)[(size_t)row * N + col] = f2bf(val);
        else          ((float*)out)[(size_t)row * N + col] = val;
      }
    }
  }
}

// ---------------- 256x256 8-phase bf16 GEMM (T2+T3+T4+T5), XCD-grouped grid ----------------
__global__ __launch_bounds__(512, 1) void gemm8p_kernel(
    const unsigned short* __restrict__ A, const unsigned short* __restrict__ Bt,
    const float* __restrict__ bias, float* __restrict__ out, int M, int N, int K) {
  __shared__ __align__(16) char lds[131072];
  const int tid  = threadIdx.x;
  const int lane = tid & 63;
  const int wv   = tid >> 6;
  const int wm = wv >> 2, wn = wv & 3;

  const int mt = M >> 8;
  const int q8 = gridDim.x >> 3;
  const int g  = (blockIdx.x & 7) * q8 + (blockIdx.x >> 3);
  const int m0 = (g % mt) * 256, n0 = (g / mt) * 256;

  const int fr = lane & 15, fg = lane >> 4;
  const size_t K2 = (size_t)K * 2;
  const int nIter = K >> 7;

  const int csw0 = (fg * 16) ^ ((fr & 7) << 4);
  const int csw1 = (64 + fg * 16) ^ ((fr & 7) << 4);

  const int sc = (lane * 16) & 127;
  const size_t laneoff = (size_t)(lane >> 3) * K2 + (size_t)(sc ^ ((lane >> 3) << 4));
  const char* Asrc = (const char*)(A + (size_t)m0 * K) + (size_t)(wv * 8) * K2 + laneoff;
  const char* Bsrc = (const char*)(Bt + (size_t)n0 * K) + laneoff;

  f32x4 acc[8][4];
  #pragma unroll
  for (int i = 0; i < 8; ++i)
    #pragma unroll
    for (int j = 0; j < 4; ++j) acc[i][j] = (f32x4){0.f, 0.f, 0.f, 0.f};

  auto stageA = [&](int b, int q, int kt) {
    GLDS16(Asrc + (size_t)(q * 64) * K2 + (size_t)kt * 128,
           lds + b * 65536 + q * 8192 + wv * 1024);
  };
  auto stageB = [&](int b, int j, int o, int kt) {
    const int gw = j * 64 + wv * 8;
    const int rw = ((gw >> 5) << 6) + (gw & 31) + o * 32;
    GLDS16(Bsrc + (size_t)rw * K2 + (size_t)kt * 128,
           lds + b * 65536 + 32768 + rw * 128);
  };

  stageA(0, 0, 0); stageA(0, 2, 0);
  stageB(0, 0, 0, 0); stageB(0, 1, 0, 0);
  stageA(0, 1, 0); stageA(0, 3, 0);
  stageB(0, 0, 1, 0); stageB(0, 1, 1, 0);
  stageA(1, 0, 1); stageA(1, 2, 1);
  stageB(1, 0, 0, 1); stageB(1, 1, 0, 1);
  __builtin_amdgcn_sched_barrier(0);
  asm volatile("s_waitcnt vmcnt(4)" ::: "memory");
  __builtin_amdgcn_s_barrier();

  for (int i = 0; i < nIter; ++i) {
    const bool last = (i == nIter - 1);
    #pragma unroll
    for (int p = 0; p < 8; ++p) {
      const int b  = p >> 2;
      const int mh = (p & 3) >> 1;
      const int nh = p & 1;
      const char* Ab = lds + b * 65536;
      const char* Bb = Ab + 32768;
      __builtin_amdgcn_sched_barrier(0);
      short8 fa[4][2], fb[2][2];
      #pragma unroll
      for (int j = 0; j < 4; ++j) {
        const int row = wm * 128 + mh * 64 + j * 16 + fr;
        fa[j][0] = *(const short8*)(Ab + row * 128 + csw0);
        fa[j][1] = *(const short8*)(Ab + row * 128 + csw1);
      }
      #pragma unroll
      for (int n = 0; n < 2; ++n) {
        const int row = wn * 64 + nh * 32 + n * 16 + fr;
        fb[n][0] = *(const short8*)(Bb + row * 128 + csw0);
        fb[n][1] = *(const short8*)(Bb + row * 128 + csw1);
      }
      if (p == 0) { stageA(1, 1, 2 * i + 1); stageA(1, 3, 2 * i + 1); }
      if (p == 1) { stageB(1, 0, 1, 2 * i + 1); stageB(1, 1, 1, 2 * i + 1); }
      if (!last) {
        if (p == 2) { stageA(0, 0, 2 * i + 2); stageA(0, 2, 2 * i + 2); }
        if (p == 3) { stageB(0, 0, 0, 2 * i + 2); stageB(0, 1, 0, 2 * i + 2); }
        if (p == 4) { stageA(0, 1, 2 * i + 2); stageA(0, 3, 2 * i + 2); }
        if (p == 5) { stageB(0, 0, 1, 2 * i + 2); stageB(0, 1, 1, 2 * i + 2); }
        if (p == 6) { stageA(1, 0, 2 * i + 3); stageA(1, 2, 2 * i + 3); }
        if (p == 7) { stageB(1, 0, 0, 2 * i + 3); stageB(1, 1, 0, 2 * i + 3); }
      }
      __builtin_amdgcn_sched_barrier(0);
      __builtin_amdgcn_s_barrier();
      __builtin_amdgcn_sched_barrier(0);
      __builtin_amdgcn_s_setprio(1);
      #pragma unroll
      for (int j = 0; j < 4; ++j)
        #pragma unroll
        for (int n = 0; n < 2; ++n) {
          acc[mh * 4 + j][nh * 2 + n] = __builtin_amdgcn_mfma_f32_16x16x32_bf16(
              fa[j][0], fb[n][0], acc[mh * 4 + j][nh * 2 + n], 0, 0, 0);
          acc[mh * 4 + j][nh * 2 + n] = __builtin_amdgcn_mfma_f32_16x16x32_bf16(
              fa[j][1], fb[n][1], acc[mh * 4 + j][nh * 2 + n], 0, 0, 0);
        }
      __builtin_amdgcn_s_setprio(0);
      __builtin_amdgcn_sched_barrier(0);
      if (p == 3) {
        if (!last) asm volatile("s_waitcnt vmcnt(4)" ::: "memory");
        else       asm volatile("s_waitcnt vmcnt(0)" ::: "memory");
      }
      if (p == 7 && !last)
        asm volatile("s_waitcnt vmcnt(4)" ::: "memory");
      __builtin_amdgcn_s_barrier();
    }
  }

  #pragma unroll
  for (int mi = 0; mi < 8; ++mi) {
    #pragma unroll
    for (int ni = 0; ni < 4; ++ni) {
      const int col = n0 + wn * 64 + ni * 16 + fr;
      const float bv = bias[col];
      #pragma unroll
      for (int r = 0; r < 4; ++r) {
        const int row = m0 + wm * 128 + mi * 16 + fg * 4 + r;
        out[(size_t)row * N + col] = acc[mi][ni][r] + bv;
      }
    }
  }
}

extern "C" void kernel_launch(void* const* d_in, const int* in_sizes, int n_in,
                              void* d_out, int out_size, void* d_ws, size_t ws_size,
                              hipStream_t stream) {
  const int*   idx   = (const int*)  d_in[0];
  const float* tok_w = (const float*)d_in[1];
  const float* pos_w = (const float*)d_in[2];
  const float* ln1_g = (const float*)d_in[3];
  const float* ln1_b = (const float*)d_in[4];
  const float* wq    = (const float*)d_in[5];
  const float* wk    = (const float*)d_in[6];
  const float* wv    = (const float*)d_in[7];
  const float* wp    = (const float*)d_in[8];
  const float* bp    = (const float*)d_in[9];
  const float* ln2_g = (const float*)d_in[10];
  const float* ln2_b = (const float*)d_in[11];
  const float* w1    = (const float*)d_in[12];
  const float* b1    = (const float*)d_in[13];
  const float* w2    = (const float*)d_in[14];
  const float* b2    = (const float*)d_in[15];
  const float* lnf_g = (const float*)d_in[16];
  const float* lnf_b = (const float*)d_in[17];
  const float* wlm   = (const float*)d_in[18];
  const float* blm   = (const float*)d_in[19];

  const int M = B_BATCH * T_SEQ;  // 2048
  const size_t EE = (size_t)E_DIM * E_DIM;
  const size_t EF = (size_t)E_DIM * F_DIM;
  char* p = (char*)d_ws;
  float* x            = (float*)p;          p += (size_t)M * E_DIM * 4;
  unsigned short* hb  = (unsigned short*)p; p += (size_t)M * E_DIM * 2;
  unsigned short* qkv = (unsigned short*)p; p += (size_t)M * 3 * E_DIM * 2;
  unsigned short* yb  = (unsigned short*)p; p += (size_t)M * E_DIM * 2;
  unsigned short* tb  = (unsigned short*)p; p += (size_t)M * F_DIM * 2;
  unsigned short* wtb = (unsigned short*)p; p += (size_t)V_VOCAB * E_DIM * 2;

  embed_kernel<<<M * E_DIM / 4 / 256, 256, 0, stream>>>(idx, tok_w, pos_w, x);

  dim3 g_a(T_SEQ / 64, B_BATCH * H_HEADS);
  for (int l = 0; l < L_LAYERS; ++l) {
    ln_kernel<<<M, 256, 0, stream>>>(x, ln1_g + (size_t)l * E_DIM, ln1_b + (size_t)l * E_DIM, hb);
    // q,k,v,p transposed in one launch: wtb[0..3EE)=qkv, wtb[3EE..4EE)=p
    wtrans4_kernel<<<dim3(E_DIM / 64, E_DIM / 64, 4), 256, 0, stream>>>(
        wq + l * EE, wk + l * EE, wv + l * EE, wp + l * EE, wtb);
    gemm_bt_kernel<128, 128, false, false, false, true>
        <<<(M / 128) * (3 * E_DIM / 128), 256, 0, stream>>>(
        hb, wtb, nullptr, nullptr, qkv, M, 3 * E_DIM, E_DIM);
    attn_mfma_kernel<<<g_a, 256, 0, stream>>>(qkv, yb);
    gemm_bt_kernel<64, 128, true, false, true, false>
        <<<(M / 64) * (E_DIM / 128), 256, 0, stream>>>(
        yb, wtb + 3 * EE, bp + (size_t)l * E_DIM, x, x, M, E_DIM, E_DIM);
    ln_kernel<<<M, 256, 0, stream>>>(x, ln2_g + (size_t)l * E_DIM, ln2_b + (size_t)l * E_DIM, hb);
    wtrans2_kernel<<<dim3(1024, 2), 256, 0, stream>>>(
        w1 + l * EF, w2 + l * EF, wtb, wtb + EF);
    gemm_bt_kernel<128, 128, true, true, false, true>
        <<<(M / 128) * (F_DIM / 128), 256, 0, stream>>>(
        hb, wtb, b1 + (size_t)l * F_DIM, nullptr, tb, M, F_DIM, E_DIM);
    gemm_bt_kernel<64, 128, true, false, true, false>
        <<<(M / 64) * (E_DIM / 128), 256, 0, stream>>>(
        tb, wtb + EF, b2 + (size_t)l * E_DIM, x, x, M, E_DIM, F_DIM);
  }
  ln_kernel<<<M, 256, 0, stream>>>(x, lnf_g, lnf_b, hb);
  wtrans_kernel<<<dim3(V_VOCAB / 64, E_DIM / 64), 256, 0, stream>>>(wlm, wtb, E_DIM, V_VOCAB);
  gemm8p_kernel<<<(M / 256) * (V_VOCAB / 256), 512, 0, stream>>>(
      hb, wtb, blm, (float*)d_out, M, V_VOCAB, E_DIM);
}

// Round 7
// 1404.217 us; speedup vs baseline: 7.8982x; 1.0942x over previous
//
#include <hip/hip_runtime.h>

#define T_SEQ   1024
#define E_DIM   1024
#define H_HEADS 16
#define D_HEAD  64
#define L_LAYERS 6
#define B_BATCH 2
#define F_DIM   4096
#define V_VOCAB 32000

typedef float f32x4 __attribute__((ext_vector_type(4)));
typedef short short8 __attribute__((ext_vector_type(8)));

__device__ __forceinline__ unsigned short f2bf(float f) {
  union { float f; unsigned int u; } v; v.f = f;
  unsigned int r = v.u + 0x7fffu + ((v.u >> 16) & 1u);  // RNE
  return (unsigned short)(r >> 16);
}

// async global->LDS, 16B per lane; lds dest = wave-uniform base + lane*16
#define GLDS16(gp, lp) __builtin_amdgcn_global_load_lds( \
    (const __attribute__((address_space(1))) void*)(gp), \
    (__attribute__((address_space(3))) void*)(lp), 16, 0, 0)

// ---------------- embedding: x = tok_w[idx] + pos_w ----------------
__global__ void embed_kernel(const int* __restrict__ idx, const float* __restrict__ tok,
                             const float* __restrict__ pos, float* __restrict__ x) {
  int i = blockIdx.x * 256 + threadIdx.x;
  int bt = i >> 8;
  int e4 = i & 255;
  int t  = bt & (T_SEQ - 1);
  int tokid = idx[bt];
  f32x4 a = *(const f32x4*)(tok + (size_t)tokid * E_DIM + e4 * 4);
  f32x4 p = *(const f32x4*)(pos + (size_t)t * E_DIM + e4 * 4);
  *(f32x4*)(x + (size_t)bt * E_DIM + e4 * 4) = a + p;
}

// ---------------- layernorm (f32 in, bf16 out) ----------------
__global__ void ln_kernel(const float* __restrict__ x, const float* __restrict__ g,
                          const float* __restrict__ b, unsigned short* __restrict__ out) {
  int row = blockIdx.x;
  int tid = threadIdx.x;
  const float* xr = x + (size_t)row * E_DIM;
  f32x4 v = *(const f32x4*)(xr + tid * 4);
  float s  = v[0] + v[1] + v[2] + v[3];
  float s2 = v[0]*v[0] + v[1]*v[1] + v[2]*v[2] + v[3]*v[3];
  #pragma unroll
  for (int off = 32; off > 0; off >>= 1) {
    s  += __shfl_xor(s,  off);
    s2 += __shfl_xor(s2, off);
  }
  __shared__ float red[2][4];
  int wave = tid >> 6;
  if ((tid & 63) == 0) { red[0][wave] = s; red[1][wave] = s2; }
  __syncthreads();
  s  = red[0][0] + red[0][1] + red[0][2] + red[0][3];
  s2 = red[1][0] + red[1][1] + red[1][2] + red[1][3];
  float mean = s * (1.0f / E_DIM);
  float var  = s2 * (1.0f / E_DIM) - mean * mean;
  float rstd = rsqrtf(var + 1e-5f);
  f32x4 gv = *(const f32x4*)(g + tid * 4);
  f32x4 bv = *(const f32x4*)(b + tid * 4);
  ushort4 o;
  o.x = f2bf((v[0] - mean) * rstd * gv[0] + bv[0]);
  o.y = f2bf((v[1] - mean) * rstd * gv[1] + bv[1]);
  o.z = f2bf((v[2] - mean) * rstd * gv[2] + bv[2]);
  o.w = f2bf((v[3] - mean) * rstd * gv[3] + bv[3]);
  *(ushort4*)(out + (size_t)row * E_DIM + tid * 4) = o;
}

// ---------------- weight transpose+convert: W f32 [K][N] -> Wt bf16 [N][K] ----------------
__device__ __forceinline__ void wtrans_body(const float* __restrict__ W,
    unsigned short* __restrict__ Wt, int K, int N, int bx, int by) {
  __shared__ float tile[64][65];
  const int n0 = bx * 64, k0 = by * 64;
  const int tr  = threadIdx.x >> 4;
  const int tc4 = (threadIdx.x & 15) * 4;
  #pragma unroll
  for (int p = 0; p < 4; ++p) {
    f32x4 v = *(const f32x4*)(W + (size_t)(k0 + p * 16 + tr) * N + n0 + tc4);
    tile[p * 16 + tr][tc4 + 0] = v[0];
    tile[p * 16 + tr][tc4 + 1] = v[1];
    tile[p * 16 + tr][tc4 + 2] = v[2];
    tile[p * 16 + tr][tc4 + 3] = v[3];
  }
  __syncthreads();
  #pragma unroll
  for (int p = 0; p < 4; ++p) {
    int n = p * 16 + tr;
    ushort4 o;
    o.x = f2bf(tile[tc4 + 0][n]);
    o.y = f2bf(tile[tc4 + 1][n]);
    o.z = f2bf(tile[tc4 + 2][n]);
    o.w = f2bf(tile[tc4 + 3][n]);
    *(ushort4*)(Wt + (size_t)(n0 + n) * K + k0 + tc4) = o;
  }
}

__global__ __launch_bounds__(256) void wtrans_kernel(const float* __restrict__ W,
    unsigned short* __restrict__ Wt, int K, int N) {
  wtrans_body(W, Wt, K, N, blockIdx.x, blockIdx.y);
}

__global__ __launch_bounds__(256) void wtrans4_kernel(const float* __restrict__ W0,
    const float* __restrict__ W1, const float* __restrict__ W2, const float* __restrict__ W3,
    unsigned short* __restrict__ Wt) {
  const float* W = blockIdx.z == 0 ? W0 : (blockIdx.z == 1 ? W1 : (blockIdx.z == 2 ? W2 : W3));
  wtrans_body(W, Wt + (size_t)blockIdx.z * E_DIM * E_DIM, E_DIM, E_DIM,
              blockIdx.x, blockIdx.y);
}

__global__ __launch_bounds__(256) void wtrans2_kernel(const float* __restrict__ W1,
    const float* __restrict__ W2, unsigned short* __restrict__ Wt1,
    unsigned short* __restrict__ Wt2) {
  const int id = blockIdx.x;
  if (blockIdx.y == 0) wtrans_body(W1, Wt1, E_DIM, F_DIM, id % (F_DIM / 64), id / (F_DIM / 64));
  else                 wtrans_body(W2, Wt2, F_DIM, E_DIM, id % (E_DIM / 64), id / (E_DIM / 64));
}

// ---------------- MFMA flash attention, swapped QK^T (lane-local softmax) ----------------
// Block = 4 waves, 64 q-rows, one (b,h). KVBLK=64. K staged [key][64d] via
// global_load_lds (inverse-swizzled source); V transposed [d][64keys] reg-staged.
// S^T = mfma(K,Q): lane(fr,fg) holds S[key=c*16+fg*4+r][q=fr] -> softmax per lane,
// 2 shfl_xor per tile. P via padded LDS (144B rows), PV = mfma(P,Vt).
__global__ __launch_bounds__(256) void attn_mfma_kernel(
    const unsigned short* __restrict__ qkv, unsigned short* __restrict__ y) {
  __shared__ __align__(16) unsigned short Kl[64 * 64];      // 8 KB
  __shared__ __align__(16) unsigned short Vt[64 * 64];      // 8 KB
  __shared__ __align__(16) unsigned short pbuf[4][16][72];  // 9 KB, 144B row stride
  const int tid  = threadIdx.x;
  const int lane = tid & 63;
  const int wave = tid >> 6;
  const int h  = blockIdx.y & (H_HEADS - 1);
  const int b  = blockIdx.y >> 4;
  const int r0 = blockIdx.x * 64 + wave * 16;
  const size_t RS = 3 * E_DIM;
  const unsigned short* q = qkv + (size_t)b * T_SEQ * RS + (size_t)h * D_HEAD;
  const unsigned short* k = q + E_DIM;
  const unsigned short* v = q + 2 * E_DIM;
  const size_t ybase = (size_t)b * T_SEQ * E_DIM + (size_t)h * D_HEAD;
  const int fr = lane & 15, fg = lane >> 4;
  const int rsw = (fr & 7) << 4;

  // K staging constants: lane covers row lane/8 (of 8), col (lane&7)*16, source pre-swizzled
  const int krow = lane >> 3;
  const int kcol = ((lane & 7) * 16) ^ ((krow & 7) << 4);

  // Q fragment (B-operand): col=q=fr, k=fg*8+i (chunk c)
  short8 aq[2];
  #pragma unroll
  for (int c = 0; c < 2; ++c)
    aq[c] = *(const short8*)(q + (size_t)(r0 + fr) * RS + c * 32 + fg * 8);

  f32x4 oacc[4];
  #pragma unroll
  for (int cg = 0; cg < 4; ++cg) oacc[cg] = (f32x4){0.f, 0.f, 0.f, 0.f};
  float m_ = -1e30f, l_ = 0.0f;   // softmax state for q-row r0+fr

  char* pb = (char*)pbuf + wave * 16 * 144;
  const int ntiles = blockIdx.x + 1;
  for (int t = 0; t < ntiles; ++t) {
    const int j0 = t * 64;
    __syncthreads();
    // ---- stage K [64][64] swizzled via GLDS (2 calls, rows wave*16..+15) ----
    #pragma unroll
    for (int i = 0; i < 2; ++i) {
      const int row = wave * 16 + i * 8;
      GLDS16((const char*)k + (size_t)(j0 + row + krow) * RS * 2 + kcol,
             (char*)Kl + row * 128);
    }
    // ---- stage V transposed [d][key]: lane=key, wave owns d wave*16..+15 ----
    {
      short8 v0 = *(const short8*)(v + (size_t)(j0 + lane) * RS + wave * 16);
      short8 v1 = *(const short8*)(v + (size_t)(j0 + lane) * RS + wave * 16 + 8);
      #pragma unroll
      for (int i = 0; i < 8; ++i) {
        const int d0 = wave * 16 + i;
        *(unsigned short*)((char*)Vt + ((d0 * 128 + lane * 2) ^ ((d0 & 7) << 4))) =
            (unsigned short)v0[i];
        const int d1 = wave * 16 + 8 + i;
        *(unsigned short*)((char*)Vt + ((d1 * 128 + lane * 2) ^ ((d1 & 7) << 4))) =
            (unsigned short)v1[i];
      }
    }
    __syncthreads();
    // ---- S^T = K @ Q^T: 4 key-subtiles ----
    f32x4 st[4];
    #pragma unroll
    for (int c = 0; c < 4; ++c) {
      const char* kb = (char*)Kl + (c * 16 + fr) * 128;
      short8 ka0 = *(const short8*)(kb + ((fg * 16) ^ rsw));
      short8 ka1 = *(const short8*)(kb + ((64 + fg * 16) ^ rsw));
      f32x4 z = (f32x4){0.f, 0.f, 0.f, 0.f};
      z = __builtin_amdgcn_mfma_f32_16x16x32_bf16(ka0, aq[0], z, 0, 0, 0);
      z = __builtin_amdgcn_mfma_f32_16x16x32_bf16(ka1, aq[1], z, 0, 0, 0);
      st[c] = z;
    }
    // ---- lane-local online softmax (q = r0+fr) ----
    const int qg = r0 + fr;
    float pv[4][4];
    float mx = -1e30f;
    #pragma unroll
    for (int c = 0; c < 4; ++c)
      #pragma unroll
      for (int r = 0; r < 4; ++r) {
        const int kj = j0 + c * 16 + fg * 4 + r;
        float val = (kj <= qg) ? st[c][r] * 0.125f : -1e30f;
        pv[c][r] = val;
        mx = fmaxf(mx, val);
      }
    mx = fmaxf(mx, __shfl_xor(mx, 16));
    mx = fmaxf(mx, __shfl_xor(mx, 32));
    const float mn = fmaxf(m_, mx);
    const float cfs = __expf(m_ - mn);
    float ls = 0.0f;
    #pragma unroll
    for (int c = 0; c < 4; ++c) {
      ushort4 o;
      float e0 = __expf(pv[c][0] - mn), e1 = __expf(pv[c][1] - mn);
      float e2 = __expf(pv[c][2] - mn), e3 = __expf(pv[c][3] - mn);
      ls += (e0 + e1) + (e2 + e3);
      o.x = f2bf(e0); o.y = f2bf(e1); o.z = f2bf(e2); o.w = f2bf(e3);
      *(ushort4*)(pb + fr * 144 + c * 32 + fg * 8) = o;
    }
    ls += __shfl_xor(ls, 16);
    ls += __shfl_xor(ls, 32);
    l_ = l_ * cfs + ls;
    m_ = mn;
    // broadcast cf into O layout (O rows q = fg*4+r)
    float cfO[4];
    #pragma unroll
    for (int r = 0; r < 4; ++r) cfO[r] = __shfl(cfs, (lane & 48) | (fg * 4 + r));
    asm volatile("s_waitcnt lgkmcnt(0)" ::: "memory");
    __builtin_amdgcn_sched_barrier(0);
    // ---- O = O*cf + P @ V ----
    short8 pa0 = *(const short8*)(pb + fr * 144 + fg * 16);
    short8 pa1 = *(const short8*)(pb + fr * 144 + 64 + fg * 16);
    __builtin_amdgcn_s_setprio(1);
    #pragma unroll
    for (int cg = 0; cg < 4; ++cg) {
      const char* vb = (char*)Vt + (cg * 16 + fr) * 128;
      short8 b0 = *(const short8*)(vb + ((fg * 16) ^ rsw));
      short8 b1 = *(const short8*)(vb + ((64 + fg * 16) ^ rsw));
      #pragma unroll
      for (int r = 0; r < 4; ++r) oacc[cg][r] *= cfO[r];
      oacc[cg] = __builtin_amdgcn_mfma_f32_16x16x32_bf16(pa0, b0, oacc[cg], 0, 0, 0);
      oacc[cg] = __builtin_amdgcn_mfma_f32_16x16x32_bf16(pa1, b1, oacc[cg], 0, 0, 0);
    }
    __builtin_amdgcn_s_setprio(0);
  }
  // epilogue: broadcast l into O layout, divide, store
  float lO[4];
  #pragma unroll
  for (int r = 0; r < 4; ++r) lO[r] = __shfl(l_, (lane & 48) | (fg * 4 + r));
  #pragma unroll
  for (int cg = 0; cg < 4; ++cg)
    #pragma unroll
    for (int r = 0; r < 4; ++r)
      y[ybase + (size_t)(r0 + fg * 4 + r) * E_DIM + cg * 16 + fr] = f2bf(oacc[cg][r] / lO[r]);
}

// ---------------- 128-tile bf16 GEMM, BK=64, source-swizzled LDS, XCD-grouped grid ----------------
template<int BM, int BN, bool HAS_BIAS, bool GELU_ACT, bool HAS_RES, bool OUT_BF16>
__global__ __launch_bounds__(256) void gemm_bt_kernel(
    const unsigned short* __restrict__ A, const unsigned short* __restrict__ Bt,
    const float* __restrict__ bias, const float* __restrict__ res,
    void* __restrict__ out, int M, int N, int K) {
  constexpr int BK = 64;
  constexpr int MR = BM / 32;
  constexpr int NR = BN / 32;
  constexpr int AI = BM / 32;
  constexpr int BI = BN / 32;
  __shared__ __align__(16) unsigned short As[BM * BK];
  __shared__ __align__(16) unsigned short Bs[BN * BK];
  const int tid  = threadIdx.x;
  const int lane = tid & 63;
  const int wave = tid >> 6;
  const int wr = wave >> 1, wc = wave & 1;

  const int mt = M / BM;
  const int q8 = gridDim.x >> 3;
  const int g  = (blockIdx.x & 7) * q8 + (blockIdx.x >> 3);
  const int m0 = (g % mt) * BM, n0 = (g / mt) * BN;

  const int fr = lane & 15, fg = lane >> 4;
  const int lrow = lane >> 3;
  const int scol = ((lane & 7) * 16) ^ (lrow << 4);
  const size_t K2 = (size_t)K * 2;
  const char* aG = (const char*)A  + (size_t)(m0 + wave * 8 + lrow) * K2 + scol;
  const char* bG = (const char*)Bt + (size_t)(n0 + wave * 8 + lrow) * K2 + scol;

  f32x4 acc[MR][NR];
  #pragma unroll
  for (int mi = 0; mi < MR; ++mi)
    #pragma unroll
    for (int ni = 0; ni < NR; ++ni) acc[mi][ni] = (f32x4){0.f, 0.f, 0.f, 0.f};

  for (int k0 = 0; k0 < K; k0 += BK) {
    __syncthreads();
    #pragma unroll
    for (int i = 0; i < AI; ++i)
      GLDS16(aG + (size_t)i * 32 * K2 + (size_t)k0 * 2, (char*)As + wave * 1024 + i * 4096);
    #pragma unroll
    for (int i = 0; i < BI; ++i)
      GLDS16(bG + (size_t)i * 32 * K2 + (size_t)k0 * 2, (char*)Bs + wave * 1024 + i * 4096);
    __syncthreads();

    short8 af[MR][2], bf[NR][2];
    #pragma unroll
    for (int mi = 0; mi < MR; ++mi) {
      const int row = wr * (BM / 2) + mi * 16 + fr;
      #pragma unroll
      for (int kh = 0; kh < 2; ++kh)
        af[mi][kh] = *(const short8*)((const char*)As + row * 128 +
                       ((kh * 64 + fg * 16) ^ ((row & 7) << 4)));
    }
    #pragma unroll
    for (int ni = 0; ni < NR; ++ni) {
      const int row = wc * (BN / 2) + ni * 16 + fr;
      #pragma unroll
      for (int kh = 0; kh < 2; ++kh)
        bf[ni][kh] = *(const short8*)((const char*)Bs + row * 128 +
                       ((kh * 64 + fg * 16) ^ ((row & 7) << 4)));
    }
    #pragma unroll
    for (int mi = 0; mi < MR; ++mi)
      #pragma unroll
      for (int ni = 0; ni < NR; ++ni) {
        acc[mi][ni] = __builtin_amdgcn_mfma_f32_16x16x32_bf16(af[mi][0], bf[ni][0], acc[mi][ni], 0, 0, 0);
        acc[mi][ni] = __builtin_amdgcn_mfma_f32_16x16x32_bf16(af[mi][1], bf[ni][1], acc[mi][ni], 0, 0, 0);
      }
  }

  #pragma unroll
  for (int mi = 0; mi < MR; ++mi) {
    #pragma unroll
    for (int ni = 0; ni < NR; ++ni) {
      const int col = n0 + wc * (BN / 2) + ni * 16 + fr;
      float bv = HAS_BIAS ? bias[col] : 0.0f;
      #pragma unroll
      for (int r = 0; r < 4; ++r) {
        const int row = m0 + wr * (BM / 2) + mi * 16 + fg * 4 + r;
        float val = acc[mi][ni][r] + bv;
        if (GELU_ACT) val = 0.5f * val * (1.0f + erff(val * 0.70710678118f));
        if (HAS_RES)  val += res[(size_t)row * N + col];
        if (OUT_BF16) ((unsigned short*)out)[(size_t)row * N + col] = f2bf(val);
        else          ((float*)out)[(size_t)row * N + col] = val;
      }
    }
  }
}

// ---------------- 256x256 8-phase bf16 GEMM (T2+T3+T4+T5 + A-reuse), XCD-grouped ----------------
__global__ __launch_bounds__(512, 1) void gemm8p_kernel(
    const unsigned short* __restrict__ A, const unsigned short* __restrict__ Bt,
    const float* __restrict__ bias, float* __restrict__ out, int M, int N, int K) {
  __shared__ __align__(16) char lds[131072];
  const int tid  = threadIdx.x;
  const int lane = tid & 63;
  const int wv   = tid >> 6;
  const int wm = wv >> 2, wn = wv & 3;

  const int mt = M >> 8;
  const int q8 = gridDim.x >> 3;
  const int g  = (blockIdx.x & 7) * q8 + (blockIdx.x >> 3);
  const int m0 = (g % mt) * 256, n0 = (g / mt) * 256;

  const int fr = lane & 15, fg = lane >> 4;
  const size_t K2 = (size_t)K * 2;
  const int nIter = K >> 7;

  const int csw0 = (fg * 16) ^ ((fr & 7) << 4);
  const int csw1 = (64 + fg * 16) ^ ((fr & 7) << 4);

  const int sc = (lane * 16) & 127;
  const size_t laneoff = (size_t)(lane >> 3) * K2 + (size_t)(sc ^ ((lane >> 3) << 4));
  const char* Asrc = (const char*)(A + (size_t)m0 * K) + (size_t)(wv * 8) * K2 + laneoff;
  const char* Bsrc = (const char*)(Bt + (size_t)n0 * K) + laneoff;

  f32x4 acc[8][4];
  #pragma unroll
  for (int i = 0; i < 8; ++i)
    #pragma unroll
    for (int j = 0; j < 4; ++j) acc[i][j] = (f32x4){0.f, 0.f, 0.f, 0.f};

  auto stageA = [&](int b, int q, int kt) {
    GLDS16(Asrc + (size_t)(q * 64) * K2 + (size_t)kt * 128,
           lds + b * 65536 + q * 8192 + wv * 1024);
  };
  auto stageB = [&](int b, int j, int o, int kt) {
    const int gw = j * 64 + wv * 8;
    const int rw = ((gw >> 5) << 6) + (gw & 31) + o * 32;
    GLDS16(Bsrc + (size_t)rw * K2 + (size_t)kt * 128,
           lds + b * 65536 + 32768 + rw * 128);
  };

  stageA(0, 0, 0); stageA(0, 2, 0);
  stageB(0, 0, 0, 0); stageB(0, 1, 0, 0);
  stageA(0, 1, 0); stageA(0, 3, 0);
  stageB(0, 0, 1, 0); stageB(0, 1, 1, 0);
  stageA(1, 0, 1); stageA(1, 2, 1);
  stageB(1, 0, 0, 1); stageB(1, 1, 0, 1);
  __builtin_amdgcn_sched_barrier(0);
  asm volatile("s_waitcnt vmcnt(4)" ::: "memory");
  __builtin_amdgcn_s_barrier();

  for (int i = 0; i < nIter; ++i) {
    const bool last = (i == nIter - 1);
    short8 fa[4][2];
    #pragma unroll
    for (int p = 0; p < 8; ++p) {
      const int b  = p >> 2;
      const int mh = (p & 3) >> 1;
      const int nh = p & 1;
      const char* Ab = lds + b * 65536;
      const char* Bb = Ab + 32768;
      __builtin_amdgcn_sched_barrier(0);
      if (nh == 0) {   // A-frags shared by the (nh=0, nh=1) phase pair
        #pragma unroll
        for (int j = 0; j < 4; ++j) {
          const int row = wm * 128 + mh * 64 + j * 16 + fr;
          fa[j][0] = *(const short8*)(Ab + row * 128 + csw0);
          fa[j][1] = *(const short8*)(Ab + row * 128 + csw1);
        }
      }
      short8 fb[2][2];
      #pragma unroll
      for (int n = 0; n < 2; ++n) {
        const int row = wn * 64 + nh * 32 + n * 16 + fr;
        fb[n][0] = *(const short8*)(Bb + row * 128 + csw0);
        fb[n][1] = *(const short8*)(Bb + row * 128 + csw1);
      }
      if (p == 0) { stageA(1, 1, 2 * i + 1); stageA(1, 3, 2 * i + 1); }
      if (p == 1) { stageB(1, 0, 1, 2 * i + 1); stageB(1, 1, 1, 2 * i + 1); }
      if (!last) {
        if (p == 2) { stageA(0, 0, 2 * i + 2); stageA(0, 2, 2 * i + 2); }
        if (p == 3) { stageB(0, 0, 0, 2 * i + 2); stageB(0, 1, 0, 2 * i + 2); }
        if (p == 4) { stageA(0, 1, 2 * i + 2); stageA(0, 3, 2 * i + 2); }
        if (p == 5) { stageB(0, 0, 1, 2 * i + 2); stageB(0, 1, 1, 2 * i + 2); }
        if (p == 6) { stageA(1, 0, 2 * i + 3); stageA(1, 2, 2 * i + 3); }
        if (p == 7) { stageB(1, 0, 0, 2 * i + 3); stageB(1, 1, 0, 2 * i + 3); }
      }
      __builtin_amdgcn_sched_barrier(0);
      __builtin_amdgcn_s_barrier();
      __builtin_amdgcn_sched_barrier(0);
      __builtin_amdgcn_s_setprio(1);
      #pragma unroll
      for (int j = 0; j < 4; ++j)
        #pragma unroll
        for (int n = 0; n < 2; ++n) {
          acc[mh * 4 + j][nh * 2 + n] = __builtin_amdgcn_mfma_f32_16x16x32_bf16(
              fa[j][0], fb[n][0], acc[mh * 4 + j][nh * 2 + n], 0, 0, 0);
          acc[mh * 4 + j][nh * 2 + n] = __builtin_amdgcn_mfma_f32_16x16x32_bf16(
              fa[j][1], fb[n][1], acc[mh * 4 + j][nh * 2 + n], 0, 0, 0);
        }
      __builtin_amdgcn_s_setprio(0);
      __builtin_amdgcn_sched_barrier(0);
      if (p == 3) {
        if (!last) asm volatile("s_waitcnt vmcnt(4)" ::: "memory");
        else       asm volatile("s_waitcnt vmcnt(0)" ::: "memory");
      }
      if (p == 7 && !last)
        asm volatile("s_waitcnt vmcnt(4)" ::: "memory");
      __builtin_amdgcn_s_barrier();
    }
  }

  #pragma unroll
  for (int mi = 0; mi < 8; ++mi) {
    #pragma unroll
    for (int ni = 0; ni < 4; ++ni) {
      const int col = n0 + wn * 64 + ni * 16 + fr;
      const float bv = bias[col];
      #pragma unroll
      for (int r = 0; r < 4; ++r) {
        const int row = m0 + wm * 128 + mi * 16 + fg * 4 + r;
        out[(size_t)row * N + col] = acc[mi][ni][r] + bv;
      }
    }
  }
}

extern "C" void kernel_launch(void* const* d_in, const int* in_sizes, int n_in,
                              void* d_out, int out_size, void* d_ws, size_t ws_size,
                              hipStream_t stream) {
  const int*   idx   = (const int*)  d_in[0];
  const float* tok_w = (const float*)d_in[1];
  const float* pos_w = (const float*)d_in[2];
  const float* ln1_g = (const float*)d_in[3];
  const float* ln1_b = (const float*)d_in[4];
  const float* wq    = (const float*)d_in[5];
  const float* wk    = (const float*)d_in[6];
  const float* wv    = (const float*)d_in[7];
  const float* wp    = (const float*)d_in[8];
  const float* bp    = (const float*)d_in[9];
  const float* ln2_g = (const float*)d_in[10];
  const float* ln2_b = (const float*)d_in[11];
  const float* w1    = (const float*)d_in[12];
  const float* b1    = (const float*)d_in[13];
  const float* w2    = (const float*)d_in[14];
  const float* b2    = (const float*)d_in[15];
  const float* lnf_g = (const float*)d_in[16];
  const float* lnf_b = (const float*)d_in[17];
  const float* wlm   = (const float*)d_in[18];
  const float* blm   = (const float*)d_in[19];

  const int M = B_BATCH * T_SEQ;  // 2048
  const size_t EE = (size_t)E_DIM * E_DIM;
  const size_t EF = (size_t)E_DIM * F_DIM;
  char* p = (char*)d_ws;
  float* x            = (float*)p;          p += (size_t)M * E_DIM * 4;
  unsigned short* hb  = (unsigned short*)p; p += (size_t)M * E_DIM * 2;
  unsigned short* qkv = (unsigned short*)p; p += (size_t)M * 3 * E_DIM * 2;
  unsigned short* yb  = (unsigned short*)p; p += (size_t)M * E_DIM * 2;
  unsigned short* tb  = (unsigned short*)p; p += (size_t)M * F_DIM * 2;
  unsigned short* wtb = (unsigned short*)p; p += (size_t)V_VOCAB * E_DIM * 2;

  embed_kernel<<<M * E_DIM / 4 / 256, 256, 0, stream>>>(idx, tok_w, pos_w, x);

  dim3 g_a(T_SEQ / 64, B_BATCH * H_HEADS);
  for (int l = 0; l < L_LAYERS; ++l) {
    ln_kernel<<<M, 256, 0, stream>>>(x, ln1_g + (size_t)l * E_DIM, ln1_b + (size_t)l * E_DIM, hb);
    wtrans4_kernel<<<dim3(E_DIM / 64, E_DIM / 64, 4), 256, 0, stream>>>(
        wq + l * EE, wk + l * EE, wv + l * EE, wp + l * EE, wtb);
    gemm_bt_kernel<128, 128, false, false, false, true>
        <<<(M / 128) * (3 * E_DIM / 128), 256, 0, stream>>>(
        hb, wtb, nullptr, nullptr, qkv, M, 3 * E_DIM, E_DIM);
    attn_mfma_kernel<<<g_a, 256, 0, stream>>>(qkv, yb);
    gemm_bt_kernel<64, 128, true, false, true, false>
        <<<(M / 64) * (E_DIM / 128), 256, 0, stream>>>(
        yb, wtb + 3 * EE, bp + (size_t)l * E_DIM, x, x, M, E_DIM, E_DIM);
    ln_kernel<<<M, 256, 0, stream>>>(x, ln2_g + (size_t)l * E_DIM, ln2_b + (size_t)l * E_DIM, hb);
    wtrans2_kernel<<<dim3(1024, 2), 256, 0, stream>>>(
        w1 + l * EF, w2 + l * EF, wtb, wtb + EF);
    gemm_bt_kernel<128, 128, true, true, false, true>
        <<<(M / 128) * (F_DIM / 128), 256, 0, stream>>>(
        hb, wtb, b1 + (size_t)l * F_DIM, nullptr, tb, M, F_DIM, E_DIM);
    gemm_bt_kernel<64, 128, true, false, true, false>
        <<<(M / 64) * (E_DIM / 128), 256, 0, stream>>>(
        tb, wtb + EF, b2 + (size_t)l * E_DIM, x, x, M, E_DIM, F_DIM);
  }
  ln_kernel<<<M, 256, 0, stream>>>(x, lnf_g, lnf_b, hb);
  wtrans_kernel<<<dim3(V_VOCAB / 64, E_DIM / 64), 256, 0, stream>>>(wlm, wtb, E_DIM, V_VOCAB);
  gemm8p_kernel<<<(M / 256) * (V_VOCAB / 256), 512, 0, stream>>>(
      hb, wtb, blm, (float*)d_out, M, V_VOCAB, E_DIM);
}

// Round 8
// 1356.559 us; speedup vs baseline: 8.1757x; 1.0351x over previous
//
#include <hip/hip_runtime.h>

#define T_SEQ   1024
#define E_DIM   1024
#define H_HEADS 16
#define D_HEAD  64
#define L_LAYERS 6
#define B_BATCH 2
#define F_DIM   4096
#define V_VOCAB 32000

typedef float f32x4 __attribute__((ext_vector_type(4)));
typedef short short8 __attribute__((ext_vector_type(8)));

__device__ __forceinline__ unsigned short f2bf(float f) {
  union { float f; unsigned int u; } v; v.f = f;
  unsigned int r = v.u + 0x7fffu + ((v.u >> 16) & 1u);  // RNE
  return (unsigned short)(r >> 16);
}

// async global->LDS, 16B per lane; lds dest = wave-uniform base + lane*16
#define GLDS16(gp, lp) __builtin_amdgcn_global_load_lds( \
    (const __attribute__((address_space(1))) void*)(gp), \
    (__attribute__((address_space(3))) void*)(lp), 16, 0, 0)

// ---------------- embedding: x = tok_w[idx] + pos_w ----------------
__global__ void embed_kernel(const int* __restrict__ idx, const float* __restrict__ tok,
                             const float* __restrict__ pos, float* __restrict__ x) {
  int i = blockIdx.x * 256 + threadIdx.x;
  int bt = i >> 8;
  int e4 = i & 255;
  int t  = bt & (T_SEQ - 1);
  int tokid = idx[bt];
  f32x4 a = *(const f32x4*)(tok + (size_t)tokid * E_DIM + e4 * 4);
  f32x4 p = *(const f32x4*)(pos + (size_t)t * E_DIM + e4 * 4);
  *(f32x4*)(x + (size_t)bt * E_DIM + e4 * 4) = a + p;
}

// ---------------- layernorm (f32 in, bf16 out) ----------------
__global__ void ln_kernel(const float* __restrict__ x, const float* __restrict__ g,
                          const float* __restrict__ b, unsigned short* __restrict__ out) {
  int row = blockIdx.x;
  int tid = threadIdx.x;
  const float* xr = x + (size_t)row * E_DIM;
  f32x4 v = *(const f32x4*)(xr + tid * 4);
  float s  = v[0] + v[1] + v[2] + v[3];
  float s2 = v[0]*v[0] + v[1]*v[1] + v[2]*v[2] + v[3]*v[3];
  #pragma unroll
  for (int off = 32; off > 0; off >>= 1) {
    s  += __shfl_xor(s,  off);
    s2 += __shfl_xor(s2, off);
  }
  __shared__ float red[2][4];
  int wave = tid >> 6;
  if ((tid & 63) == 0) { red[0][wave] = s; red[1][wave] = s2; }
  __syncthreads();
  s  = red[0][0] + red[0][1] + red[0][2] + red[0][3];
  s2 = red[1][0] + red[1][1] + red[1][2] + red[1][3];
  float mean = s * (1.0f / E_DIM);
  float var  = s2 * (1.0f / E_DIM) - mean * mean;
  float rstd = rsqrtf(var + 1e-5f);
  f32x4 gv = *(const f32x4*)(g + tid * 4);
  f32x4 bv = *(const f32x4*)(b + tid * 4);
  ushort4 o;
  o.x = f2bf((v[0] - mean) * rstd * gv[0] + bv[0]);
  o.y = f2bf((v[1] - mean) * rstd * gv[1] + bv[1]);
  o.z = f2bf((v[2] - mean) * rstd * gv[2] + bv[2]);
  o.w = f2bf((v[3] - mean) * rstd * gv[3] + bv[3]);
  *(ushort4*)(out + (size_t)row * E_DIM + tid * 4) = o;
}

// ---------------- weight transpose+convert: W f32 [K][N] -> Wt bf16 [N][K] ----------------
__device__ __forceinline__ void wtrans_body(const float* __restrict__ W,
    unsigned short* __restrict__ Wt, int K, int N, int bx, int by) {
  __shared__ float tile[64][65];
  const int n0 = bx * 64, k0 = by * 64;
  const int tr  = threadIdx.x >> 4;
  const int tc4 = (threadIdx.x & 15) * 4;
  #pragma unroll
  for (int p = 0; p < 4; ++p) {
    f32x4 v = *(const f32x4*)(W + (size_t)(k0 + p * 16 + tr) * N + n0 + tc4);
    tile[p * 16 + tr][tc4 + 0] = v[0];
    tile[p * 16 + tr][tc4 + 1] = v[1];
    tile[p * 16 + tr][tc4 + 2] = v[2];
    tile[p * 16 + tr][tc4 + 3] = v[3];
  }
  __syncthreads();
  #pragma unroll
  for (int p = 0; p < 4; ++p) {
    int n = p * 16 + tr;
    ushort4 o;
    o.x = f2bf(tile[tc4 + 0][n]);
    o.y = f2bf(tile[tc4 + 1][n]);
    o.z = f2bf(tile[tc4 + 2][n]);
    o.w = f2bf(tile[tc4 + 3][n]);
    *(ushort4*)(Wt + (size_t)(n0 + n) * K + k0 + tc4) = o;
  }
}

__global__ __launch_bounds__(256) void wtrans_kernel(const float* __restrict__ W,
    unsigned short* __restrict__ Wt, int K, int N) {
  wtrans_body(W, Wt, K, N, blockIdx.x, blockIdx.y);
}

__global__ __launch_bounds__(256) void wtrans4_kernel(const float* __restrict__ W0,
    const float* __restrict__ W1, const float* __restrict__ W2, const float* __restrict__ W3,
    unsigned short* __restrict__ Wt) {
  const float* W = blockIdx.z == 0 ? W0 : (blockIdx.z == 1 ? W1 : (blockIdx.z == 2 ? W2 : W3));
  wtrans_body(W, Wt + (size_t)blockIdx.z * E_DIM * E_DIM, E_DIM, E_DIM,
              blockIdx.x, blockIdx.y);
}

__global__ __launch_bounds__(256) void wtrans2_kernel(const float* __restrict__ W1,
    const float* __restrict__ W2, unsigned short* __restrict__ Wt1,
    unsigned short* __restrict__ Wt2) {
  const int id = blockIdx.x;
  if (blockIdx.y == 0) wtrans_body(W1, Wt1, E_DIM, F_DIM, id % (F_DIM / 64), id / (F_DIM / 64));
  else                 wtrans_body(W2, Wt2, F_DIM, E_DIM, id % (E_DIM / 64), id / (E_DIM / 64));
}

// ---------------- MFMA flash attention, causal-paired, GLDS K/V staging ----------------
// Block = 8 waves (512 thr). Waves 0-3 own q-tile (15-bx), waves 4-7 own q-tile bx
// -> every block does exactly 17 tile-wave units (perfect causal balance).
// K [key][64d] and V^T [d][64key] both staged via global_load_lds with
// inverse-swizzled sources (V is pre-transposed by the QKV GEMM epilogue).
// Swapped QK^T: lane owns one q-row's softmax state (2 shfl_xor per tile).
__global__ __launch_bounds__(512) void attn_mfma_kernel(
    const unsigned short* __restrict__ qk, const unsigned short* __restrict__ vt,
    unsigned short* __restrict__ y) {
  __shared__ __align__(16) unsigned short Kl[64 * 64];      // 8 KB
  __shared__ __align__(16) unsigned short Vl[64 * 64];      // 8 KB
  __shared__ __align__(16) unsigned short pbuf[8][16][72];  // 18 KB
  const int tid  = threadIdx.x;
  const int lane = tid & 63;
  const int wave = tid >> 6;          // 0..7
  const int grp  = wave >> 2;         // 0 = hi q-tile, 1 = lo q-tile
  const int wl   = wave & 3;
  const int bx = blockIdx.x;          // 0..7
  const int h  = blockIdx.y & (H_HEADS - 1);
  const int b  = blockIdx.y >> 4;
  const int qt = grp == 0 ? (15 - bx) : bx;
  const int r0 = qt * 64 + wl * 16;
  const size_t RS = 2 * E_DIM;
  const unsigned short* q = qk + (size_t)b * T_SEQ * RS + (size_t)h * D_HEAD;
  const unsigned short* k = q + E_DIM;
  const unsigned short* vb = vt + (size_t)(b * H_HEADS + h) * D_HEAD * T_SEQ; // [d][t]
  const size_t ybase = (size_t)b * T_SEQ * E_DIM + (size_t)h * D_HEAD;
  const int fr = lane & 15, fg = lane >> 4;
  const int rsw = (fr & 7) << 4;
  const int srow = lane >> 3;                          // 0..7
  const int ssw  = ((lane & 7) * 16) ^ (srow << 4);    // inverse-swizzled source col

  short8 aq[2];
  #pragma unroll
  for (int c = 0; c < 2; ++c)
    aq[c] = *(const short8*)(q + (size_t)(r0 + fr) * RS + c * 32 + fg * 8);

  f32x4 oacc[4];
  #pragma unroll
  for (int cg = 0; cg < 4; ++cg) oacc[cg] = (f32x4){0.f, 0.f, 0.f, 0.f};
  float m_ = -1e30f, l_ = 0.0f;   // softmax state for q-row r0+fr

  char* pb = (char*)pbuf + wave * 16 * 144;
  const int ntiles = 16 - bx;
  for (int t = 0; t < ntiles; ++t) {
    const int j0 = t * 64;
    __syncthreads();
    // stage K rows wave*8..+7 (keys), V rows wave*8..+7 (dims)
    GLDS16((const char*)k + (size_t)(j0 + wave * 8 + srow) * RS * 2 + ssw,
           (char*)Kl + wave * 8 * 128);
    GLDS16((const char*)vb + ((size_t)(wave * 8 + srow) * T_SEQ + j0) * 2 + ssw,
           (char*)Vl + wave * 8 * 128);
    __syncthreads();
    if (t <= qt) {
      // ---- S^T = K @ Q^T ----
      f32x4 st[4];
      #pragma unroll
      for (int c = 0; c < 4; ++c) {
        const char* kb = (char*)Kl + (c * 16 + fr) * 128;
        short8 ka0 = *(const short8*)(kb + ((fg * 16) ^ rsw));
        short8 ka1 = *(const short8*)(kb + ((64 + fg * 16) ^ rsw));
        f32x4 z = (f32x4){0.f, 0.f, 0.f, 0.f};
        z = __builtin_amdgcn_mfma_f32_16x16x32_bf16(ka0, aq[0], z, 0, 0, 0);
        z = __builtin_amdgcn_mfma_f32_16x16x32_bf16(ka1, aq[1], z, 0, 0, 0);
        st[c] = z;
      }
      // ---- lane-local online softmax (q = r0+fr) ----
      const int qg = r0 + fr;
      float pv[4][4];
      float mx = -1e30f;
      #pragma unroll
      for (int c = 0; c < 4; ++c)
        #pragma unroll
        for (int r = 0; r < 4; ++r) {
          const int kj = j0 + c * 16 + fg * 4 + r;
          float val = (kj <= qg) ? st[c][r] * 0.125f : -1e30f;
          pv[c][r] = val;
          mx = fmaxf(mx, val);
        }
      mx = fmaxf(mx, __shfl_xor(mx, 16));
      mx = fmaxf(mx, __shfl_xor(mx, 32));
      const float mn = fmaxf(m_, mx);
      const float cfs = __expf(m_ - mn);
      float ls = 0.0f;
      #pragma unroll
      for (int c = 0; c < 4; ++c) {
        ushort4 o;
        float e0 = __expf(pv[c][0] - mn), e1 = __expf(pv[c][1] - mn);
        float e2 = __expf(pv[c][2] - mn), e3 = __expf(pv[c][3] - mn);
        ls += (e0 + e1) + (e2 + e3);
        o.x = f2bf(e0); o.y = f2bf(e1); o.z = f2bf(e2); o.w = f2bf(e3);
        *(ushort4*)(pb + fr * 144 + c * 32 + fg * 8) = o;
      }
      ls += __shfl_xor(ls, 16);
      ls += __shfl_xor(ls, 32);
      l_ = l_ * cfs + ls;
      m_ = mn;
      float cfO[4];
      #pragma unroll
      for (int r = 0; r < 4; ++r) cfO[r] = __shfl(cfs, (lane & 48) | (fg * 4 + r));
      asm volatile("s_waitcnt lgkmcnt(0)" ::: "memory");
      __builtin_amdgcn_sched_barrier(0);
      // ---- O = O*cf + P @ V ----
      short8 pa0 = *(const short8*)(pb + fr * 144 + fg * 16);
      short8 pa1 = *(const short8*)(pb + fr * 144 + 64 + fg * 16);
      __builtin_amdgcn_s_setprio(1);
      #pragma unroll
      for (int cg = 0; cg < 4; ++cg) {
        const char* vv = (char*)Vl + (cg * 16 + fr) * 128;
        short8 b0 = *(const short8*)(vv + ((fg * 16) ^ rsw));
        short8 b1 = *(const short8*)(vv + ((64 + fg * 16) ^ rsw));
        #pragma unroll
        for (int r = 0; r < 4; ++r) oacc[cg][r] *= cfO[r];
        oacc[cg] = __builtin_amdgcn_mfma_f32_16x16x32_bf16(pa0, b0, oacc[cg], 0, 0, 0);
        oacc[cg] = __builtin_amdgcn_mfma_f32_16x16x32_bf16(pa1, b1, oacc[cg], 0, 0, 0);
      }
      __builtin_amdgcn_s_setprio(0);
    }
  }
  float lO[4];
  #pragma unroll
  for (int r = 0; r < 4; ++r) lO[r] = __shfl(l_, (lane & 48) | (fg * 4 + r));
  #pragma unroll
  for (int cg = 0; cg < 4; ++cg)
    #pragma unroll
    for (int r = 0; r < 4; ++r)
      y[ybase + (size_t)(r0 + fg * 4 + r) * E_DIM + cg * 16 + fr] = f2bf(oacc[cg][r] / lO[r]);
}

// ---------------- 128-tile bf16 GEMM, BK=64, source-swizzled LDS, XCD-grouped grid ----------------
// OMODE: 0 = f32 out (+res), 1 = bf16 out, 2 = QKV split (Q,K -> qk stride 2E; V -> vt[b,h,d][t])
template<int BM, int BN, bool HAS_BIAS, bool GELU_ACT, bool HAS_RES, int OMODE>
__global__ __launch_bounds__(256) void gemm_bt_kernel(
    const unsigned short* __restrict__ A, const unsigned short* __restrict__ Bt,
    const float* __restrict__ bias, const float* __restrict__ res,
    void* __restrict__ out, unsigned short* __restrict__ vt, int M, int N, int K) {
  constexpr int BK = 64;
  constexpr int MR = BM / 32;
  constexpr int NR = BN / 32;
  constexpr int AI = BM / 32;
  constexpr int BI = BN / 32;
  __shared__ __align__(16) unsigned short As[BM * BK];
  __shared__ __align__(16) unsigned short Bs[BN * BK];
  const int tid  = threadIdx.x;
  const int lane = tid & 63;
  const int wave = tid >> 6;
  const int wr = wave >> 1, wc = wave & 1;

  const int mt = M / BM;
  const int q8 = gridDim.x >> 3;
  const int g  = (blockIdx.x & 7) * q8 + (blockIdx.x >> 3);
  const int m0 = (g % mt) * BM, n0 = (g / mt) * BN;

  const int fr = lane & 15, fg = lane >> 4;
  const int lrow = lane >> 3;
  const int scol = ((lane & 7) * 16) ^ (lrow << 4);
  const size_t K2 = (size_t)K * 2;
  const char* aG = (const char*)A  + (size_t)(m0 + wave * 8 + lrow) * K2 + scol;
  const char* bG = (const char*)Bt + (size_t)(n0 + wave * 8 + lrow) * K2 + scol;

  f32x4 acc[MR][NR];
  #pragma unroll
  for (int mi = 0; mi < MR; ++mi)
    #pragma unroll
    for (int ni = 0; ni < NR; ++ni) acc[mi][ni] = (f32x4){0.f, 0.f, 0.f, 0.f};

  for (int k0 = 0; k0 < K; k0 += BK) {
    __syncthreads();
    #pragma unroll
    for (int i = 0; i < AI; ++i)
      GLDS16(aG + (size_t)i * 32 * K2 + (size_t)k0 * 2, (char*)As + wave * 1024 + i * 4096);
    #pragma unroll
    for (int i = 0; i < BI; ++i)
      GLDS16(bG + (size_t)i * 32 * K2 + (size_t)k0 * 2, (char*)Bs + wave * 1024 + i * 4096);
    __syncthreads();

    short8 af[MR][2], bf[NR][2];
    #pragma unroll
    for (int mi = 0; mi < MR; ++mi) {
      const int row = wr * (BM / 2) + mi * 16 + fr;
      #pragma unroll
      for (int kh = 0; kh < 2; ++kh)
        af[mi][kh] = *(const short8*)((const char*)As + row * 128 +
                       ((kh * 64 + fg * 16) ^ ((row & 7) << 4)));
    }
    #pragma unroll
    for (int ni = 0; ni < NR; ++ni) {
      const int row = wc * (BN / 2) + ni * 16 + fr;
      #pragma unroll
      for (int kh = 0; kh < 2; ++kh)
        bf[ni][kh] = *(const short8*)((const char*)Bs + row * 128 +
                       ((kh * 64 + fg * 16) ^ ((row & 7) << 4)));
    }
    #pragma unroll
    for (int mi = 0; mi < MR; ++mi)
      #pragma unroll
      for (int ni = 0; ni < NR; ++ni) {
        acc[mi][ni] = __builtin_amdgcn_mfma_f32_16x16x32_bf16(af[mi][0], bf[ni][0], acc[mi][ni], 0, 0, 0);
        acc[mi][ni] = __builtin_amdgcn_mfma_f32_16x16x32_bf16(af[mi][1], bf[ni][1], acc[mi][ni], 0, 0, 0);
      }
  }

  #pragma unroll
  for (int mi = 0; mi < MR; ++mi) {
    #pragma unroll
    for (int ni = 0; ni < NR; ++ni) {
      const int col = n0 + wc * (BN / 2) + ni * 16 + fr;
      float bv = HAS_BIAS ? bias[col] : 0.0f;
      float vals[4];
      const int rbase = m0 + wr * (BM / 2) + mi * 16 + fg * 4;
      #pragma unroll
      for (int r = 0; r < 4; ++r) {
        float val = acc[mi][ni][r] + bv;
        if (GELU_ACT) val = 0.5f * val * (1.0f + erff(val * 0.70710678118f));
        if (HAS_RES)  val += res[(size_t)(rbase + r) * N + col];
        vals[r] = val;
      }
      if (OMODE == 0) {
        #pragma unroll
        for (int r = 0; r < 4; ++r)
          ((float*)out)[(size_t)(rbase + r) * N + col] = vals[r];
      } else if (OMODE == 1) {
        #pragma unroll
        for (int r = 0; r < 4; ++r)
          ((unsigned short*)out)[(size_t)(rbase + r) * N + col] = f2bf(vals[r]);
      } else {
        if (col < 2 * E_DIM) {          // Q,K -> row-major stride 2E (block-uniform branch)
          #pragma unroll
          for (int r = 0; r < 4; ++r)
            ((unsigned short*)out)[(size_t)(rbase + r) * 2 * E_DIM + col] = f2bf(vals[r]);
        } else {                         // V -> vt[(b*16+h)*64+d][t], 4 consecutive t
          const int c2 = col - 2 * E_DIM;
          const int hh = c2 >> 6, d = c2 & 63;
          const int bb = rbase >> 10, t0 = rbase & (T_SEQ - 1);
          ushort4 o;
          o.x = f2bf(vals[0]); o.y = f2bf(vals[1]);
          o.z = f2bf(vals[2]); o.w = f2bf(vals[3]);
          *(ushort4*)(vt + ((size_t)(bb * H_HEADS + hh) * D_HEAD + d) * T_SEQ + t0) = o;
        }
      }
    }
  }
}

// ---------------- 256x256 8-phase bf16 GEMM (T2+T3+T4+T5), XCD-grouped ----------------
__global__ __launch_bounds__(512, 1) void gemm8p_kernel(
    const unsigned short* __restrict__ A, const unsigned short* __restrict__ Bt,
    const float* __restrict__ bias, float* __restrict__ out, int M, int N, int K) {
  __shared__ __align__(16) char lds[131072];
  const int tid  = threadIdx.x;
  const int lane = tid & 63;
  const int wv   = tid >> 6;
  const int wm = wv >> 2, wn = wv & 3;

  const int mt = M >> 8;
  const int q8 = gridDim.x >> 3;
  const int g  = (blockIdx.x & 7) * q8 + (blockIdx.x >> 3);
  const int m0 = (g % mt) * 256, n0 = (g / mt) * 256;

  const int fr = lane & 15, fg = lane >> 4;
  const size_t K2 = (size_t)K * 2;
  const int nIter = K >> 7;

  const int csw0 = (fg * 16) ^ ((fr & 7) << 4);
  const int csw1 = (64 + fg * 16) ^ ((fr & 7) << 4);

  const int sc = (lane * 16) & 127;
  const size_t laneoff = (size_t)(lane >> 3) * K2 + (size_t)(sc ^ ((lane >> 3) << 4));
  const char* Asrc = (const char*)(A + (size_t)m0 * K) + (size_t)(wv * 8) * K2 + laneoff;
  const char* Bsrc = (const char*)(Bt + (size_t)n0 * K) + laneoff;

  f32x4 acc[8][4];
  #pragma unroll
  for (int i = 0; i < 8; ++i)
    #pragma unroll
    for (int j = 0; j < 4; ++j) acc[i][j] = (f32x4){0.f, 0.f, 0.f, 0.f};

  auto stageA = [&](int b, int q, int kt) {
    GLDS16(Asrc + (size_t)(q * 64) * K2 + (size_t)kt * 128,
           lds + b * 65536 + q * 8192 + wv * 1024);
  };
  auto stageB = [&](int b, int j, int o, int kt) {
    const int gw = j * 64 + wv * 8;
    const int rw = ((gw >> 5) << 6) + (gw & 31) + o * 32;
    GLDS16(Bsrc + (size_t)rw * K2 + (size_t)kt * 128,
           lds + b * 65536 + 32768 + rw * 128);
  };

  stageA(0, 0, 0); stageA(0, 2, 0);
  stageB(0, 0, 0, 0); stageB(0, 1, 0, 0);
  stageA(0, 1, 0); stageA(0, 3, 0);
  stageB(0, 0, 1, 0); stageB(0, 1, 1, 0);
  stageA(1, 0, 1); stageA(1, 2, 1);
  stageB(1, 0, 0, 1); stageB(1, 1, 0, 1);
  __builtin_amdgcn_sched_barrier(0);
  asm volatile("s_waitcnt vmcnt(4)" ::: "memory");
  __builtin_amdgcn_s_barrier();

  for (int i = 0; i < nIter; ++i) {
    const bool last = (i == nIter - 1);
    #pragma unroll
    for (int p = 0; p < 8; ++p) {
      const int b  = p >> 2;
      const int mh = (p & 3) >> 1;
      const int nh = p & 1;
      const char* Ab = lds + b * 65536;
      const char* Bb = Ab + 32768;
      __builtin_amdgcn_sched_barrier(0);
      short8 fa[4][2], fb[2][2];
      #pragma unroll
      for (int j = 0; j < 4; ++j) {
        const int row = wm * 128 + mh * 64 + j * 16 + fr;
        fa[j][0] = *(const short8*)(Ab + row * 128 + csw0);
        fa[j][1] = *(const short8*)(Ab + row * 128 + csw1);
      }
      #pragma unroll
      for (int n = 0; n < 2; ++n) {
        const int row = wn * 64 + nh * 32 + n * 16 + fr;
        fb[n][0] = *(const short8*)(Bb + row * 128 + csw0);
        fb[n][1] = *(const short8*)(Bb + row * 128 + csw1);
      }
      if (p == 0) { stageA(1, 1, 2 * i + 1); stageA(1, 3, 2 * i + 1); }
      if (p == 1) { stageB(1, 0, 1, 2 * i + 1); stageB(1, 1, 1, 2 * i + 1); }
      if (!last) {
        if (p == 2) { stageA(0, 0, 2 * i + 2); stageA(0, 2, 2 * i + 2); }
        if (p == 3) { stageB(0, 0, 0, 2 * i + 2); stageB(0, 1, 0, 2 * i + 2); }
        if (p == 4) { stageA(0, 1, 2 * i + 2); stageA(0, 3, 2 * i + 2); }
        if (p == 5) { stageB(0, 0, 1, 2 * i + 2); stageB(0, 1, 1, 2 * i + 2); }
        if (p == 6) { stageA(1, 0, 2 * i + 3); stageA(1, 2, 2 * i + 3); }
        if (p == 7) { stageB(1, 0, 0, 2 * i + 3); stageB(1, 1, 0, 2 * i + 3); }
      }
      __builtin_amdgcn_sched_barrier(0);
      __builtin_amdgcn_s_barrier();
      __builtin_amdgcn_sched_barrier(0);
      __builtin_amdgcn_s_setprio(1);
      #pragma unroll
      for (int j = 0; j < 4; ++j)
        #pragma unroll
        for (int n = 0; n < 2; ++n) {
          acc[mh * 4 + j][nh * 2 + n] = __builtin_amdgcn_mfma_f32_16x16x32_bf16(
              fa[j][0], fb[n][0], acc[mh * 4 + j][nh * 2 + n], 0, 0, 0);
          acc[mh * 4 + j][nh * 2 + n] = __builtin_amdgcn_mfma_f32_16x16x32_bf16(
              fa[j][1], fb[n][1], acc[mh * 4 + j][nh * 2 + n], 0, 0, 0);
        }
      __builtin_amdgcn_s_setprio(0);
      __builtin_amdgcn_sched_barrier(0);
      if (p == 3) {
        if (!last) asm volatile("s_waitcnt vmcnt(4)" ::: "memory");
        else       asm volatile("s_waitcnt vmcnt(0)" ::: "memory");
      }
      if (p == 7 && !last)
        asm volatile("s_waitcnt vmcnt(4)" ::: "memory");
      __builtin_amdgcn_s_barrier();
    }
  }

  #pragma unroll
  for (int mi = 0; mi < 8; ++mi) {
    #pragma unroll
    for (int ni = 0; ni < 4; ++ni) {
      const int col = n0 + wn * 64 + ni * 16 + fr;
      const float bv = bias[col];
      #pragma unroll
      for (int r = 0; r < 4; ++r) {
        const int row = m0 + wm * 128 + mi * 16 + fg * 4 + r;
        out[(size_t)row * N + col] = acc[mi][ni][r] + bv;
      }
    }
  }
}

extern "C" void kernel_launch(void* const* d_in, const int* in_sizes, int n_in,
                              void* d_out, int out_size, void* d_ws, size_t ws_size,
                              hipStream_t stream) {
  const int*   idx   = (const int*)  d_in[0];
  const float* tok_w = (const float*)d_in[1];
  const float* pos_w = (const float*)d_in[2];
  const float* ln1_g = (const float*)d_in[3];
  const float* ln1_b = (const float*)d_in[4];
  const float* wq    = (const float*)d_in[5];
  const float* wk    = (const float*)d_in[6];
  const float* wv    = (const float*)d_in[7];
  const float* wp    = (const float*)d_in[8];
  const float* bp    = (const float*)d_in[9];
  const float* ln2_g = (const float*)d_in[10];
  const float* ln2_b = (const float*)d_in[11];
  const float* w1    = (const float*)d_in[12];
  const float* b1    = (const float*)d_in[13];
  const float* w2    = (const float*)d_in[14];
  const float* b2    = (const float*)d_in[15];
  const float* lnf_g = (const float*)d_in[16];
  const float* lnf_b = (const float*)d_in[17];
  const float* wlm   = (const float*)d_in[18];
  const float* blm   = (const float*)d_in[19];

  const int M = B_BATCH * T_SEQ;  // 2048
  const size_t EE = (size_t)E_DIM * E_DIM;
  const size_t EF = (size_t)E_DIM * F_DIM;
  char* p = (char*)d_ws;
  float* x            = (float*)p;          p += (size_t)M * E_DIM * 4;       // 8 MB
  unsigned short* hb  = (unsigned short*)p; p += (size_t)M * E_DIM * 2;       // 4 MB
  unsigned short* qkb = (unsigned short*)p; p += (size_t)M * 2 * E_DIM * 2;   // 8 MB
  unsigned short* vtb = (unsigned short*)p; p += (size_t)M * E_DIM * 2;       // 4 MB
  unsigned short* yb  = (unsigned short*)p; p += (size_t)M * E_DIM * 2;       // 4 MB
  unsigned short* tb  = (unsigned short*)p; p += (size_t)M * F_DIM * 2;       // 16 MB
  unsigned short* wtb = (unsigned short*)p; p += (size_t)V_VOCAB * E_DIM * 2; // 65.5 MB

  embed_kernel<<<M * E_DIM / 4 / 256, 256, 0, stream>>>(idx, tok_w, pos_w, x);

  for (int l = 0; l < L_LAYERS; ++l) {
    ln_kernel<<<M, 256, 0, stream>>>(x, ln1_g + (size_t)l * E_DIM, ln1_b + (size_t)l * E_DIM, hb);
    wtrans4_kernel<<<dim3(E_DIM / 64, E_DIM / 64, 4), 256, 0, stream>>>(
        wq + l * EE, wk + l * EE, wv + l * EE, wp + l * EE, wtb);
    gemm_bt_kernel<128, 128, false, false, false, 2>
        <<<(M / 128) * (3 * E_DIM / 128), 256, 0, stream>>>(
        hb, wtb, nullptr, nullptr, qkb, vtb, M, 3 * E_DIM, E_DIM);
    attn_mfma_kernel<<<dim3(8, B_BATCH * H_HEADS), 512, 0, stream>>>(qkb, vtb, yb);
    gemm_bt_kernel<64, 128, true, false, true, 0>
        <<<(M / 64) * (E_DIM / 128), 256, 0, stream>>>(
        yb, wtb + 3 * EE, bp + (size_t)l * E_DIM, x, x, nullptr, M, E_DIM, E_DIM);
    ln_kernel<<<M, 256, 0, stream>>>(x, ln2_g + (size_t)l * E_DIM, ln2_b + (size_t)l * E_DIM, hb);
    wtrans2_kernel<<<dim3(1024, 2), 256, 0, stream>>>(
        w1 + l * EF, w2 + l * EF, wtb, wtb + EF);
    gemm_bt_kernel<128, 128, true, true, false, 1>
        <<<(M / 128) * (F_DIM / 128), 256, 0, stream>>>(
        hb, wtb, b1 + (size_t)l * F_DIM, nullptr, tb, nullptr, M, F_DIM, E_DIM);
    gemm_bt_kernel<64, 128, true, false, true, 0>
        <<<(M / 64) * (E_DIM / 128), 256, 0, stream>>>(
        tb, wtb + EF, b2 + (size_t)l * E_DIM, x, x, nullptr, M, E_DIM, F_DIM);
  }
  ln_kernel<<<M, 256, 0, stream>>>(x, lnf_g, lnf_b, hb);
  wtrans_kernel<<<dim3(V_VOCAB / 64, E_DIM / 64), 256, 0, stream>>>(wlm, wtb, E_DIM, V_VOCAB);
  gemm8p_kernel<<<(M / 256) * (V_VOCAB / 256), 512, 0, stream>>>(
      hb, wtb, blm, (float*)d_out, M, V_VOCAB, E_DIM);
}

// Round 9
// 1325.333 us; speedup vs baseline: 8.3683x; 1.0236x over previous
//
#include <hip/hip_runtime.h>

#define T_SEQ   1024
#define E_DIM   1024
#define H_HEADS 16
#define D_HEAD  64
#define L_LAYERS 6
#define B_BATCH 2
#define F_DIM   4096
#define V_VOCAB 32000

typedef float f32x4 __attribute__((ext_vector_type(4)));
typedef short short8 __attribute__((ext_vector_type(8)));

__device__ __forceinline__ unsigned short f2bf(float f) {
  union { float f; unsigned int u; } v; v.f = f;
  unsigned int r = v.u + 0x7fffu + ((v.u >> 16) & 1u);  // RNE
  return (unsigned short)(r >> 16);
}

// async global->LDS, 16B per lane; lds dest = wave-uniform base + lane*16
#define GLDS16(gp, lp) __builtin_amdgcn_global_load_lds( \
    (const __attribute__((address_space(1))) void*)(gp), \
    (__attribute__((address_space(3))) void*)(lp), 16, 0, 0)

// ---------------- embedding: x = tok_w[idx] + pos_w ----------------
__global__ void embed_kernel(const int* __restrict__ idx, const float* __restrict__ tok,
                             const float* __restrict__ pos, float* __restrict__ x) {
  int i = blockIdx.x * 256 + threadIdx.x;
  int bt = i >> 8;
  int e4 = i & 255;
  int t  = bt & (T_SEQ - 1);
  int tokid = idx[bt];
  f32x4 a = *(const f32x4*)(tok + (size_t)tokid * E_DIM + e4 * 4);
  f32x4 p = *(const f32x4*)(pos + (size_t)t * E_DIM + e4 * 4);
  *(f32x4*)(x + (size_t)bt * E_DIM + e4 * 4) = a + p;
}

// ---------------- layernorm (f32 in, bf16 out) ----------------
__global__ void ln_kernel(const float* __restrict__ x, const float* __restrict__ g,
                          const float* __restrict__ b, unsigned short* __restrict__ out) {
  int row = blockIdx.x;
  int tid = threadIdx.x;
  const float* xr = x + (size_t)row * E_DIM;
  f32x4 v = *(const f32x4*)(xr + tid * 4);
  float s  = v[0] + v[1] + v[2] + v[3];
  float s2 = v[0]*v[0] + v[1]*v[1] + v[2]*v[2] + v[3]*v[3];
  #pragma unroll
  for (int off = 32; off > 0; off >>= 1) {
    s  += __shfl_xor(s,  off);
    s2 += __shfl_xor(s2, off);
  }
  __shared__ float red[2][4];
  int wave = tid >> 6;
  if ((tid & 63) == 0) { red[0][wave] = s; red[1][wave] = s2; }
  __syncthreads();
  s  = red[0][0] + red[0][1] + red[0][2] + red[0][3];
  s2 = red[1][0] + red[1][1] + red[1][2] + red[1][3];
  float mean = s * (1.0f / E_DIM);
  float var  = s2 * (1.0f / E_DIM) - mean * mean;
  float rstd = rsqrtf(var + 1e-5f);
  f32x4 gv = *(const f32x4*)(g + tid * 4);
  f32x4 bv = *(const f32x4*)(b + tid * 4);
  ushort4 o;
  o.x = f2bf((v[0] - mean) * rstd * gv[0] + bv[0]);
  o.y = f2bf((v[1] - mean) * rstd * gv[1] + bv[1]);
  o.z = f2bf((v[2] - mean) * rstd * gv[2] + bv[2]);
  o.w = f2bf((v[3] - mean) * rstd * gv[3] + bv[3]);
  *(ushort4*)(out + (size_t)row * E_DIM + tid * 4) = o;
}

// ---------------- weight transpose+convert: W f32 [K][N] -> Wt bf16 [N][K] ----------------
__device__ __forceinline__ void wtrans_body(const float* __restrict__ W,
    unsigned short* __restrict__ Wt, int K, int N, int bx, int by) {
  __shared__ float tile[64][65];
  const int n0 = bx * 64, k0 = by * 64;
  const int tr  = threadIdx.x >> 4;
  const int tc4 = (threadIdx.x & 15) * 4;
  #pragma unroll
  for (int p = 0; p < 4; ++p) {
    f32x4 v = *(const f32x4*)(W + (size_t)(k0 + p * 16 + tr) * N + n0 + tc4);
    tile[p * 16 + tr][tc4 + 0] = v[0];
    tile[p * 16 + tr][tc4 + 1] = v[1];
    tile[p * 16 + tr][tc4 + 2] = v[2];
    tile[p * 16 + tr][tc4 + 3] = v[3];
  }
  __syncthreads();
  #pragma unroll
  for (int p = 0; p < 4; ++p) {
    int n = p * 16 + tr;
    ushort4 o;
    o.x = f2bf(tile[tc4 + 0][n]);
    o.y = f2bf(tile[tc4 + 1][n]);
    o.z = f2bf(tile[tc4 + 2][n]);
    o.w = f2bf(tile[tc4 + 3][n]);
    *(ushort4*)(Wt + (size_t)(n0 + n) * K + k0 + tc4) = o;
  }
}

__global__ __launch_bounds__(256) void wtrans_kernel(const float* __restrict__ W,
    unsigned short* __restrict__ Wt, int K, int N) {
  wtrans_body(W, Wt, K, N, blockIdx.x, blockIdx.y);
}

__global__ __launch_bounds__(256) void wtrans4_kernel(const float* __restrict__ W0,
    const float* __restrict__ W1, const float* __restrict__ W2, const float* __restrict__ W3,
    unsigned short* __restrict__ Wt) {
  const float* W = blockIdx.z == 0 ? W0 : (blockIdx.z == 1 ? W1 : (blockIdx.z == 2 ? W2 : W3));
  wtrans_body(W, Wt + (size_t)blockIdx.z * E_DIM * E_DIM, E_DIM, E_DIM,
              blockIdx.x, blockIdx.y);
}

__global__ __launch_bounds__(256) void wtrans2_kernel(const float* __restrict__ W1,
    const float* __restrict__ W2, unsigned short* __restrict__ Wt1,
    unsigned short* __restrict__ Wt2) {
  const int id = blockIdx.x;
  if (blockIdx.y == 0) wtrans_body(W1, Wt1, E_DIM, F_DIM, id % (F_DIM / 64), id / (F_DIM / 64));
  else                 wtrans_body(W2, Wt2, F_DIM, E_DIM, id % (E_DIM / 64), id / (E_DIM / 64));
}

// ---------------- MFMA flash attention, split-key, all-waves-busy ----------------
// Grid (16 q-tiles, 32 bh), 512 thr = 8 waves. Wave (wl,g): q-rows wl*16..+15 of
// q-tile qt, key-half g (32 keys) of each 64-key tile. Independent online-softmax
// state per group; one LDS merge at the end. qt = b ? 15-qx : qx pairs long+short
// blocks per CU. Double-buffered K/V staging (GLDS, inverse-swizzled source) with
// raw s_barrier pairs + counted vmcnt(2) so prefetch overlaps compute.
__global__ __launch_bounds__(512) void attn_mfma_kernel(
    const unsigned short* __restrict__ qk, const unsigned short* __restrict__ vt,
    unsigned short* __restrict__ y) {
  __shared__ __align__(16) char smem[2 * 16384 + 8 * 1280 + 512];
  const int tid  = threadIdx.x;
  const int lane = tid & 63;
  const int wave = tid >> 6;
  const int wl = wave & 3;       // q-row sub-tile
  const int g  = wave >> 2;      // key half
  const int qx = blockIdx.x;
  const int h  = blockIdx.y & (H_HEADS - 1);
  const int b  = blockIdx.y >> 4;
  const int qt = b ? (15 - qx) : qx;
  const int r0 = qt * 64 + wl * 16;
  const size_t RS = 2 * E_DIM;
  const unsigned short* q  = qk + (size_t)b * T_SEQ * RS + (size_t)h * D_HEAD;
  const unsigned short* k  = q + E_DIM;
  const unsigned short* vb = vt + (size_t)(b * H_HEADS + h) * D_HEAD * T_SEQ; // [d][t]
  const size_t ybase = (size_t)b * T_SEQ * E_DIM + (size_t)h * D_HEAD;
  const int fr = lane & 15, fg = lane >> 4;
  const int srow = lane >> 3;
  const int ssw  = ((lane & 7) * 16) ^ (srow << 4);
  char* pb = smem + 32768 + wave * 1280;            // P tile [16][80B]
  float* mlb = (float*)(smem + 32768 + 10240);      // [4][16][2]

  short8 aq[2];
  #pragma unroll
  for (int c = 0; c < 2; ++c)
    aq[c] = *(const short8*)(q + (size_t)(r0 + fr) * RS + c * 32 + fg * 8);

  f32x4 oacc[4];
  #pragma unroll
  for (int cg = 0; cg < 4; ++cg) oacc[cg] = (f32x4){0.f, 0.f, 0.f, 0.f};
  float m_ = -1e30f, l_ = 0.0f;

  auto stage = [&](int t) {   // 2 GLDS/wave: K rows wave*8..+7, V^T rows (d) wave*8..+7
    const int j0 = t * 64;
    char* Kd = smem + (t & 1) * 16384;
    GLDS16((const char*)k  + (size_t)(j0 + wave * 8 + srow) * RS * 2 + ssw,
           Kd + wave * 1024);
    GLDS16((const char*)vb + ((size_t)(wave * 8 + srow) * T_SEQ + j0) * 2 + ssw,
           Kd + 8192 + wave * 1024);
  };

  stage(0);
  for (int t = 0; t <= qt; ++t) {
    __builtin_amdgcn_sched_barrier(0);
    __builtin_amdgcn_s_barrier();            // everyone done reading buf[(t+1)&1]
    if (t < qt) stage(t + 1);
    __builtin_amdgcn_sched_barrier(0);
    if (t < qt) asm volatile("s_waitcnt vmcnt(2)" ::: "memory");  // stage(t) landed
    else        asm volatile("s_waitcnt vmcnt(0)" ::: "memory");
    __builtin_amdgcn_sched_barrier(0);
    __builtin_amdgcn_s_barrier();            // buf[t&1] visible to all waves
    __builtin_amdgcn_sched_barrier(0);
    const char* Kl = smem + (t & 1) * 16384;
    const char* Vl = Kl + 8192;
    const int j0 = t * 64;
    if (!(t == qt && g == 1 && wl < 2)) {    // wave-uniform diag skip (all-masked)
      // ---- S^T = K_half @ Q^T ----
      f32x4 st[2];
      #pragma unroll
      for (int cc = 0; cc < 2; ++cc) {
        const int kloc = g * 32 + cc * 16 + fr;
        const char* kb = Kl + kloc * 128;
        const int sw = (kloc & 7) << 4;
        short8 ka0 = *(const short8*)(kb + ((fg * 16) ^ sw));
        short8 ka1 = *(const short8*)(kb + ((64 + fg * 16) ^ sw));
        f32x4 z = (f32x4){0.f, 0.f, 0.f, 0.f};
        z = __builtin_amdgcn_mfma_f32_16x16x32_bf16(ka0, aq[0], z, 0, 0, 0);
        z = __builtin_amdgcn_mfma_f32_16x16x32_bf16(ka1, aq[1], z, 0, 0, 0);
        st[cc] = z;
      }
      // ---- lane-local online softmax (q-row = r0+fr) ----
      const int qg = r0 + fr;
      float pv[2][4];
      float mx = -1e30f;
      #pragma unroll
      for (int cc = 0; cc < 2; ++cc)
        #pragma unroll
        for (int r = 0; r < 4; ++r) {
          const int kj = j0 + g * 32 + cc * 16 + fg * 4 + r;
          float val = (kj <= qg) ? st[cc][r] * 0.125f : -1e30f;
          pv[cc][r] = val;
          mx = fmaxf(mx, val);
        }
      mx = fmaxf(mx, __shfl_xor(mx, 16));
      mx = fmaxf(mx, __shfl_xor(mx, 32));
      const float mn = fmaxf(m_, mx);
      const float cfs = __expf(m_ - mn);
      float ls = 0.0f;
      #pragma unroll
      for (int cc = 0; cc < 2; ++cc) {
        ushort4 o;
        float e0 = pv[cc][0] > -1e29f ? __expf(pv[cc][0] - mn) : 0.0f;
        float e1 = pv[cc][1] > -1e29f ? __expf(pv[cc][1] - mn) : 0.0f;
        float e2 = pv[cc][2] > -1e29f ? __expf(pv[cc][2] - mn) : 0.0f;
        float e3 = pv[cc][3] > -1e29f ? __expf(pv[cc][3] - mn) : 0.0f;
        ls += (e0 + e1) + (e2 + e3);
        o.x = f2bf(e0); o.y = f2bf(e1); o.z = f2bf(e2); o.w = f2bf(e3);
        *(ushort4*)(pb + fr * 80 + cc * 32 + fg * 8) = o;
      }
      ls += __shfl_xor(ls, 16);
      ls += __shfl_xor(ls, 32);
      l_ = l_ * cfs + ls;
      m_ = mn;
      float cfO[4];
      #pragma unroll
      for (int r = 0; r < 4; ++r) cfO[r] = __shfl(cfs, (lane & 48) | (fg * 4 + r));
      asm volatile("s_waitcnt lgkmcnt(0)" ::: "memory");
      __builtin_amdgcn_sched_barrier(0);
      // ---- O = O*cf + P_half @ V_half ----
      short8 pa = *(const short8*)(pb + fr * 80 + fg * 16);
      __builtin_amdgcn_s_setprio(1);
      #pragma unroll
      for (int cg = 0; cg < 4; ++cg) {
        const int d = cg * 16 + fr;
        short8 bv = *(const short8*)(Vl + d * 128 + ((g * 64 + fg * 16) ^ ((d & 7) << 4)));
        #pragma unroll
        for (int r = 0; r < 4; ++r) oacc[cg][r] *= cfO[r];
        oacc[cg] = __builtin_amdgcn_mfma_f32_16x16x32_bf16(pa, bv, oacc[cg], 0, 0, 0);
      }
      __builtin_amdgcn_s_setprio(0);
    }
  }
  // ---- merge the two key-half states ----
  __syncthreads();
  float* obuf = (float*)smem;    // [4][16][64] f32, reuses staging region
  if (g == 1) {
    #pragma unroll
    for (int cg = 0; cg < 4; ++cg)
      #pragma unroll
      for (int r = 0; r < 4; ++r)
        obuf[wl * 1024 + (fg * 4 + r) * 64 + cg * 16 + fr] = oacc[cg][r];
    if (fg == 0) { mlb[(wl * 16 + fr) * 2] = m_; mlb[(wl * 16 + fr) * 2 + 1] = l_; }
  }
  __syncthreads();
  if (g == 0) {
    const float m1 = mlb[(wl * 16 + fr) * 2];
    const float l1 = mlb[(wl * 16 + fr) * 2 + 1];
    const float m  = fmaxf(m_, m1);
    const float c0 = __expf(m_ - m), c1 = __expf(m1 - m);
    const float li = 1.0f / (l_ * c0 + l1 * c1);
    float c0O[4], c1O[4], liO[4];
    #pragma unroll
    for (int r = 0; r < 4; ++r) {
      const int src = (lane & 48) | (fg * 4 + r);
      c0O[r] = __shfl(c0, src); c1O[r] = __shfl(c1, src); liO[r] = __shfl(li, src);
    }
    #pragma unroll
    for (int cg = 0; cg < 4; ++cg)
      #pragma unroll
      for (int r = 0; r < 4; ++r) {
        const float o1 = obuf[wl * 1024 + (fg * 4 + r) * 64 + cg * 16 + fr];
        const float val = (oacc[cg][r] * c0O[r] + o1 * c1O[r]) * liO[r];
        y[ybase + (size_t)(r0 + fg * 4 + r) * E_DIM + cg * 16 + fr] = f2bf(val);
      }
  }
}

// ---------------- 128-tile bf16 GEMM, BK=64, source-swizzled LDS, XCD-grouped grid ----------------
// OMODE: 0 = f32 out (+res), 1 = bf16 out, 2 = QKV split (Q,K -> qk stride 2E; V -> vt[b,h,d][t])
template<int BM, int BN, bool HAS_BIAS, bool GELU_ACT, bool HAS_RES, int OMODE>
__global__ __launch_bounds__(256) void gemm_bt_kernel(
    const unsigned short* __restrict__ A, const unsigned short* __restrict__ Bt,
    const float* __restrict__ bias, const float* __restrict__ res,
    void* __restrict__ out, unsigned short* __restrict__ vt, int M, int N, int K) {
  constexpr int BK = 64;
  constexpr int MR = BM / 32;
  constexpr int NR = BN / 32;
  constexpr int AI = BM / 32;
  constexpr int BI = BN / 32;
  __shared__ __align__(16) unsigned short As[BM * BK];
  __shared__ __align__(16) unsigned short Bs[BN * BK];
  const int tid  = threadIdx.x;
  const int lane = tid & 63;
  const int wave = tid >> 6;
  const int wr = wave >> 1, wc = wave & 1;

  const int mt = M / BM;
  const int q8 = gridDim.x >> 3;
  const int g  = (blockIdx.x & 7) * q8 + (blockIdx.x >> 3);
  const int m0 = (g % mt) * BM, n0 = (g / mt) * BN;

  const int fr = lane & 15, fg = lane >> 4;
  const int lrow = lane >> 3;
  const int scol = ((lane & 7) * 16) ^ (lrow << 4);
  const size_t K2 = (size_t)K * 2;
  const char* aG = (const char*)A  + (size_t)(m0 + wave * 8 + lrow) * K2 + scol;
  const char* bG = (const char*)Bt + (size_t)(n0 + wave * 8 + lrow) * K2 + scol;

  f32x4 acc[MR][NR];
  #pragma unroll
  for (int mi = 0; mi < MR; ++mi)
    #pragma unroll
    for (int ni = 0; ni < NR; ++ni) acc[mi][ni] = (f32x4){0.f, 0.f, 0.f, 0.f};

  for (int k0 = 0; k0 < K; k0 += BK) {
    __syncthreads();
    #pragma unroll
    for (int i = 0; i < AI; ++i)
      GLDS16(aG + (size_t)i * 32 * K2 + (size_t)k0 * 2, (char*)As + wave * 1024 + i * 4096);
    #pragma unroll
    for (int i = 0; i < BI; ++i)
      GLDS16(bG + (size_t)i * 32 * K2 + (size_t)k0 * 2, (char*)Bs + wave * 1024 + i * 4096);
    __syncthreads();

    short8 af[MR][2], bf[NR][2];
    #pragma unroll
    for (int mi = 0; mi < MR; ++mi) {
      const int row = wr * (BM / 2) + mi * 16 + fr;
      #pragma unroll
      for (int kh = 0; kh < 2; ++kh)
        af[mi][kh] = *(const short8*)((const char*)As + row * 128 +
                       ((kh * 64 + fg * 16) ^ ((row & 7) << 4)));
    }
    #pragma unroll
    for (int ni = 0; ni < NR; ++ni) {
      const int row = wc * (BN / 2) + ni * 16 + fr;
      #pragma unroll
      for (int kh = 0; kh < 2; ++kh)
        bf[ni][kh] = *(const short8*)((const char*)Bs + row * 128 +
                       ((kh * 64 + fg * 16) ^ ((row & 7) << 4)));
    }
    #pragma unroll
    for (int mi = 0; mi < MR; ++mi)
      #pragma unroll
      for (int ni = 0; ni < NR; ++ni) {
        acc[mi][ni] = __builtin_amdgcn_mfma_f32_16x16x32_bf16(af[mi][0], bf[ni][0], acc[mi][ni], 0, 0, 0);
        acc[mi][ni] = __builtin_amdgcn_mfma_f32_16x16x32_bf16(af[mi][1], bf[ni][1], acc[mi][ni], 0, 0, 0);
      }
  }

  #pragma unroll
  for (int mi = 0; mi < MR; ++mi) {
    #pragma unroll
    for (int ni = 0; ni < NR; ++ni) {
      const int col = n0 + wc * (BN / 2) + ni * 16 + fr;
      float bv = HAS_BIAS ? bias[col] : 0.0f;
      float vals[4];
      const int rbase = m0 + wr * (BM / 2) + mi * 16 + fg * 4;
      #pragma unroll
      for (int r = 0; r < 4; ++r) {
        float val = acc[mi][ni][r] + bv;
        if (GELU_ACT) val = 0.5f * val * (1.0f + erff(val * 0.70710678118f));
        if (HAS_RES)  val += res[(size_t)(rbase + r) * N + col];
        vals[r] = val;
      }
      if (OMODE == 0) {
        #pragma unroll
        for (int r = 0; r < 4; ++r)
          ((float*)out)[(size_t)(rbase + r) * N + col] = vals[r];
      } else if (OMODE == 1) {
        #pragma unroll
        for (int r = 0; r < 4; ++r)
          ((unsigned short*)out)[(size_t)(rbase + r) * N + col] = f2bf(vals[r]);
      } else {
        if (col < 2 * E_DIM) {          // Q,K -> row-major stride 2E (block-uniform branch)
          #pragma unroll
          for (int r = 0; r < 4; ++r)
            ((unsigned short*)out)[(size_t)(rbase + r) * 2 * E_DIM + col] = f2bf(vals[r]);
        } else {                         // V -> vt[(b*16+h)*64+d][t], 4 consecutive t
          const int c2 = col - 2 * E_DIM;
          const int hh = c2 >> 6, d = c2 & 63;
          const int bb = rbase >> 10, t0 = rbase & (T_SEQ - 1);
          ushort4 o;
          o.x = f2bf(vals[0]); o.y = f2bf(vals[1]);
          o.z = f2bf(vals[2]); o.w = f2bf(vals[3]);
          *(ushort4*)(vt + ((size_t)(bb * H_HEADS + hh) * D_HEAD + d) * T_SEQ + t0) = o;
        }
      }
    }
  }
}

// ---------------- 256x256 8-phase bf16 GEMM (T2+T3+T4+T5), XCD-grouped ----------------
__global__ __launch_bounds__(512, 1) void gemm8p_kernel(
    const unsigned short* __restrict__ A, const unsigned short* __restrict__ Bt,
    const float* __restrict__ bias, float* __restrict__ out, int M, int N, int K) {
  __shared__ __align__(16) char lds[131072];
  const int tid  = threadIdx.x;
  const int lane = tid & 63;
  const int wv   = tid >> 6;
  const int wm = wv >> 2, wn = wv & 3;

  const int mt = M >> 8;
  const int q8 = gridDim.x >> 3;
  const int g  = (blockIdx.x & 7) * q8 + (blockIdx.x >> 3);
  const int m0 = (g % mt) * 256, n0 = (g / mt) * 256;

  const int fr = lane & 15, fg = lane >> 4;
  const size_t K2 = (size_t)K * 2;
  const int nIter = K >> 7;

  const int csw0 = (fg * 16) ^ ((fr & 7) << 4);
  const int csw1 = (64 + fg * 16) ^ ((fr & 7) << 4);

  const int sc = (lane * 16) & 127;
  const size_t laneoff = (size_t)(lane >> 3) * K2 + (size_t)(sc ^ ((lane >> 3) << 4));
  const char* Asrc = (const char*)(A + (size_t)m0 * K) + (size_t)(wv * 8) * K2 + laneoff;
  const char* Bsrc = (const char*)(Bt + (size_t)n0 * K) + laneoff;

  f32x4 acc[8][4];
  #pragma unroll
  for (int i = 0; i < 8; ++i)
    #pragma unroll
    for (int j = 0; j < 4; ++j) acc[i][j] = (f32x4){0.f, 0.f, 0.f, 0.f};

  auto stageA = [&](int b, int q, int kt) {
    GLDS16(Asrc + (size_t)(q * 64) * K2 + (size_t)kt * 128,
           lds + b * 65536 + q * 8192 + wv * 1024);
  };
  auto stageB = [&](int b, int j, int o, int kt) {
    const int gw = j * 64 + wv * 8;
    const int rw = ((gw >> 5) << 6) + (gw & 31) + o * 32;
    GLDS16(Bsrc + (size_t)rw * K2 + (size_t)kt * 128,
           lds + b * 65536 + 32768 + rw * 128);
  };

  stageA(0, 0, 0); stageA(0, 2, 0);
  stageB(0, 0, 0, 0); stageB(0, 1, 0, 0);
  stageA(0, 1, 0); stageA(0, 3, 0);
  stageB(0, 0, 1, 0); stageB(0, 1, 1, 0);
  stageA(1, 0, 1); stageA(1, 2, 1);
  stageB(1, 0, 0, 1); stageB(1, 1, 0, 1);
  __builtin_amdgcn_sched_barrier(0);
  asm volatile("s_waitcnt vmcnt(4)" ::: "memory");
  __builtin_amdgcn_s_barrier();

  for (int i = 0; i < nIter; ++i) {
    const bool last = (i == nIter - 1);
    #pragma unroll
    for (int p = 0; p < 8; ++p) {
      const int b  = p >> 2;
      const int mh = (p & 3) >> 1;
      const int nh = p & 1;
      const char* Ab = lds + b * 65536;
      const char* Bb = Ab + 32768;
      __builtin_amdgcn_sched_barrier(0);
      short8 fa[4][2], fb[2][2];
      #pragma unroll
      for (int j = 0; j < 4; ++j) {
        const int row = wm * 128 + mh * 64 + j * 16 + fr;
        fa[j][0] = *(const short8*)(Ab + row * 128 + csw0);
        fa[j][1] = *(const short8*)(Ab + row * 128 + csw1);
      }
      #pragma unroll
      for (int n = 0; n < 2; ++n) {
        const int row = wn * 64 + nh * 32 + n * 16 + fr;
        fb[n][0] = *(const short8*)(Bb + row * 128 + csw0);
        fb[n][1] = *(const short8*)(Bb + row * 128 + csw1);
      }
      if (p == 0) { stageA(1, 1, 2 * i + 1); stageA(1, 3, 2 * i + 1); }
      if (p == 1) { stageB(1, 0, 1, 2 * i + 1); stageB(1, 1, 1, 2 * i + 1); }
      if (!last) {
        if (p == 2) { stageA(0, 0, 2 * i + 2); stageA(0, 2, 2 * i + 2); }
        if (p == 3) { stageB(0, 0, 0, 2 * i + 2); stageB(0, 1, 0, 2 * i + 2); }
        if (p == 4) { stageA(0, 1, 2 * i + 2); stageA(0, 3, 2 * i + 2); }
        if (p == 5) { stageB(0, 0, 1, 2 * i + 2); stageB(0, 1, 1, 2 * i + 2); }
        if (p == 6) { stageA(1, 0, 2 * i + 3); stageA(1, 2, 2 * i + 3); }
        if (p == 7) { stageB(1, 0, 0, 2 * i + 3); stageB(1, 1, 0, 2 * i + 3); }
      }
      __builtin_amdgcn_sched_barrier(0);
      __builtin_amdgcn_s_barrier();
      __builtin_amdgcn_sched_barrier(0);
      __builtin_amdgcn_s_setprio(1);
      #pragma unroll
      for (int j = 0; j < 4; ++j)
        #pragma unroll
        for (int n = 0; n < 2; ++n) {
          acc[mh * 4 + j][nh * 2 + n] = __builtin_amdgcn_mfma_f32_16x16x32_bf16(
              fa[j][0], fb[n][0], acc[mh * 4 + j][nh * 2 + n], 0, 0, 0);
          acc[mh * 4 + j][nh * 2 + n] = __builtin_amdgcn_mfma_f32_16x16x32_bf16(
              fa[j][1], fb[n][1], acc[mh * 4 + j][nh * 2 + n], 0, 0, 0);
        }
      __builtin_amdgcn_s_setprio(0);
      __builtin_amdgcn_sched_barrier(0);
      if (p == 3) {
        if (!last) asm volatile("s_waitcnt vmcnt(4)" ::: "memory");
        else       asm volatile("s_waitcnt vmcnt(0)" ::: "memory");
      }
      if (p == 7 && !last)
        asm volatile("s_waitcnt vmcnt(4)" ::: "memory");
      __builtin_amdgcn_s_barrier();
    }
  }

  #pragma unroll
  for (int mi = 0; mi < 8; ++mi) {
    #pragma unroll
    for (int ni = 0; ni < 4; ++ni) {
      const int col = n0 + wn * 64 + ni * 16 + fr;
      const float bv = bias[col];
      #pragma unroll
      for (int r = 0; r < 4; ++r) {
        const int row = m0 + wm * 128 + mi * 16 + fg * 4 + r;
        out[(size_t)row * N + col] = acc[mi][ni][r] + bv;
      }
    }
  }
}

extern "C" void kernel_launch(void* const* d_in, const int* in_sizes, int n_in,
                              void* d_out, int out_size, void* d_ws, size_t ws_size,
                              hipStream_t stream) {
  const int*   idx   = (const int*)  d_in[0];
  const float* tok_w = (const float*)d_in[1];
  const float* pos_w = (const float*)d_in[2];
  const float* ln1_g = (const float*)d_in[3];
  const float* ln1_b = (const float*)d_in[4];
  const float* wq    = (const float*)d_in[5];
  const float* wk    = (const float*)d_in[6];
  const float* wv    = (const float*)d_in[7];
  const float* wp    = (const float*)d_in[8];
  const float* bp    = (const float*)d_in[9];
  const float* ln2_g = (const float*)d_in[10];
  const float* ln2_b = (const float*)d_in[11];
  const float* w1    = (const float*)d_in[12];
  const float* b1    = (const float*)d_in[13];
  const float* w2    = (const float*)d_in[14];
  const float* b2    = (const float*)d_in[15];
  const float* lnf_g = (const float*)d_in[16];
  const float* lnf_b = (const float*)d_in[17];
  const float* wlm   = (const float*)d_in[18];
  const float* blm   = (const float*)d_in[19];

  const int M = B_BATCH * T_SEQ;  // 2048
  const size_t EE = (size_t)E_DIM * E_DIM;
  const size_t EF = (size_t)E_DIM * F_DIM;
  char* p = (char*)d_ws;
  float* x            = (float*)p;          p += (size_t)M * E_DIM * 4;
  unsigned short* hb  = (unsigned short*)p; p += (size_t)M * E_DIM * 2;
  unsigned short* qkb = (unsigned short*)p; p += (size_t)M * 2 * E_DIM * 2;
  unsigned short* vtb = (unsigned short*)p; p += (size_t)M * E_DIM * 2;
  unsigned short* yb  = (unsigned short*)p; p += (size_t)M * E_DIM * 2;
  unsigned short* tb  = (unsigned short*)p; p += (size_t)M * F_DIM * 2;
  unsigned short* wtb = (unsigned short*)p; p += (size_t)V_VOCAB * E_DIM * 2;

  embed_kernel<<<M * E_DIM / 4 / 256, 256, 0, stream>>>(idx, tok_w, pos_w, x);

  for (int l = 0; l < L_LAYERS; ++l) {
    ln_kernel<<<M, 256, 0, stream>>>(x, ln1_g + (size_t)l * E_DIM, ln1_b + (size_t)l * E_DIM, hb);
    wtrans4_kernel<<<dim3(E_DIM / 64, E_DIM / 64, 4), 256, 0, stream>>>(
        wq + l * EE, wk + l * EE, wv + l * EE, wp + l * EE, wtb);
    gemm_bt_kernel<128, 128, false, false, false, 2>
        <<<(M / 128) * (3 * E_DIM / 128), 256, 0, stream>>>(
        hb, wtb, nullptr, nullptr, qkb, vtb, M, 3 * E_DIM, E_DIM);
    attn_mfma_kernel<<<dim3(16, B_BATCH * H_HEADS), 512, 0, stream>>>(qkb, vtb, yb);
    gemm_bt_kernel<64, 128, true, false, true, 0>
        <<<(M / 64) * (E_DIM / 128), 256, 0, stream>>>(
        yb, wtb + 3 * EE, bp + (size_t)l * E_DIM, x, x, nullptr, M, E_DIM, E_DIM);
    ln_kernel<<<M, 256, 0, stream>>>(x, ln2_g + (size_t)l * E_DIM, ln2_b + (size_t)l * E_DIM, hb);
    wtrans2_kernel<<<dim3(1024, 2), 256, 0, stream>>>(
        w1 + l * EF, w2 + l * EF, wtb, wtb + EF);
    gemm_bt_kernel<128, 128, true, true, false, 1>
        <<<(M / 128) * (F_DIM / 128), 256, 0, stream>>>(
        hb, wtb, b1 + (size_t)l * F_DIM, nullptr, tb, nullptr, M, F_DIM, E_DIM);
    gemm_bt_kernel<64, 128, true, false, true, 0>
        <<<(M / 64) * (E_DIM / 128), 256, 0, stream>>>(
        tb, wtb + EF, b2 + (size_t)l * E_DIM, x, x, nullptr, M, E_DIM, F_DIM);
  }
  ln_kernel<<<M, 256, 0, stream>>>(x, lnf_g, lnf_b, hb);
  wtrans_kernel<<<dim3(V_VOCAB / 64, E_DIM / 64), 256, 0, stream>>>(wlm, wtb, E_DIM, V_VOCAB);
  gemm8p_kernel<<<(M / 256) * (V_VOCAB / 256), 512, 0, stream>>>(
      hb, wtb, blm, (float*)d_out, M, V_VOCAB, E_DIM);
}

// Round 10
// 1296.944 us; speedup vs baseline: 8.5515x; 1.0219x over previous
//
#include <hip/hip_runtime.h>

#define T_SEQ   1024
#define E_DIM   1024
#define H_HEADS 16
#define D_HEAD  64
#define L_LAYERS 6
#define B_BATCH 2
#define F_DIM   4096
#define V_VOCAB 32000

typedef float f32x4 __attribute__((ext_vector_type(4)));
typedef short short8 __attribute__((ext_vector_type(8)));

__device__ __forceinline__ unsigned short f2bf(float f) {
  union { float f; unsigned int u; } v; v.f = f;
  unsigned int r = v.u + 0x7fffu + ((v.u >> 16) & 1u);  // RNE
  return (unsigned short)(r >> 16);
}

// async global->LDS, 16B per lane; lds dest = wave-uniform base + lane*16
#define GLDS16(gp, lp) __builtin_amdgcn_global_load_lds( \
    (const __attribute__((address_space(1))) void*)(gp), \
    (__attribute__((address_space(3))) void*)(lp), 16, 0, 0)

// ---------------- embedding: x = tok_w[idx] + pos_w ----------------
__global__ void embed_kernel(const int* __restrict__ idx, const float* __restrict__ tok,
                             const float* __restrict__ pos, float* __restrict__ x) {
  int i = blockIdx.x * 256 + threadIdx.x;
  int bt = i >> 8;
  int e4 = i & 255;
  int t  = bt & (T_SEQ - 1);
  int tokid = idx[bt];
  f32x4 a = *(const f32x4*)(tok + (size_t)tokid * E_DIM + e4 * 4);
  f32x4 p = *(const f32x4*)(pos + (size_t)t * E_DIM + e4 * 4);
  *(f32x4*)(x + (size_t)bt * E_DIM + e4 * 4) = a + p;
}

// ---------------- layernorm (f32 in, bf16 out) ----------------
__global__ void ln_kernel(const float* __restrict__ x, const float* __restrict__ g,
                          const float* __restrict__ b, unsigned short* __restrict__ out) {
  int row = blockIdx.x;
  int tid = threadIdx.x;
  const float* xr = x + (size_t)row * E_DIM;
  f32x4 v = *(const f32x4*)(xr + tid * 4);
  float s  = v[0] + v[1] + v[2] + v[3];
  float s2 = v[0]*v[0] + v[1]*v[1] + v[2]*v[2] + v[3]*v[3];
  #pragma unroll
  for (int off = 32; off > 0; off >>= 1) {
    s  += __shfl_xor(s,  off);
    s2 += __shfl_xor(s2, off);
  }
  __shared__ float red[2][4];
  int wave = tid >> 6;
  if ((tid & 63) == 0) { red[0][wave] = s; red[1][wave] = s2; }
  __syncthreads();
  s  = red[0][0] + red[0][1] + red[0][2] + red[0][3];
  s2 = red[1][0] + red[1][1] + red[1][2] + red[1][3];
  float mean = s * (1.0f / E_DIM);
  float var  = s2 * (1.0f / E_DIM) - mean * mean;
  float rstd = rsqrtf(var + 1e-5f);
  f32x4 gv = *(const f32x4*)(g + tid * 4);
  f32x4 bv = *(const f32x4*)(b + tid * 4);
  ushort4 o;
  o.x = f2bf((v[0] - mean) * rstd * gv[0] + bv[0]);
  o.y = f2bf((v[1] - mean) * rstd * gv[1] + bv[1]);
  o.z = f2bf((v[2] - mean) * rstd * gv[2] + bv[2]);
  o.w = f2bf((v[3] - mean) * rstd * gv[3] + bv[3]);
  *(ushort4*)(out + (size_t)row * E_DIM + tid * 4) = o;
}

// ---------------- weight transpose+convert: W f32 [K][N] -> Wt bf16 [N][K] ----------------
__device__ __forceinline__ void wtrans_body(const float* __restrict__ W,
    unsigned short* __restrict__ Wt, int K, int N, int bx, int by) {
  __shared__ float tile[64][65];
  const int n0 = bx * 64, k0 = by * 64;
  const int tr  = threadIdx.x >> 4;
  const int tc4 = (threadIdx.x & 15) * 4;
  #pragma unroll
  for (int p = 0; p < 4; ++p) {
    f32x4 v = *(const f32x4*)(W + (size_t)(k0 + p * 16 + tr) * N + n0 + tc4);
    tile[p * 16 + tr][tc4 + 0] = v[0];
    tile[p * 16 + tr][tc4 + 1] = v[1];
    tile[p * 16 + tr][tc4 + 2] = v[2];
    tile[p * 16 + tr][tc4 + 3] = v[3];
  }
  __syncthreads();
  #pragma unroll
  for (int p = 0; p < 4; ++p) {
    int n = p * 16 + tr;
    ushort4 o;
    o.x = f2bf(tile[tc4 + 0][n]);
    o.y = f2bf(tile[tc4 + 1][n]);
    o.z = f2bf(tile[tc4 + 2][n]);
    o.w = f2bf(tile[tc4 + 3][n]);
    *(ushort4*)(Wt + (size_t)(n0 + n) * K + k0 + tc4) = o;
  }
}

__global__ __launch_bounds__(256) void wtrans_kernel(const float* __restrict__ W,
    unsigned short* __restrict__ Wt, int K, int N) {
  wtrans_body(W, Wt, K, N, blockIdx.x, blockIdx.y);
}

// all 6 layer weights in one launch: wtb = [q,k,v,p (EE each)][w1t (EF)][w2t (EF)]
__global__ __launch_bounds__(256) void wtrans6_kernel(const float* __restrict__ wq,
    const float* __restrict__ wk, const float* __restrict__ wv, const float* __restrict__ wp,
    const float* __restrict__ w1, const float* __restrict__ w2,
    unsigned short* __restrict__ wtb) {
  const size_t EE = (size_t)E_DIM * E_DIM;
  const size_t EF = (size_t)E_DIM * F_DIM;
  const int id = blockIdx.x;
  if (id < 1024) {
    const int z = id >> 8, r = id & 255;
    const float* W = z == 0 ? wq : (z == 1 ? wk : (z == 2 ? wv : wp));
    wtrans_body(W, wtb + z * EE, E_DIM, E_DIM, r & 15, r >> 4);
  } else if (id < 2048) {
    const int r = id - 1024;
    wtrans_body(w1, wtb + 4 * EE, E_DIM, F_DIM, r & 63, r >> 6);
  } else {
    const int r = id - 2048;
    wtrans_body(w2, wtb + 4 * EE + EF, F_DIM, E_DIM, r & 15, r >> 4);
  }
}

// ---------------- MFMA flash attention, split-key, all-waves-busy ----------------
__global__ __launch_bounds__(512) void attn_mfma_kernel(
    const unsigned short* __restrict__ qk, const unsigned short* __restrict__ vt,
    unsigned short* __restrict__ y) {
  __shared__ __align__(16) char smem[2 * 16384 + 8 * 1280 + 512];
  const int tid  = threadIdx.x;
  const int lane = tid & 63;
  const int wave = tid >> 6;
  const int wl = wave & 3;
  const int g  = wave >> 2;
  const int qx = blockIdx.x;
  const int h  = blockIdx.y & (H_HEADS - 1);
  const int b  = blockIdx.y >> 4;
  const int qt = b ? (15 - qx) : qx;
  const int r0 = qt * 64 + wl * 16;
  const size_t RS = 2 * E_DIM;
  const unsigned short* q  = qk + (size_t)b * T_SEQ * RS + (size_t)h * D_HEAD;
  const unsigned short* k  = q + E_DIM;
  const unsigned short* vb = vt + (size_t)(b * H_HEADS + h) * D_HEAD * T_SEQ;
  const size_t ybase = (size_t)b * T_SEQ * E_DIM + (size_t)h * D_HEAD;
  const int fr = lane & 15, fg = lane >> 4;
  const int srow = lane >> 3;
  const int ssw  = ((lane & 7) * 16) ^ (srow << 4);
  char* pb = smem + 32768 + wave * 1280;
  float* mlb = (float*)(smem + 32768 + 10240);

  short8 aq[2];
  #pragma unroll
  for (int c = 0; c < 2; ++c)
    aq[c] = *(const short8*)(q + (size_t)(r0 + fr) * RS + c * 32 + fg * 8);

  f32x4 oacc[4];
  #pragma unroll
  for (int cg = 0; cg < 4; ++cg) oacc[cg] = (f32x4){0.f, 0.f, 0.f, 0.f};
  float m_ = -1e30f, l_ = 0.0f;

  auto stage = [&](int t) {
    const int j0 = t * 64;
    char* Kd = smem + (t & 1) * 16384;
    GLDS16((const char*)k  + (size_t)(j0 + wave * 8 + srow) * RS * 2 + ssw,
           Kd + wave * 1024);
    GLDS16((const char*)vb + ((size_t)(wave * 8 + srow) * T_SEQ + j0) * 2 + ssw,
           Kd + 8192 + wave * 1024);
  };

  stage(0);
  for (int t = 0; t <= qt; ++t) {
    __builtin_amdgcn_sched_barrier(0);
    __builtin_amdgcn_s_barrier();
    if (t < qt) stage(t + 1);
    __builtin_amdgcn_sched_barrier(0);
    if (t < qt) asm volatile("s_waitcnt vmcnt(2)" ::: "memory");
    else        asm volatile("s_waitcnt vmcnt(0)" ::: "memory");
    __builtin_amdgcn_sched_barrier(0);
    __builtin_amdgcn_s_barrier();
    __builtin_amdgcn_sched_barrier(0);
    const char* Kl = smem + (t & 1) * 16384;
    const char* Vl = Kl + 8192;
    const int j0 = t * 64;
    if (!(t == qt && g == 1 && wl < 2)) {
      f32x4 st[2];
      #pragma unroll
      for (int cc = 0; cc < 2; ++cc) {
        const int kloc = g * 32 + cc * 16 + fr;
        const char* kb = Kl + kloc * 128;
        const int sw = (kloc & 7) << 4;
        short8 ka0 = *(const short8*)(kb + ((fg * 16) ^ sw));
        short8 ka1 = *(const short8*)(kb + ((64 + fg * 16) ^ sw));
        f32x4 z = (f32x4){0.f, 0.f, 0.f, 0.f};
        z = __builtin_amdgcn_mfma_f32_16x16x32_bf16(ka0, aq[0], z, 0, 0, 0);
        z = __builtin_amdgcn_mfma_f32_16x16x32_bf16(ka1, aq[1], z, 0, 0, 0);
        st[cc] = z;
      }
      const int qg = r0 + fr;
      float pv[2][4];
      float mx = -1e30f;
      #pragma unroll
      for (int cc = 0; cc < 2; ++cc)
        #pragma unroll
        for (int r = 0; r < 4; ++r) {
          const int kj = j0 + g * 32 + cc * 16 + fg * 4 + r;
          float val = (kj <= qg) ? st[cc][r] * 0.125f : -1e30f;
          pv[cc][r] = val;
          mx = fmaxf(mx, val);
        }
      mx = fmaxf(mx, __shfl_xor(mx, 16));
      mx = fmaxf(mx, __shfl_xor(mx, 32));
      const float mn = fmaxf(m_, mx);
      const float cfs = __expf(m_ - mn);
      float ls = 0.0f;
      #pragma unroll
      for (int cc = 0; cc < 2; ++cc) {
        ushort4 o;
        float e0 = pv[cc][0] > -1e29f ? __expf(pv[cc][0] - mn) : 0.0f;
        float e1 = pv[cc][1] > -1e29f ? __expf(pv[cc][1] - mn) : 0.0f;
        float e2 = pv[cc][2] > -1e29f ? __expf(pv[cc][2] - mn) : 0.0f;
        float e3 = pv[cc][3] > -1e29f ? __expf(pv[cc][3] - mn) : 0.0f;
        ls += (e0 + e1) + (e2 + e3);
        o.x = f2bf(e0); o.y = f2bf(e1); o.z = f2bf(e2); o.w = f2bf(e3);
        *(ushort4*)(pb + fr * 80 + cc * 32 + fg * 8) = o;
      }
      ls += __shfl_xor(ls, 16);
      ls += __shfl_xor(ls, 32);
      l_ = l_ * cfs + ls;
      m_ = mn;
      float cfO[4];
      #pragma unroll
      for (int r = 0; r < 4; ++r) cfO[r] = __shfl(cfs, (lane & 48) | (fg * 4 + r));
      asm volatile("s_waitcnt lgkmcnt(0)" ::: "memory");
      __builtin_amdgcn_sched_barrier(0);
      short8 pa = *(const short8*)(pb + fr * 80 + fg * 16);
      __builtin_amdgcn_s_setprio(1);
      #pragma unroll
      for (int cg = 0; cg < 4; ++cg) {
        const int d = cg * 16 + fr;
        short8 bv = *(const short8*)(Vl + d * 128 + ((g * 64 + fg * 16) ^ ((d & 7) << 4)));
        #pragma unroll
        for (int r = 0; r < 4; ++r) oacc[cg][r] *= cfO[r];
        oacc[cg] = __builtin_amdgcn_mfma_f32_16x16x32_bf16(pa, bv, oacc[cg], 0, 0, 0);
      }
      __builtin_amdgcn_s_setprio(0);
    }
  }
  __syncthreads();
  float* obuf = (float*)smem;
  if (g == 1) {
    #pragma unroll
    for (int cg = 0; cg < 4; ++cg)
      #pragma unroll
      for (int r = 0; r < 4; ++r)
        obuf[wl * 1024 + (fg * 4 + r) * 64 + cg * 16 + fr] = oacc[cg][r];
    if (fg == 0) { mlb[(wl * 16 + fr) * 2] = m_; mlb[(wl * 16 + fr) * 2 + 1] = l_; }
  }
  __syncthreads();
  if (g == 0) {
    const float m1 = mlb[(wl * 16 + fr) * 2];
    const float l1 = mlb[(wl * 16 + fr) * 2 + 1];
    const float m  = fmaxf(m_, m1);
    const float c0 = __expf(m_ - m), c1 = __expf(m1 - m);
    const float li = 1.0f / (l_ * c0 + l1 * c1);
    float c0O[4], c1O[4], liO[4];
    #pragma unroll
    for (int r = 0; r < 4; ++r) {
      const int src = (lane & 48) | (fg * 4 + r);
      c0O[r] = __shfl(c0, src); c1O[r] = __shfl(c1, src); liO[r] = __shfl(li, src);
    }
    #pragma unroll
    for (int cg = 0; cg < 4; ++cg)
      #pragma unroll
      for (int r = 0; r < 4; ++r) {
        const float o1 = obuf[wl * 1024 + (fg * 4 + r) * 64 + cg * 16 + fr];
        const float val = (oacc[cg][r] * c0O[r] + o1 * c1O[r]) * liO[r];
        y[ybase + (size_t)(r0 + fg * 4 + r) * E_DIM + cg * 16 + fr] = f2bf(val);
      }
  }
}

// ---------------- 128-tile bf16 GEMM, BK=64, 2-barrier (proj / MLP2) ----------------
template<int BM, int BN, bool HAS_BIAS, bool GELU_ACT, bool HAS_RES, int OMODE>
__global__ __launch_bounds__(256) void gemm_bt_kernel(
    const unsigned short* __restrict__ A, const unsigned short* __restrict__ Bt,
    const float* __restrict__ bias, const float* __restrict__ res,
    void* __restrict__ out, unsigned short* __restrict__ vt, int M, int N, int K) {
  constexpr int BK = 64;
  constexpr int MR = BM / 32;
  constexpr int NR = BN / 32;
  constexpr int AI = BM / 32;
  constexpr int BI = BN / 32;
  __shared__ __align__(16) unsigned short As[BM * BK];
  __shared__ __align__(16) unsigned short Bs[BN * BK];
  const int tid  = threadIdx.x;
  const int lane = tid & 63;
  const int wave = tid >> 6;
  const int wr = wave >> 1, wc = wave & 1;

  const int mt = M / BM;
  const int q8 = gridDim.x >> 3;
  const int g  = (blockIdx.x & 7) * q8 + (blockIdx.x >> 3);
  const int m0 = (g % mt) * BM, n0 = (g / mt) * BN;

  const int fr = lane & 15, fg = lane >> 4;
  const int lrow = lane >> 3;
  const int scol = ((lane & 7) * 16) ^ (lrow << 4);
  const size_t K2 = (size_t)K * 2;
  const char* aG = (const char*)A  + (size_t)(m0 + wave * 8 + lrow) * K2 + scol;
  const char* bG = (const char*)Bt + (size_t)(n0 + wave * 8 + lrow) * K2 + scol;

  f32x4 acc[MR][NR];
  #pragma unroll
  for (int mi = 0; mi < MR; ++mi)
    #pragma unroll
    for (int ni = 0; ni < NR; ++ni) acc[mi][ni] = (f32x4){0.f, 0.f, 0.f, 0.f};

  for (int k0 = 0; k0 < K; k0 += BK) {
    __syncthreads();
    #pragma unroll
    for (int i = 0; i < AI; ++i)
      GLDS16(aG + (size_t)i * 32 * K2 + (size_t)k0 * 2, (char*)As + wave * 1024 + i * 4096);
    #pragma unroll
    for (int i = 0; i < BI; ++i)
      GLDS16(bG + (size_t)i * 32 * K2 + (size_t)k0 * 2, (char*)Bs + wave * 1024 + i * 4096);
    __syncthreads();

    short8 af[MR][2], bf[NR][2];
    #pragma unroll
    for (int mi = 0; mi < MR; ++mi) {
      const int row = wr * (BM / 2) + mi * 16 + fr;
      #pragma unroll
      for (int kh = 0; kh < 2; ++kh)
        af[mi][kh] = *(const short8*)((const char*)As + row * 128 +
                       ((kh * 64 + fg * 16) ^ ((row & 7) << 4)));
    }
    #pragma unroll
    for (int ni = 0; ni < NR; ++ni) {
      const int row = wc * (BN / 2) + ni * 16 + fr;
      #pragma unroll
      for (int kh = 0; kh < 2; ++kh)
        bf[ni][kh] = *(const short8*)((const char*)Bs + row * 128 +
                       ((kh * 64 + fg * 16) ^ ((row & 7) << 4)));
    }
    #pragma unroll
    for (int mi = 0; mi < MR; ++mi)
      #pragma unroll
      for (int ni = 0; ni < NR; ++ni) {
        acc[mi][ni] = __builtin_amdgcn_mfma_f32_16x16x32_bf16(af[mi][0], bf[ni][0], acc[mi][ni], 0, 0, 0);
        acc[mi][ni] = __builtin_amdgcn_mfma_f32_16x16x32_bf16(af[mi][1], bf[ni][1], acc[mi][ni], 0, 0, 0);
      }
  }

  #pragma unroll
  for (int mi = 0; mi < MR; ++mi) {
    #pragma unroll
    for (int ni = 0; ni < NR; ++ni) {
      const int col = n0 + wc * (BN / 2) + ni * 16 + fr;
      float bv = HAS_BIAS ? bias[col] : 0.0f;
      float vals[4];
      const int rbase = m0 + wr * (BM / 2) + mi * 16 + fg * 4;
      #pragma unroll
      for (int r = 0; r < 4; ++r) {
        float val = acc[mi][ni][r] + bv;
        if (GELU_ACT) val = 0.5f * val * (1.0f + erff(val * 0.70710678118f));
        if (HAS_RES)  val += res[(size_t)(rbase + r) * N + col];
        vals[r] = val;
      }
      if (OMODE == 0) {
        #pragma unroll
        for (int r = 0; r < 4; ++r)
          ((float*)out)[(size_t)(rbase + r) * N + col] = vals[r];
      } else {
        #pragma unroll
        for (int r = 0; r < 4; ++r)
          ((unsigned short*)out)[(size_t)(rbase + r) * N + col] = f2bf(vals[r]);
      }
    }
  }
}

// ---------------- 128x256 8-phase bf16 GEMM (QKV / MLP1), T2+T3+T4+T5 ----------------
// 8 waves (2M x 4N), wave owns 64x64. BK=64, 2-tile dbuf (96 KB LDS).
// A staged as 2 mh-aligned calls [mh][wm][32 rows]; B as 4 nh-aligned calls
// [nh][w2][w1][32 rows]. Staging only into regions whose readers finished a
// phase earlier; counted vmcnt(3) gates at p3/p7.
// OMODE: 1 = bf16 out, 2 = QKV split (cols<2E -> qk stride 2E; else vt[b,h,d][t])
template<int OMODE, bool HAS_BIAS, bool GELU_ACT>
__global__ __launch_bounds__(512, 1) void gemm8p2_kernel(
    const unsigned short* __restrict__ A, const unsigned short* __restrict__ Bt,
    const float* __restrict__ bias, void* __restrict__ out,
    unsigned short* __restrict__ vt, int M, int N, int K) {
  __shared__ __align__(16) char lds[98304];
  const int tid  = threadIdx.x;
  const int lane = tid & 63;
  const int wv   = tid >> 6;
  const int wm = wv >> 2, wn = wv & 3;

  const int mt = M >> 7;
  const int q8 = gridDim.x >> 3;
  const int g  = (blockIdx.x & 7) * q8 + (blockIdx.x >> 3);
  const int m0 = (g % mt) * 128, n0 = (g / mt) * 256;

  const int fr = lane & 15, fg = lane >> 4;
  const size_t K2 = (size_t)K * 2;
  const int nIter = K >> 7;

  const int csw0 = (fg * 16) ^ ((fr & 7) << 4);
  const int csw1 = (64 + fg * 16) ^ ((fr & 7) << 4);

  const int sc = (lane * 16) & 127;
  const size_t laneoff = (size_t)(lane >> 3) * K2 + (size_t)(sc ^ ((lane >> 3) << 4));
  const char* Asrc = (const char*)(A + (size_t)m0 * K) + laneoff;
  const char* Bsrc = (const char*)(Bt + (size_t)n0 * K) + laneoff;
  const int arow_wv = (wv >> 2) * 64 + (wv & 3) * 8;   // A: wm half + sub-row
  const int brow_wv = (wv >> 2) * 64 + (wv & 3) * 8;   // B: same shape within call

  f32x4 acc[4][4];
  #pragma unroll
  for (int i = 0; i < 4; ++i)
    #pragma unroll
    for (int j = 0; j < 4; ++j) acc[i][j] = (f32x4){0.f, 0.f, 0.f, 0.f};

  // A call c (=mh): LDS rows' c*64..+63 = [wm0 rows c*32..+31][wm1 rows 64+c*32..+31]
  auto stageA = [&](int b, int c, int kt) {
    GLDS16(Asrc + (size_t)(arow_wv + c * 32) * K2 + (size_t)kt * 128,
           lds + b * 49152 + c * 8192 + wv * 1024);
  };
  // B call j (= nh*2 + w2): global row = w2*128 + (wv>>2)*64 + nh*32 + (wv&3)*8 + srow
  auto stageB = [&](int b, int j, int kt) {
    GLDS16(Bsrc + (size_t)((j & 1) * 128 + (j >> 1) * 32 + brow_wv) * K2 + (size_t)kt * 128,
           lds + b * 49152 + 16384 + j * 8192 + wv * 1024);
  };

  // prologue: tile0 full, tile1 {A-c0, B-nh0}
  stageA(0, 0, 0); stageA(0, 1, 0);
  stageB(0, 0, 0); stageB(0, 1, 0); stageB(0, 2, 0); stageB(0, 3, 0);
  stageA(1, 0, 1); stageB(1, 0, 1); stageB(1, 1, 1);
  __builtin_amdgcn_sched_barrier(0);
  asm volatile("s_waitcnt vmcnt(3)" ::: "memory");
  __builtin_amdgcn_s_barrier();

  for (int i = 0; i < nIter; ++i) {
    const bool last = (i == nIter - 1);
    #pragma unroll
    for (int p = 0; p < 8; ++p) {
      const int b  = p >> 2;
      const int mh = (p >> 1) & 1;
      const int nh = p & 1;
      const char* Ab = lds + b * 49152;
      const char* Bb = Ab + 16384;
      __builtin_amdgcn_sched_barrier(0);
      short8 fa[2][2], fb[2][2];
      #pragma unroll
      for (int j = 0; j < 2; ++j) {
        const int row = mh * 64 + wm * 32 + j * 16 + fr;
        fa[j][0] = *(const short8*)(Ab + row * 128 + csw0);
        fa[j][1] = *(const short8*)(Ab + row * 128 + csw1);
      }
      #pragma unroll
      for (int n = 0; n < 2; ++n) {
        const int row = nh * 128 + (wn >> 1) * 64 + (wn & 1) * 32 + n * 16 + fr;
        fb[n][0] = *(const short8*)(Bb + row * 128 + csw0);
        fb[n][1] = *(const short8*)(Bb + row * 128 + csw1);
      }
      if (p == 0) stageA(1, 1, 2 * i + 1);
      if (p == 1) { stageB(1, 2, 2 * i + 1); stageB(1, 3, 2 * i + 1); }
      if (!last) {
        if (p == 2) stageA(0, 0, 2 * i + 2);
        if (p == 3) { stageB(0, 0, 2 * i + 2); stageB(0, 1, 2 * i + 2); }
        if (p == 4) stageA(0, 1, 2 * i + 2);
        if (p == 5) { stageB(0, 2, 2 * i + 2); stageB(0, 3, 2 * i + 2); }
        if (p == 6) stageA(1, 0, 2 * i + 3);
        if (p == 7) { stageB(1, 0, 2 * i + 3); stageB(1, 1, 2 * i + 3); }
      }
      __builtin_amdgcn_sched_barrier(0);
      __builtin_amdgcn_s_barrier();
      __builtin_amdgcn_sched_barrier(0);
      __builtin_amdgcn_s_setprio(1);
      #pragma unroll
      for (int j = 0; j < 2; ++j)
        #pragma unroll
        for (int n = 0; n < 2; ++n) {
          acc[mh * 2 + j][nh * 2 + n] = __builtin_amdgcn_mfma_f32_16x16x32_bf16(
              fa[j][0], fb[n][0], acc[mh * 2 + j][nh * 2 + n], 0, 0, 0);
          acc[mh * 2 + j][nh * 2 + n] = __builtin_amdgcn_mfma_f32_16x16x32_bf16(
              fa[j][1], fb[n][1], acc[mh * 2 + j][nh * 2 + n], 0, 0, 0);
        }
      __builtin_amdgcn_s_setprio(0);
      __builtin_amdgcn_sched_barrier(0);
      if (p == 3) {
        if (!last) asm volatile("s_waitcnt vmcnt(3)" ::: "memory");
        else       asm volatile("s_waitcnt vmcnt(0)" ::: "memory");
      }
      if (p == 7 && !last)
        asm volatile("s_waitcnt vmcnt(3)" ::: "memory");
      __builtin_amdgcn_s_barrier();
    }
  }

  #pragma unroll
  for (int mi = 0; mi < 4; ++mi) {
    #pragma unroll
    for (int ni = 0; ni < 4; ++ni) {
      const int col = n0 + wn * 64 + ni * 16 + fr;
      float bv = HAS_BIAS ? bias[col] : 0.0f;
      const int rbase = m0 + wm * 64 + mi * 16 + fg * 4;
      float vals[4];
      #pragma unroll
      for (int r = 0; r < 4; ++r) {
        float val = acc[mi][ni][r] + bv;
        if (GELU_ACT) val = 0.5f * val * (1.0f + erff(val * 0.70710678118f));
        vals[r] = val;
      }
      if (OMODE == 1) {
        #pragma unroll
        for (int r = 0; r < 4; ++r)
          ((unsigned short*)out)[(size_t)(rbase + r) * N + col] = f2bf(vals[r]);
      } else {
        if (col < 2 * E_DIM) {
          #pragma unroll
          for (int r = 0; r < 4; ++r)
            ((unsigned short*)out)[(size_t)(rbase + r) * 2 * E_DIM + col] = f2bf(vals[r]);
        } else {
          const int c2 = col - 2 * E_DIM;
          const int hh = c2 >> 6, d = c2 & 63;
          const int bb = rbase >> 10, t0 = rbase & (T_SEQ - 1);
          ushort4 o;
          o.x = f2bf(vals[0]); o.y = f2bf(vals[1]);
          o.z = f2bf(vals[2]); o.w = f2bf(vals[3]);
          *(ushort4*)(vt + ((size_t)(bb * H_HEADS + hh) * D_HEAD + d) * T_SEQ + t0) = o;
        }
      }
    }
  }
}

// ---------------- 256x256 8-phase bf16 GEMM (LM head) ----------------
__global__ __launch_bounds__(512, 1) void gemm8p_kernel(
    const unsigned short* __restrict__ A, const unsigned short* __restrict__ Bt,
    const float* __restrict__ bias, float* __restrict__ out, int M, int N, int K) {
  __shared__ __align__(16) char lds[131072];
  const int tid  = threadIdx.x;
  const int lane = tid & 63;
  const int wv   = tid >> 6;
  const int wm = wv >> 2, wn = wv & 3;

  const int mt = M >> 8;
  const int q8 = gridDim.x >> 3;
  const int g  = (blockIdx.x & 7) * q8 + (blockIdx.x >> 3);
  const int m0 = (g % mt) * 256, n0 = (g / mt) * 256;

  const int fr = lane & 15, fg = lane >> 4;
  const size_t K2 = (size_t)K * 2;
  const int nIter = K >> 7;

  const int csw0 = (fg * 16) ^ ((fr & 7) << 4);
  const int csw1 = (64 + fg * 16) ^ ((fr & 7) << 4);

  const int sc = (lane * 16) & 127;
  const size_t laneoff = (size_t)(lane >> 3) * K2 + (size_t)(sc ^ ((lane >> 3) << 4));
  const char* Asrc = (const char*)(A + (size_t)m0 * K) + (size_t)(wv * 8) * K2 + laneoff;
  const char* Bsrc = (const char*)(Bt + (size_t)n0 * K) + laneoff;

  f32x4 acc[8][4];
  #pragma unroll
  for (int i = 0; i < 8; ++i)
    #pragma unroll
    for (int j = 0; j < 4; ++j) acc[i][j] = (f32x4){0.f, 0.f, 0.f, 0.f};

  auto stageA = [&](int b, int q, int kt) {
    GLDS16(Asrc + (size_t)(q * 64) * K2 + (size_t)kt * 128,
           lds + b * 65536 + q * 8192 + wv * 1024);
  };
  auto stageB = [&](int b, int j, int o, int kt) {
    const int gw = j * 64 + wv * 8;
    const int rw = ((gw >> 5) << 6) + (gw & 31) + o * 32;
    GLDS16(Bsrc + (size_t)rw * K2 + (size_t)kt * 128,
           lds + b * 65536 + 32768 + rw * 128);
  };

  stageA(0, 0, 0); stageA(0, 2, 0);
  stageB(0, 0, 0, 0); stageB(0, 1, 0, 0);
  stageA(0, 1, 0); stageA(0, 3, 0);
  stageB(0, 0, 1, 0); stageB(0, 1, 1, 0);
  stageA(1, 0, 1); stageA(1, 2, 1);
  stageB(1, 0, 0, 1); stageB(1, 1, 0, 1);
  __builtin_amdgcn_sched_barrier(0);
  asm volatile("s_waitcnt vmcnt(4)" ::: "memory");
  __builtin_amdgcn_s_barrier();

  for (int i = 0; i < nIter; ++i) {
    const bool last = (i == nIter - 1);
    #pragma unroll
    for (int p = 0; p < 8; ++p) {
      const int b  = p >> 2;
      const int mh = (p & 3) >> 1;
      const int nh = p & 1;
      const char* Ab = lds + b * 65536;
      const char* Bb = Ab + 32768;
      __builtin_amdgcn_sched_barrier(0);
      short8 fa[4][2], fb[2][2];
      #pragma unroll
      for (int j = 0; j < 4; ++j) {
        const int row = wm * 128 + mh * 64 + j * 16 + fr;
        fa[j][0] = *(const short8*)(Ab + row * 128 + csw0);
        fa[j][1] = *(const short8*)(Ab + row * 128 + csw1);
      }
      #pragma unroll
      for (int n = 0; n < 2; ++n) {
        const int row = wn * 64 + nh * 32 + n * 16 + fr;
        fb[n][0] = *(const short8*)(Bb + row * 128 + csw0);
        fb[n][1] = *(const short8*)(Bb + row * 128 + csw1);
      }
      if (p == 0) { stageA(1, 1, 2 * i + 1); stageA(1, 3, 2 * i + 1); }
      if (p == 1) { stageB(1, 0, 1, 2 * i + 1); stageB(1, 1, 1, 2 * i + 1); }
      if (!last) {
        if (p == 2) { stageA(0, 0, 2 * i + 2); stageA(0, 2, 2 * i + 2); }
        if (p == 3) { stageB(0, 0, 0, 2 * i + 2); stageB(0, 1, 0, 2 * i + 2); }
        if (p == 4) { stageA(0, 1, 2 * i + 2); stageA(0, 3, 2 * i + 2); }
        if (p == 5) { stageB(0, 0, 1, 2 * i + 2); stageB(0, 1, 1, 2 * i + 2); }
        if (p == 6) { stageA(1, 0, 2 * i + 3); stageA(1, 2, 2 * i + 3); }
        if (p == 7) { stageB(1, 0, 0, 2 * i + 3); stageB(1, 1, 0, 2 * i + 3); }
      }
      __builtin_amdgcn_sched_barrier(0);
      __builtin_amdgcn_s_barrier();
      __builtin_amdgcn_sched_barrier(0);
      __builtin_amdgcn_s_setprio(1);
      #pragma unroll
      for (int j = 0; j < 4; ++j)
        #pragma unroll
        for (int n = 0; n < 2; ++n) {
          acc[mh * 4 + j][nh * 2 + n] = __builtin_amdgcn_mfma_f32_16x16x32_bf16(
              fa[j][0], fb[n][0], acc[mh * 4 + j][nh * 2 + n], 0, 0, 0);
          acc[mh * 4 + j][nh * 2 + n] = __builtin_amdgcn_mfma_f32_16x16x32_bf16(
              fa[j][1], fb[n][1], acc[mh * 4 + j][nh * 2 + n], 0, 0, 0);
        }
      __builtin_amdgcn_s_setprio(0);
      __builtin_amdgcn_sched_barrier(0);
      if (p == 3) {
        if (!last) asm volatile("s_waitcnt vmcnt(4)" ::: "memory");
        else       asm volatile("s_waitcnt vmcnt(0)" ::: "memory");
      }
      if (p == 7 && !last)
        asm volatile("s_waitcnt vmcnt(4)" ::: "memory");
      __builtin_amdgcn_s_barrier();
    }
  }

  #pragma unroll
  for (int mi = 0; mi < 8; ++mi) {
    #pragma unroll
    for (int ni = 0; ni < 4; ++ni) {
      const int col = n0 + wn * 64 + ni * 16 + fr;
      const float bv = bias[col];
      #pragma unroll
      for (int r = 0; r < 4; ++r) {
        const int row = m0 + wm * 128 + mi * 16 + fg * 4 + r;
        out[(size_t)row * N + col] = acc[mi][ni][r] + bv;
      }
    }
  }
}

extern "C" void kernel_launch(void* const* d_in, const int* in_sizes, int n_in,
                              void* d_out, int out_size, void* d_ws, size_t ws_size,
                              hipStream_t stream) {
  const int*   idx   = (const int*)  d_in[0];
  const float* tok_w = (const float*)d_in[1];
  const float* pos_w = (const float*)d_in[2];
  const float* ln1_g = (const float*)d_in[3];
  const float* ln1_b = (const float*)d_in[4];
  const float* wq    = (const float*)d_in[5];
  const float* wk    = (const float*)d_in[6];
  const float* wv    = (const float*)d_in[7];
  const float* wp    = (const float*)d_in[8];
  const float* bp    = (const float*)d_in[9];
  const float* ln2_g = (const float*)d_in[10];
  const float* ln2_b = (const float*)d_in[11];
  const float* w1    = (const float*)d_in[12];
  const float* b1    = (const float*)d_in[13];
  const float* w2    = (const float*)d_in[14];
  const float* b2    = (const float*)d_in[15];
  const float* lnf_g = (const float*)d_in[16];
  const float* lnf_b = (const float*)d_in[17];
  const float* wlm   = (const float*)d_in[18];
  const float* blm   = (const float*)d_in[19];

  const int M = B_BATCH * T_SEQ;  // 2048
  const size_t EE = (size_t)E_DIM * E_DIM;
  const size_t EF = (size_t)E_DIM * F_DIM;
  char* p = (char*)d_ws;
  float* x            = (float*)p;          p += (size_t)M * E_DIM * 4;
  unsigned short* hb  = (unsigned short*)p; p += (size_t)M * E_DIM * 2;
  unsigned short* qkb = (unsigned short*)p; p += (size_t)M * 2 * E_DIM * 2;
  unsigned short* vtb = (unsigned short*)p; p += (size_t)M * E_DIM * 2;
  unsigned short* yb  = (unsigned short*)p; p += (size_t)M * E_DIM * 2;
  unsigned short* tb  = (unsigned short*)p; p += (size_t)M * F_DIM * 2;
  unsigned short* wtb = (unsigned short*)p; p += (size_t)V_VOCAB * E_DIM * 2;

  embed_kernel<<<M * E_DIM / 4 / 256, 256, 0, stream>>>(idx, tok_w, pos_w, x);

  for (int l = 0; l < L_LAYERS; ++l) {
    wtrans6_kernel<<<3072, 256, 0, stream>>>(
        wq + l * EE, wk + l * EE, wv + l * EE, wp + l * EE,
        w1 + l * EF, w2 + l * EF, wtb);
    ln_kernel<<<M, 256, 0, stream>>>(x, ln1_g + (size_t)l * E_DIM, ln1_b + (size_t)l * E_DIM, hb);
    gemm8p2_kernel<2, false, false>
        <<<(M / 128) * (3 * E_DIM / 256), 512, 0, stream>>>(
        hb, wtb, nullptr, qkb, vtb, M, 3 * E_DIM, E_DIM);
    attn_mfma_kernel<<<dim3(16, B_BATCH * H_HEADS), 512, 0, stream>>>(qkb, vtb, yb);
    gemm_bt_kernel<64, 128, true, false, true, 0>
        <<<(M / 64) * (E_DIM / 128), 256, 0, stream>>>(
        yb, wtb + 3 * EE, bp + (size_t)l * E_DIM, x, x, nullptr, M, E_DIM, E_DIM);
    ln_kernel<<<M, 256, 0, stream>>>(x, ln2_g + (size_t)l * E_DIM, ln2_b + (size_t)l * E_DIM, hb);
    gemm8p2_kernel<1, true, true>
        <<<(M / 128) * (F_DIM / 256), 512, 0, stream>>>(
        hb, wtb + 4 * EE, b1 + (size_t)l * F_DIM, tb, nullptr, M, F_DIM, E_DIM);
    gemm_bt_kernel<64, 128, true, false, true, 0>
        <<<(M / 64) * (E_DIM / 128), 256, 0, stream>>>(
        tb, wtb + 4 * EE + EF, b2 + (size_t)l * E_DIM, x, x, nullptr, M, E_DIM, F_DIM);
  }
  ln_kernel<<<M, 256, 0, stream>>>(x, lnf_g, lnf_b, hb);
  wtrans_kernel<<<dim3(V_VOCAB / 64, E_DIM / 64), 256, 0, stream>>>(wlm, wtb, E_DIM, V_VOCAB);
  gemm8p_kernel<<<(M / 256) * (V_VOCAB / 256), 512, 0, stream>>>(
      hb, wtb, blm, (float*)d_out, M, V_VOCAB, E_DIM);
}

// Round 12
// 1291.962 us; speedup vs baseline: 8.5844x; 1.0039x over previous
//
#include <hip/hip_runtime.h>

#define T_SEQ   1024
#define E_DIM   1024
#define H_HEADS 16
#define D_HEAD  64
#define L_LAYERS 6
#define B_BATCH 2
#define F_DIM   4096
#define V_VOCAB 32000

typedef float f32x4 __attribute__((ext_vector_type(4)));
typedef short short8 __attribute__((ext_vector_type(8)));

__device__ __forceinline__ unsigned short f2bf(float f) {
  union { float f; unsigned int u; } v; v.f = f;
  unsigned int r = v.u + 0x7fffu + ((v.u >> 16) & 1u);  // RNE
  return (unsigned short)(r >> 16);
}

// async global->LDS, 16B per lane; lds dest = wave-uniform base + lane*16
#define GLDS16(gp, lp) __builtin_amdgcn_global_load_lds( \
    (const __attribute__((address_space(1))) void*)(gp), \
    (__attribute__((address_space(3))) void*)(lp), 16, 0, 0)

// ---------------- embedding: x = tok_w[idx] + pos_w ----------------
__global__ void embed_kernel(const int* __restrict__ idx, const float* __restrict__ tok,
                             const float* __restrict__ pos, float* __restrict__ x) {
  int i = blockIdx.x * 256 + threadIdx.x;
  int bt = i >> 8;
  int e4 = i & 255;
  int t  = bt & (T_SEQ - 1);
  int tokid = idx[bt];
  f32x4 a = *(const f32x4*)(tok + (size_t)tokid * E_DIM + e4 * 4);
  f32x4 p = *(const f32x4*)(pos + (size_t)t * E_DIM + e4 * 4);
  *(f32x4*)(x + (size_t)bt * E_DIM + e4 * 4) = a + p;
}

// ---------------- layernorm body (f32 in, bf16 out), 256 threads ----------------
__device__ __forceinline__ void ln_body(const float* __restrict__ x,
    const float* __restrict__ g, const float* __restrict__ b,
    unsigned short* __restrict__ out, int row) {
  int tid = threadIdx.x;
  const float* xr = x + (size_t)row * E_DIM;
  f32x4 v = *(const f32x4*)(xr + tid * 4);
  float s  = v[0] + v[1] + v[2] + v[3];
  float s2 = v[0]*v[0] + v[1]*v[1] + v[2]*v[2] + v[3]*v[3];
  #pragma unroll
  for (int off = 32; off > 0; off >>= 1) {
    s  += __shfl_xor(s,  off);
    s2 += __shfl_xor(s2, off);
  }
  __shared__ float red[2][4];
  int wave = tid >> 6;
  if ((tid & 63) == 0) { red[0][wave] = s; red[1][wave] = s2; }
  __syncthreads();
  s  = red[0][0] + red[0][1] + red[0][2] + red[0][3];
  s2 = red[1][0] + red[1][1] + red[1][2] + red[1][3];
  float mean = s * (1.0f / E_DIM);
  float var  = s2 * (1.0f / E_DIM) - mean * mean;
  float rstd = rsqrtf(var + 1e-5f);
  f32x4 gv = *(const f32x4*)(g + tid * 4);
  f32x4 bv = *(const f32x4*)(b + tid * 4);
  ushort4 o;
  o.x = f2bf((v[0] - mean) * rstd * gv[0] + bv[0]);
  o.y = f2bf((v[1] - mean) * rstd * gv[1] + bv[1]);
  o.z = f2bf((v[2] - mean) * rstd * gv[2] + bv[2]);
  o.w = f2bf((v[3] - mean) * rstd * gv[3] + bv[3]);
  *(ushort4*)(out + (size_t)row * E_DIM + tid * 4) = o;
}

__global__ void ln_kernel(const float* __restrict__ x, const float* __restrict__ g,
                          const float* __restrict__ b, unsigned short* __restrict__ out) {
  ln_body(x, g, b, out, blockIdx.x);
}

// ---------------- weight transpose+convert: W f32 [K][N] -> Wt bf16 [N][K] ----------------
__device__ __forceinline__ void wtrans_body(const float* __restrict__ W,
    unsigned short* __restrict__ Wt, int K, int N, int bx, int by) {
  __shared__ float tile[64][65];
  const int n0 = bx * 64, k0 = by * 64;
  const int tr  = threadIdx.x >> 4;
  const int tc4 = (threadIdx.x & 15) * 4;
  #pragma unroll
  for (int p = 0; p < 4; ++p) {
    f32x4 v = *(const f32x4*)(W + (size_t)(k0 + p * 16 + tr) * N + n0 + tc4);
    tile[p * 16 + tr][tc4 + 0] = v[0];
    tile[p * 16 + tr][tc4 + 1] = v[1];
    tile[p * 16 + tr][tc4 + 2] = v[2];
    tile[p * 16 + tr][tc4 + 3] = v[3];
  }
  __syncthreads();
  #pragma unroll
  for (int p = 0; p < 4; ++p) {
    int n = p * 16 + tr;
    ushort4 o;
    o.x = f2bf(tile[tc4 + 0][n]);
    o.y = f2bf(tile[tc4 + 1][n]);
    o.z = f2bf(tile[tc4 + 2][n]);
    o.w = f2bf(tile[tc4 + 3][n]);
    *(ushort4*)(Wt + (size_t)(n0 + n) * K + k0 + tc4) = o;
  }
}

// layer weights (q,k,v,p,w1,w2) + ln1 in one launch; grid = 3072 + 2048
__global__ __launch_bounds__(256) void wtrans6ln_kernel(const float* __restrict__ wq,
    const float* __restrict__ wk, const float* __restrict__ wv, const float* __restrict__ wp,
    const float* __restrict__ w1, const float* __restrict__ w2,
    const float* __restrict__ lng, const float* __restrict__ lnb,
    const float* __restrict__ x, unsigned short* __restrict__ wtb,
    unsigned short* __restrict__ hb) {
  const size_t EE = (size_t)E_DIM * E_DIM;
  const size_t EF = (size_t)E_DIM * F_DIM;
  const int id = blockIdx.x;
  if (id < 1024) {
    const int z = id >> 8, r = id & 255;
    const float* W = z == 0 ? wq : (z == 1 ? wk : (z == 2 ? wv : wp));
    wtrans_body(W, wtb + z * EE, E_DIM, E_DIM, r & 15, r >> 4);
  } else if (id < 2048) {
    const int r = id - 1024;
    wtrans_body(w1, wtb + 4 * EE, E_DIM, F_DIM, r & 63, r >> 6);
  } else if (id < 3072) {
    const int r = id - 2048;
    wtrans_body(w2, wtb + 4 * EE + EF, F_DIM, E_DIM, r & 15, r >> 4);
  } else {
    ln_body(x, lng, lnb, hb, id - 3072);
  }
}

// LM weight transpose + final layernorm; grid = 8000 + 2048
__global__ __launch_bounds__(256) void wtransv_ln_kernel(const float* __restrict__ wlm,
    const float* __restrict__ lng, const float* __restrict__ lnb,
    const float* __restrict__ x, unsigned short* __restrict__ wtb,
    unsigned short* __restrict__ hb) {
  const int id = blockIdx.x;
  if (id < 8000) wtrans_body(wlm, wtb, E_DIM, V_VOCAB, id % 500, id / 500);
  else           ln_body(x, lng, lnb, hb, id - 8000);
}

// ---------------- MFMA flash attention, split-key, all-waves-busy ----------------
__global__ __launch_bounds__(512) void attn_mfma_kernel(
    const unsigned short* __restrict__ qk, const unsigned short* __restrict__ vt,
    unsigned short* __restrict__ y) {
  __shared__ __align__(16) char smem[2 * 16384 + 8 * 1280 + 512];
  const int tid  = threadIdx.x;
  const int lane = tid & 63;
  const int wave = tid >> 6;
  const int wl = wave & 3;
  const int g  = wave >> 2;
  const int qx = blockIdx.x;
  const int h  = blockIdx.y & (H_HEADS - 1);
  const int b  = blockIdx.y >> 4;
  const int qt = b ? (15 - qx) : qx;
  const int r0 = qt * 64 + wl * 16;
  const size_t RS = 2 * E_DIM;
  const unsigned short* q  = qk + (size_t)b * T_SEQ * RS + (size_t)h * D_HEAD;
  const unsigned short* k  = q + E_DIM;
  const unsigned short* vb = vt + (size_t)(b * H_HEADS + h) * D_HEAD * T_SEQ;
  const size_t ybase = (size_t)b * T_SEQ * E_DIM + (size_t)h * D_HEAD;
  const int fr = lane & 15, fg = lane >> 4;
  const int srow = lane >> 3;
  const int ssw  = ((lane & 7) * 16) ^ (srow << 4);
  char* pb = smem + 32768 + wave * 1280;
  float* mlb = (float*)(smem + 32768 + 10240);

  short8 aq[2];
  #pragma unroll
  for (int c = 0; c < 2; ++c)
    aq[c] = *(const short8*)(q + (size_t)(r0 + fr) * RS + c * 32 + fg * 8);

  f32x4 oacc[4];
  #pragma unroll
  for (int cg = 0; cg < 4; ++cg) oacc[cg] = (f32x4){0.f, 0.f, 0.f, 0.f};
  float m_ = -1e30f, l_ = 0.0f;

  auto stage = [&](int t) {
    const int j0 = t * 64;
    char* Kd = smem + (t & 1) * 16384;
    GLDS16((const char*)k  + (size_t)(j0 + wave * 8 + srow) * RS * 2 + ssw,
           Kd + wave * 1024);
    GLDS16((const char*)vb + ((size_t)(wave * 8 + srow) * T_SEQ + j0) * 2 + ssw,
           Kd + 8192 + wave * 1024);
  };

  stage(0);
  for (int t = 0; t <= qt; ++t) {
    __builtin_amdgcn_sched_barrier(0);
    __builtin_amdgcn_s_barrier();
    if (t < qt) stage(t + 1);
    __builtin_amdgcn_sched_barrier(0);
    if (t < qt) asm volatile("s_waitcnt vmcnt(2)" ::: "memory");
    else        asm volatile("s_waitcnt vmcnt(0)" ::: "memory");
    __builtin_amdgcn_sched_barrier(0);
    __builtin_amdgcn_s_barrier();
    __builtin_amdgcn_sched_barrier(0);
    const char* Kl = smem + (t & 1) * 16384;
    const char* Vl = Kl + 8192;
    const int j0 = t * 64;
    if (!(t == qt && g == 1 && wl < 2)) {
      f32x4 st[2];
      #pragma unroll
      for (int cc = 0; cc < 2; ++cc) {
        const int kloc = g * 32 + cc * 16 + fr;
        const char* kb = Kl + kloc * 128;
        const int sw = (kloc & 7) << 4;
        short8 ka0 = *(const short8*)(kb + ((fg * 16) ^ sw));
        short8 ka1 = *(const short8*)(kb + ((64 + fg * 16) ^ sw));
        f32x4 z = (f32x4){0.f, 0.f, 0.f, 0.f};
        z = __builtin_amdgcn_mfma_f32_16x16x32_bf16(ka0, aq[0], z, 0, 0, 0);
        z = __builtin_amdgcn_mfma_f32_16x16x32_bf16(ka1, aq[1], z, 0, 0, 0);
        st[cc] = z;
      }
      const int qg = r0 + fr;
      float pv[2][4];
      float mx = -1e30f;
      #pragma unroll
      for (int cc = 0; cc < 2; ++cc)
        #pragma unroll
        for (int r = 0; r < 4; ++r) {
          const int kj = j0 + g * 32 + cc * 16 + fg * 4 + r;
          float val = (kj <= qg) ? st[cc][r] * 0.125f : -1e30f;
          pv[cc][r] = val;
          mx = fmaxf(mx, val);
        }
      mx = fmaxf(mx, __shfl_xor(mx, 16));
      mx = fmaxf(mx, __shfl_xor(mx, 32));
      const float mn = fmaxf(m_, mx);
      const float cfs = __expf(m_ - mn);
      float ls = 0.0f;
      #pragma unroll
      for (int cc = 0; cc < 2; ++cc) {
        ushort4 o;
        float e0 = pv[cc][0] > -1e29f ? __expf(pv[cc][0] - mn) : 0.0f;
        float e1 = pv[cc][1] > -1e29f ? __expf(pv[cc][1] - mn) : 0.0f;
        float e2 = pv[cc][2] > -1e29f ? __expf(pv[cc][2] - mn) : 0.0f;
        float e3 = pv[cc][3] > -1e29f ? __expf(pv[cc][3] - mn) : 0.0f;
        ls += (e0 + e1) + (e2 + e3);
        o.x = f2bf(e0); o.y = f2bf(e1); o.z = f2bf(e2); o.w = f2bf(e3);
        *(ushort4*)(pb + fr * 80 + cc * 32 + fg * 8) = o;
      }
      ls += __shfl_xor(ls, 16);
      ls += __shfl_xor(ls, 32);
      l_ = l_ * cfs + ls;
      m_ = mn;
      float cfO[4];
      #pragma unroll
      for (int r = 0; r < 4; ++r) cfO[r] = __shfl(cfs, (lane & 48) | (fg * 4 + r));
      asm volatile("s_waitcnt lgkmcnt(0)" ::: "memory");
      __builtin_amdgcn_sched_barrier(0);
      short8 pa = *(const short8*)(pb + fr * 80 + fg * 16);
      __builtin_amdgcn_s_setprio(1);
      #pragma unroll
      for (int cg = 0; cg < 4; ++cg) {
        const int d = cg * 16 + fr;
        short8 bv = *(const short8*)(Vl + d * 128 + ((g * 64 + fg * 16) ^ ((d & 7) << 4)));
        #pragma unroll
        for (int r = 0; r < 4; ++r) oacc[cg][r] *= cfO[r];
        oacc[cg] = __builtin_amdgcn_mfma_f32_16x16x32_bf16(pa, bv, oacc[cg], 0, 0, 0);
      }
      __builtin_amdgcn_s_setprio(0);
    }
  }
  __syncthreads();
  float* obuf = (float*)smem;
  if (g == 1) {
    #pragma unroll
    for (int cg = 0; cg < 4; ++cg)
      #pragma unroll
      for (int r = 0; r < 4; ++r)
        obuf[wl * 1024 + (fg * 4 + r) * 64 + cg * 16 + fr] = oacc[cg][r];
    if (fg == 0) { mlb[(wl * 16 + fr) * 2] = m_; mlb[(wl * 16 + fr) * 2 + 1] = l_; }
  }
  __syncthreads();
  if (g == 0) {
    const float m1 = mlb[(wl * 16 + fr) * 2];
    const float l1 = mlb[(wl * 16 + fr) * 2 + 1];
    const float m  = fmaxf(m_, m1);
    const float c0 = __expf(m_ - m), c1 = __expf(m1 - m);
    const float li = 1.0f / (l_ * c0 + l1 * c1);
    float c0O[4], c1O[4], liO[4];
    #pragma unroll
    for (int r = 0; r < 4; ++r) {
      const int src = (lane & 48) | (fg * 4 + r);
      c0O[r] = __shfl(c0, src); c1O[r] = __shfl(c1, src); liO[r] = __shfl(li, src);
    }
    #pragma unroll
    for (int cg = 0; cg < 4; ++cg)
      #pragma unroll
      for (int r = 0; r < 4; ++r) {
        const float o1 = obuf[wl * 1024 + (fg * 4 + r) * 64 + cg * 16 + fr];
        const float val = (oacc[cg][r] * c0O[r] + o1 * c1O[r]) * liO[r];
        y[ybase + (size_t)(r0 + fg * 4 + r) * E_DIM + cg * 16 + fr] = f2bf(val);
      }
  }
}

// ---------------- 128-tile bf16 GEMM, BK=64, 2-barrier (proj / MLP2) ----------------
// OMODE 0: f32 out (+res), LDS-transposed coalesced epilogue.
// Unified smem so the per-wave epilogue scratch is provably in-bounds.
template<int BM, int BN, bool HAS_BIAS, bool GELU_ACT, bool HAS_RES, int OMODE>
__global__ __launch_bounds__(256) void gemm_bt_kernel(
    const unsigned short* __restrict__ A, const unsigned short* __restrict__ Bt,
    const float* __restrict__ bias, const float* __restrict__ res,
    void* __restrict__ out, unsigned short* __restrict__ vt, int M, int N, int K) {
  constexpr int BK = 64;
  constexpr int MR = BM / 32;
  constexpr int NR = BN / 32;
  constexpr int AI = BM / 32;
  constexpr int BI = BN / 32;
  __shared__ __align__(16) char smem[(BM + BN) * BK * 2];   // As | Bs (and epilogue scratch)
  unsigned short* As = (unsigned short*)smem;
  unsigned short* Bs = (unsigned short*)(smem + (size_t)BM * BK * 2);
  const int tid  = threadIdx.x;
  const int lane = tid & 63;
  const int wave = tid >> 6;
  const int wr = wave >> 1, wc = wave & 1;

  const int mt = M / BM;
  const int q8 = gridDim.x >> 3;
  const int g  = (blockIdx.x & 7) * q8 + (blockIdx.x >> 3);
  const int m0 = (g % mt) * BM, n0 = (g / mt) * BN;

  const int fr = lane & 15, fg = lane >> 4;
  const int lrow = lane >> 3;
  const int scol = ((lane & 7) * 16) ^ (lrow << 4);
  const size_t K2 = (size_t)K * 2;
  const char* aG = (const char*)A  + (size_t)(m0 + wave * 8 + lrow) * K2 + scol;
  const char* bG = (const char*)Bt + (size_t)(n0 + wave * 8 + lrow) * K2 + scol;

  f32x4 acc[MR][NR];
  #pragma unroll
  for (int mi = 0; mi < MR; ++mi)
    #pragma unroll
    for (int ni = 0; ni < NR; ++ni) acc[mi][ni] = (f32x4){0.f, 0.f, 0.f, 0.f};

  for (int k0 = 0; k0 < K; k0 += BK) {
    __syncthreads();
    #pragma unroll
    for (int i = 0; i < AI; ++i)
      GLDS16(aG + (size_t)i * 32 * K2 + (size_t)k0 * 2, (char*)As + wave * 1024 + i * 4096);
    #pragma unroll
    for (int i = 0; i < BI; ++i)
      GLDS16(bG + (size_t)i * 32 * K2 + (size_t)k0 * 2, (char*)Bs + wave * 1024 + i * 4096);
    __syncthreads();

    short8 af[MR][2], bf[NR][2];
    #pragma unroll
    for (int mi = 0; mi < MR; ++mi) {
      const int row = wr * (BM / 2) + mi * 16 + fr;
      #pragma unroll
      for (int kh = 0; kh < 2; ++kh)
        af[mi][kh] = *(const short8*)((const char*)As + row * 128 +
                       ((kh * 64 + fg * 16) ^ ((row & 7) << 4)));
    }
    #pragma unroll
    for (int ni = 0; ni < NR; ++ni) {
      const int row = wc * (BN / 2) + ni * 16 + fr;
      #pragma unroll
      for (int kh = 0; kh < 2; ++kh)
        bf[ni][kh] = *(const short8*)((const char*)Bs + row * 128 +
                       ((kh * 64 + fg * 16) ^ ((row & 7) << 4)));
    }
    #pragma unroll
    for (int mi = 0; mi < MR; ++mi)
      #pragma unroll
      for (int ni = 0; ni < NR; ++ni) {
        acc[mi][ni] = __builtin_amdgcn_mfma_f32_16x16x32_bf16(af[mi][0], bf[ni][0], acc[mi][ni], 0, 0, 0);
        acc[mi][ni] = __builtin_amdgcn_mfma_f32_16x16x32_bf16(af[mi][1], bf[ni][1], acc[mi][ni], 0, 0, 0);
      }
  }

  if (OMODE == 0) {
    // coalesced epilogue: per-wave [16][68] f32 scratch (4 waves x 4352B = 17408B
    // <= 24576B allocation), read back row-major, res added at f32x4, 256B stores.
    __syncthreads();   // all waves done with As/Bs fragments
    float* tw = (float*)(smem + wave * 4352);
    float bv4[NR];
    #pragma unroll
    for (int ni = 0; ni < NR; ++ni)
      bv4[ni] = HAS_BIAS ? bias[n0 + wc * (BN / 2) + ni * 16 + fr] : 0.0f;
    #pragma unroll
    for (int mi = 0; mi < MR; ++mi) {
      #pragma unroll
      for (int ni = 0; ni < NR; ++ni)
        #pragma unroll
        for (int r = 0; r < 4; ++r) {
          float val = acc[mi][ni][r] + bv4[ni];
          if (GELU_ACT) val = 0.5f * val * (1.0f + erff(val * 0.70710678118f));
          tw[(fg * 4 + r) * 68 + ni * 16 + fr] = val;
        }
      asm volatile("s_waitcnt lgkmcnt(0)" ::: "memory");
      __builtin_amdgcn_sched_barrier(0);
      #pragma unroll
      for (int rr = 0; rr < 4; ++rr) {
        const int row = rr * 4 + (lane >> 4);
        const int grow = m0 + wr * (BM / 2) + mi * 16 + row;
        const int gcol = n0 + wc * (BN / 2) + (lane & 15) * 4;
        f32x4 v = *(const f32x4*)&tw[row * 68 + (lane & 15) * 4];
        if (HAS_RES) v += *(const f32x4*)(res + (size_t)grow * N + gcol);
        *(f32x4*)((float*)out + (size_t)grow * N + gcol) = v;
      }
      asm volatile("s_waitcnt lgkmcnt(0)" ::: "memory");
      __builtin_amdgcn_sched_barrier(0);
    }
  } else {
    #pragma unroll
    for (int mi = 0; mi < MR; ++mi)
      #pragma unroll
      for (int ni = 0; ni < NR; ++ni) {
        const int col = n0 + wc * (BN / 2) + ni * 16 + fr;
        float bv = HAS_BIAS ? bias[col] : 0.0f;
        const int rbase = m0 + wr * (BM / 2) + mi * 16 + fg * 4;
        #pragma unroll
        for (int r = 0; r < 4; ++r) {
          float val = acc[mi][ni][r] + bv;
          if (GELU_ACT) val = 0.5f * val * (1.0f + erff(val * 0.70710678118f));
          ((unsigned short*)out)[(size_t)(rbase + r) * N + col] = f2bf(val);
        }
      }
  }
}

// ---------------- 128x256 8-phase bf16 GEMM (QKV / MLP1), T2+T3+T4+T5 ----------------
// OMODE: 1 = bf16 out (LDS-transposed coalesced), 2 = QKV split
template<int OMODE, bool HAS_BIAS, bool GELU_ACT>
__global__ __launch_bounds__(512, 1) void gemm8p2_kernel(
    const unsigned short* __restrict__ A, const unsigned short* __restrict__ Bt,
    const float* __restrict__ bias, void* __restrict__ out,
    unsigned short* __restrict__ vt, int M, int N, int K) {
  __shared__ __align__(16) char lds[98304];
  const int tid  = threadIdx.x;
  const int lane = tid & 63;
  const int wv   = tid >> 6;
  const int wm = wv >> 2, wn = wv & 3;

  const int mt = M >> 7;
  const int q8 = gridDim.x >> 3;
  const int g  = (blockIdx.x & 7) * q8 + (blockIdx.x >> 3);
  const int m0 = (g % mt) * 128, n0 = (g / mt) * 256;

  const int fr = lane & 15, fg = lane >> 4;
  const size_t K2 = (size_t)K * 2;
  const int nIter = K >> 7;

  const int csw0 = (fg * 16) ^ ((fr & 7) << 4);
  const int csw1 = (64 + fg * 16) ^ ((fr & 7) << 4);

  const int sc = (lane * 16) & 127;
  const size_t laneoff = (size_t)(lane >> 3) * K2 + (size_t)(sc ^ ((lane >> 3) << 4));
  const char* Asrc = (const char*)(A + (size_t)m0 * K) + laneoff;
  const char* Bsrc = (const char*)(Bt + (size_t)n0 * K) + laneoff;
  const int arow_wv = (wv >> 2) * 64 + (wv & 3) * 8;
  const int brow_wv = (wv >> 2) * 64 + (wv & 3) * 8;

  f32x4 acc[4][4];
  #pragma unroll
  for (int i = 0; i < 4; ++i)
    #pragma unroll
    for (int j = 0; j < 4; ++j) acc[i][j] = (f32x4){0.f, 0.f, 0.f, 0.f};

  auto stageA = [&](int b, int c, int kt) {
    GLDS16(Asrc + (size_t)(arow_wv + c * 32) * K2 + (size_t)kt * 128,
           lds + b * 49152 + c * 8192 + wv * 1024);
  };
  auto stageB = [&](int b, int j, int kt) {
    GLDS16(Bsrc + (size_t)((j & 1) * 128 + (j >> 1) * 32 + brow_wv) * K2 + (size_t)kt * 128,
           lds + b * 49152 + 16384 + j * 8192 + wv * 1024);
  };

  stageA(0, 0, 0); stageA(0, 1, 0);
  stageB(0, 0, 0); stageB(0, 1, 0); stageB(0, 2, 0); stageB(0, 3, 0);
  stageA(1, 0, 1); stageB(1, 0, 1); stageB(1, 1, 1);
  __builtin_amdgcn_sched_barrier(0);
  asm volatile("s_waitcnt vmcnt(3)" ::: "memory");
  __builtin_amdgcn_s_barrier();

  for (int i = 0; i < nIter; ++i) {
    const bool last = (i == nIter - 1);
    #pragma unroll
    for (int p = 0; p < 8; ++p) {
      const int b  = p >> 2;
      const int mh = (p >> 1) & 1;
      const int nh = p & 1;
      const char* Ab = lds + b * 49152;
      const char* Bb = Ab + 16384;
      __builtin_amdgcn_sched_barrier(0);
      short8 fa[2][2], fb[2][2];
      #pragma unroll
      for (int j = 0; j < 2; ++j) {
        const int row = mh * 64 + wm * 32 + j * 16 + fr;
        fa[j][0] = *(const short8*)(Ab + row * 128 + csw0);
        fa[j][1] = *(const short8*)(Ab + row * 128 + csw1);
      }
      #pragma unroll
      for (int n = 0; n < 2; ++n) {
        const int row = nh * 128 + (wn >> 1) * 64 + (wn & 1) * 32 + n * 16 + fr;
        fb[n][0] = *(const short8*)(Bb + row * 128 + csw0);
        fb[n][1] = *(const short8*)(Bb + row * 128 + csw1);
      }
      if (p == 0) stageA(1, 1, 2 * i + 1);
      if (p == 1) { stageB(1, 2, 2 * i + 1); stageB(1, 3, 2 * i + 1); }
      if (!last) {
        if (p == 2) stageA(0, 0, 2 * i + 2);
        if (p == 3) { stageB(0, 0, 2 * i + 2); stageB(0, 1, 2 * i + 2); }
        if (p == 4) stageA(0, 1, 2 * i + 2);
        if (p == 5) { stageB(0, 2, 2 * i + 2); stageB(0, 3, 2 * i + 2); }
        if (p == 6) stageA(1, 0, 2 * i + 3);
        if (p == 7) { stageB(1, 0, 2 * i + 3); stageB(1, 1, 2 * i + 3); }
      }
      __builtin_amdgcn_sched_barrier(0);
      __builtin_amdgcn_s_barrier();
      __builtin_amdgcn_sched_barrier(0);
      __builtin_amdgcn_s_setprio(1);
      #pragma unroll
      for (int j = 0; j < 2; ++j)
        #pragma unroll
        for (int n = 0; n < 2; ++n) {
          acc[mh * 2 + j][nh * 2 + n] = __builtin_amdgcn_mfma_f32_16x16x32_bf16(
              fa[j][0], fb[n][0], acc[mh * 2 + j][nh * 2 + n], 0, 0, 0);
          acc[mh * 2 + j][nh * 2 + n] = __builtin_amdgcn_mfma_f32_16x16x32_bf16(
              fa[j][1], fb[n][1], acc[mh * 2 + j][nh * 2 + n], 0, 0, 0);
        }
      __builtin_amdgcn_s_setprio(0);
      __builtin_amdgcn_sched_barrier(0);
      if (p == 3) {
        if (!last) asm volatile("s_waitcnt vmcnt(3)" ::: "memory");
        else       asm volatile("s_waitcnt vmcnt(0)" ::: "memory");
      }
      if (p == 7 && !last)
        asm volatile("s_waitcnt vmcnt(3)" ::: "memory");
      __builtin_amdgcn_s_barrier();
    }
  }

  if (OMODE == 1) {
    // coalesced bf16 epilogue: per-wave [16][68] ushort region (8 x 2176B = 17408B)
    unsigned short* tw = (unsigned short*)(lds + wv * 2176);
    float bv4[4];
    #pragma unroll
    for (int ni = 0; ni < 4; ++ni)
      bv4[ni] = HAS_BIAS ? bias[n0 + wn * 64 + ni * 16 + fr] : 0.0f;
    #pragma unroll
    for (int mi = 0; mi < 4; ++mi) {
      #pragma unroll
      for (int ni = 0; ni < 4; ++ni)
        #pragma unroll
        for (int r = 0; r < 4; ++r) {
          float val = acc[mi][ni][r] + bv4[ni];
          if (GELU_ACT) val = 0.5f * val * (1.0f + erff(val * 0.70710678118f));
          tw[(fg * 4 + r) * 68 + ni * 16 + fr] = f2bf(val);
        }
      asm volatile("s_waitcnt lgkmcnt(0)" ::: "memory");
      __builtin_amdgcn_sched_barrier(0);
      #pragma unroll
      for (int rr = 0; rr < 4; ++rr) {
        const int row = rr * 4 + (lane >> 4);
        const int grow = m0 + wm * 64 + mi * 16 + row;
        const int gcol = n0 + wn * 64 + (lane & 15) * 4;
        ushort4 v = *(const ushort4*)&tw[row * 68 + (lane & 15) * 4];
        *(ushort4*)((unsigned short*)out + (size_t)grow * N + gcol) = v;
      }
      asm volatile("s_waitcnt lgkmcnt(0)" ::: "memory");
      __builtin_amdgcn_sched_barrier(0);
    }
  } else {
    #pragma unroll
    for (int mi = 0; mi < 4; ++mi) {
      #pragma unroll
      for (int ni = 0; ni < 4; ++ni) {
        const int col = n0 + wn * 64 + ni * 16 + fr;
        float bv = HAS_BIAS ? bias[col] : 0.0f;
        const int rbase = m0 + wm * 64 + mi * 16 + fg * 4;
        float vals[4];
        #pragma unroll
        for (int r = 0; r < 4; ++r) vals[r] = acc[mi][ni][r] + bv;
        if (col < 2 * E_DIM) {
          #pragma unroll
          for (int r = 0; r < 4; ++r)
            ((unsigned short*)out)[(size_t)(rbase + r) * 2 * E_DIM + col] = f2bf(vals[r]);
        } else {
          const int c2 = col - 2 * E_DIM;
          const int hh = c2 >> 6, d = c2 & 63;
          const int bb = rbase >> 10, t0 = rbase & (T_SEQ - 1);
          ushort4 o;
          o.x = f2bf(vals[0]); o.y = f2bf(vals[1]);
          o.z = f2bf(vals[2]); o.w = f2bf(vals[3]);
          *(ushort4*)(vt + ((size_t)(bb * H_HEADS + hh) * D_HEAD + d) * T_SEQ + t0) = o;
        }
      }
    }
  }
}

// ---------------- 256x256 8-phase bf16 GEMM (LM head) ----------------
__global__ __launch_bounds__(512, 1) void gemm8p_kernel(
    const unsigned short* __restrict__ A, const unsigned short* __restrict__ Bt,
    const float* __restrict__ bias, float* __restrict__ out, int M, int N, int K) {
  __shared__ __align__(16) char lds[131072];
  const int tid  = threadIdx.x;
  const int lane = tid & 63;
  const int wv   = tid >> 6;
  const int wm = wv >> 2, wn = wv & 3;

  const int mt = M >> 8;
  const int q8 = gridDim.x >> 3;
  const int g  = (blockIdx.x & 7) * q8 + (blockIdx.x >> 3);
  const int m0 = (g % mt) * 256, n0 = (g / mt) * 256;

  const int fr = lane & 15, fg = lane >> 4;
  const size_t K2 = (size_t)K * 2;
  const int nIter = K >> 7;

  const int csw0 = (fg * 16) ^ ((fr & 7) << 4);
  const int csw1 = (64 + fg * 16) ^ ((fr & 7) << 4);

  const int sc = (lane * 16) & 127;
  const size_t laneoff = (size_t)(lane >> 3) * K2 + (size_t)(sc ^ ((lane >> 3) << 4));
  const char* Asrc = (const char*)(A + (size_t)m0 * K) + (size_t)(wv * 8) * K2 + laneoff;
  const char* Bsrc = (const char*)(Bt + (size_t)n0 * K) + laneoff;

  f32x4 acc[8][4];
  #pragma unroll
  for (int i = 0; i < 8; ++i)
    #pragma unroll
    for (int j = 0; j < 4; ++j) acc[i][j] = (f32x4){0.f, 0.f, 0.f, 0.f};

  auto stageA = [&](int b, int q, int kt) {
    GLDS16(Asrc + (size_t)(q * 64) * K2 + (size_t)kt * 128,
           lds + b * 65536 + q * 8192 + wv * 1024);
  };
  auto stageB = [&](int b, int j, int o, int kt) {
    const int gw = j * 64 + wv * 8;
    const int rw = ((gw >> 5) << 6) + (gw & 31) + o * 32;
    GLDS16(Bsrc + (size_t)rw * K2 + (size_t)kt * 128,
           lds + b * 65536 + 32768 + rw * 128);
  };

  stageA(0, 0, 0); stageA(0, 2, 0);
  stageB(0, 0, 0, 0); stageB(0, 1, 0, 0);
  stageA(0, 1, 0); stageA(0, 3, 0);
  stageB(0, 0, 1, 0); stageB(0, 1, 1, 0);
  stageA(1, 0, 1); stageA(1, 2, 1);
  stageB(1, 0, 0, 1); stageB(1, 1, 0, 1);
  __builtin_amdgcn_sched_barrier(0);
  asm volatile("s_waitcnt vmcnt(4)" ::: "memory");
  __builtin_amdgcn_s_barrier();

  for (int i = 0; i < nIter; ++i) {
    const bool last = (i == nIter - 1);
    #pragma unroll
    for (int p = 0; p < 8; ++p) {
      const int b  = p >> 2;
      const int mh = (p & 3) >> 1;
      const int nh = p & 1;
      const char* Ab = lds + b * 65536;
      const char* Bb = Ab + 32768;
      __builtin_amdgcn_sched_barrier(0);
      short8 fa[4][2], fb[2][2];
      #pragma unroll
      for (int j = 0; j < 4; ++j) {
        const int row = wm * 128 + mh * 64 + j * 16 + fr;
        fa[j][0] = *(const short8*)(Ab + row * 128 + csw0);
        fa[j][1] = *(const short8*)(Ab + row * 128 + csw1);
      }
      #pragma unroll
      for (int n = 0; n < 2; ++n) {
        const int row = wn * 64 + nh * 32 + n * 16 + fr;
        fb[n][0] = *(const short8*)(Bb + row * 128 + csw0);
        fb[n][1] = *(const short8*)(Bb + row * 128 + csw1);
      }
      if (p == 0) { stageA(1, 1, 2 * i + 1); stageA(1, 3, 2 * i + 1); }
      if (p == 1) { stageB(1, 0, 1, 2 * i + 1); stageB(1, 1, 1, 2 * i + 1); }
      if (!last) {
        if (p == 2) { stageA(0, 0, 2 * i + 2); stageA(0, 2, 2 * i + 2); }
        if (p == 3) { stageB(0, 0, 0, 2 * i + 2); stageB(0, 1, 0, 2 * i + 2); }
        if (p == 4) { stageA(0, 1, 2 * i + 2); stageA(0, 3, 2 * i + 2); }
        if (p == 5) { stageB(0, 0, 1, 2 * i + 2); stageB(0, 1, 1, 2 * i + 2); }
        if (p == 6) { stageA(1, 0, 2 * i + 3); stageA(1, 2, 2 * i + 3); }
        if (p == 7) { stageB(1, 0, 0, 2 * i + 3); stageB(1, 1, 0, 2 * i + 3); }
      }
      __builtin_amdgcn_sched_barrier(0);
      __builtin_amdgcn_s_barrier();
      __builtin_amdgcn_sched_barrier(0);
      __builtin_amdgcn_s_setprio(1);
      #pragma unroll
      for (int j = 0; j < 4; ++j)
        #pragma unroll
        for (int n = 0; n < 2; ++n) {
          acc[mh * 4 + j][nh * 2 + n] = __builtin_amdgcn_mfma_f32_16x16x32_bf16(
              fa[j][0], fb[n][0], acc[mh * 4 + j][nh * 2 + n], 0, 0, 0);
          acc[mh * 4 + j][nh * 2 + n] = __builtin_amdgcn_mfma_f32_16x16x32_bf16(
              fa[j][1], fb[n][1], acc[mh * 4 + j][nh * 2 + n], 0, 0, 0);
        }
      __builtin_amdgcn_s_setprio(0);
      __builtin_amdgcn_sched_barrier(0);
      if (p == 3) {
        if (!last) asm volatile("s_waitcnt vmcnt(4)" ::: "memory");
        else       asm volatile("s_waitcnt vmcnt(0)" ::: "memory");
      }
      if (p == 7 && !last)
        asm volatile("s_waitcnt vmcnt(4)" ::: "memory");
      __builtin_amdgcn_s_barrier();
    }
  }

  // coalesced f32 epilogue: per-wave [16][68] f32 region (8 x 4352B = 34816B)
  float* tw = (float*)(lds + wv * 4352);
  float bv4[4];
  #pragma unroll
  for (int ni = 0; ni < 4; ++ni) bv4[ni] = bias[n0 + wn * 64 + ni * 16 + fr];
  #pragma unroll
  for (int mi = 0; mi < 8; ++mi) {
    #pragma unroll
    for (int ni = 0; ni < 4; ++ni)
      #pragma unroll
      for (int r = 0; r < 4; ++r)
        tw[(fg * 4 + r) * 68 + ni * 16 + fr] = acc[mi][ni][r] + bv4[ni];
    asm volatile("s_waitcnt lgkmcnt(0)" ::: "memory");
    __builtin_amdgcn_sched_barrier(0);
    #pragma unroll
    for (int rr = 0; rr < 4; ++rr) {
      const int row = rr * 4 + (lane >> 4);
      const int grow = m0 + wm * 128 + mi * 16 + row;
      const int gcol = n0 + wn * 64 + (lane & 15) * 4;
      f32x4 v = *(const f32x4*)&tw[row * 68 + (lane & 15) * 4];
      *(f32x4*)(out + (size_t)grow * N + gcol) = v;
    }
    asm volatile("s_waitcnt lgkmcnt(0)" ::: "memory");
    __builtin_amdgcn_sched_barrier(0);
  }
}

extern "C" void kernel_launch(void* const* d_in, const int* in_sizes, int n_in,
                              void* d_out, int out_size, void* d_ws, size_t ws_size,
                              hipStream_t stream) {
  const int*   idx   = (const int*)  d_in[0];
  const float* tok_w = (const float*)d_in[1];
  const float* pos_w = (const float*)d_in[2];
  const float* ln1_g = (const float*)d_in[3];
  const float* ln1_b = (const float*)d_in[4];
  const float* wq    = (const float*)d_in[5];
  const float* wk    = (const float*)d_in[6];
  const float* wv    = (const float*)d_in[7];
  const float* wp    = (const float*)d_in[8];
  const float* bp    = (const float*)d_in[9];
  const float* ln2_g = (const float*)d_in[10];
  const float* ln2_b = (const float*)d_in[11];
  const float* w1    = (const float*)d_in[12];
  const float* b1    = (const float*)d_in[13];
  const float* w2    = (const float*)d_in[14];
  const float* b2    = (const float*)d_in[15];
  const float* lnf_g = (const float*)d_in[16];
  const float* lnf_b = (const float*)d_in[17];
  const float* wlm   = (const float*)d_in[18];
  const float* blm   = (const float*)d_in[19];

  const int M = B_BATCH * T_SEQ;  // 2048
  const size_t EE = (size_t)E_DIM * E_DIM;
  const size_t EF = (size_t)E_DIM * F_DIM;
  char* p = (char*)d_ws;
  float* x            = (float*)p;          p += (size_t)M * E_DIM * 4;
  unsigned short* hb  = (unsigned short*)p; p += (size_t)M * E_DIM * 2;
  unsigned short* qkb = (unsigned short*)p; p += (size_t)M * 2 * E_DIM * 2;
  unsigned short* vtb = (unsigned short*)p; p += (size_t)M * E_DIM * 2;
  unsigned short* yb  = (unsigned short*)p; p += (size_t)M * E_DIM * 2;
  unsigned short* tb  = (unsigned short*)p; p += (size_t)M * F_DIM * 2;
  unsigned short* wtb = (unsigned short*)p; p += (size_t)V_VOCAB * E_DIM * 2;

  embed_kernel<<<M * E_DIM / 4 / 256, 256, 0, stream>>>(idx, tok_w, pos_w, x);

  for (int l = 0; l < L_LAYERS; ++l) {
    wtrans6ln_kernel<<<5120, 256, 0, stream>>>(
        wq + l * EE, wk + l * EE, wv + l * EE, wp + l * EE,
        w1 + l * EF, w2 + l * EF,
        ln1_g + (size_t)l * E_DIM, ln1_b + (size_t)l * E_DIM, x, wtb, hb);
    gemm8p2_kernel<2, false, false>
        <<<(M / 128) * (3 * E_DIM / 256), 512, 0, stream>>>(
        hb, wtb, nullptr, qkb, vtb, M, 3 * E_DIM, E_DIM);
    attn_mfma_kernel<<<dim3(16, B_BATCH * H_HEADS), 512, 0, stream>>>(qkb, vtb, yb);
    gemm_bt_kernel<64, 128, true, false, true, 0>
        <<<(M / 64) * (E_DIM / 128), 256, 0, stream>>>(
        yb, wtb + 3 * EE, bp + (size_t)l * E_DIM, x, x, nullptr, M, E_DIM, E_DIM);
    ln_kernel<<<M, 256, 0, stream>>>(x, ln2_g + (size_t)l * E_DIM, ln2_b + (size_t)l * E_DIM, hb);
    gemm8p2_kernel<1, true, true>
        <<<(M / 128) * (F_DIM / 256), 512, 0, stream>>>(
        hb, wtb + 4 * EE, b1 + (size_t)l * F_DIM, tb, nullptr, M, F_DIM, E_DIM);
    gemm_bt_kernel<64, 128, true, false, true, 0>
        <<<(M / 64) * (E_DIM / 128), 256, 0, stream>>>(
        tb, wtb + 4 * EE + EF, b2 + (size_t)l * E_DIM, x, x, nullptr, M, E_DIM, F_DIM);
  }
  wtransv_ln_kernel<<<10048, 256, 0, stream>>>(wlm, lnf_g, lnf_b, x, wtb, hb);
  gemm8p_kernel<<<(M / 256) * (V_VOCAB / 256), 512, 0, stream>>>(
      hb, wtb, blm, (float*)d_out, M, V_VOCAB, E_DIM);
}